// Round 13
// baseline (373.060 us; speedup 1.0000x reference)
//
#include <hip/hip_runtime.h>

#define HID 2048
#define HEADS 16
#define HD 128
#define BATCH 2
#define S 2048
#define ROWS (BATCH*S)

typedef short short8 __attribute__((ext_vector_type(8)));
typedef unsigned short ushort4v __attribute__((ext_vector_type(4)));
typedef unsigned short ushort2v __attribute__((ext_vector_type(2)));
typedef float f32x4 __attribute__((ext_vector_type(4)));
typedef __bf16 bf16x8 __attribute__((ext_vector_type(8)));
typedef __bf16 bf16x4 __attribute__((ext_vector_type(4)));

static __device__ __forceinline__ float b2f(unsigned short u) {
  union { float f; unsigned int i; } v; v.i = ((unsigned int)u) << 16; return v.f;
}
static __device__ __forceinline__ unsigned short f2b(float f) {
  union { float f; unsigned int i; } v; v.f = f;
  unsigned int u = v.i;
  unsigned int r = ((u >> 16) & 1u) + 0x7fffu;
  return (unsigned short)((u + r) >> 16);
}

// async global->LDS, 16B per lane; LDS dest = wave-uniform base + lane*16 (global src is per-lane)
static __device__ __forceinline__ void gload_lds16(const unsigned short* g, unsigned short* l) {
  __builtin_amdgcn_global_load_lds(
      (const __attribute__((address_space(1))) unsigned int*)(const void*)g,
      (__attribute__((address_space(3))) unsigned int*)(void*)l,
      16, 0, 0);
}

// ---------------- debug fill (ws-size canary) ----------------
__global__ void fill_debug(unsigned short* __restrict__ out, long n) {
  long i = (long)blockIdx.x * blockDim.x + threadIdx.x;
  if (i < n) out[i] = 0x447A;  // bf16 1000.0
}

// ---------------- fused prep: conv repacks + x convert + rope tables + small converts ----------
__global__ void prep_all(const float* __restrict__ c1w, const float* __restrict__ c2w,
                         const float* __restrict__ x, const int* __restrict__ positions,
                         const float* __restrict__ c1b, const float* __restrict__ c2b,
                         const float* __restrict__ rmsw,
                         unsigned short* __restrict__ w1t0, unsigned short* __restrict__ w1t1,
                         unsigned short* __restrict__ w2t0, unsigned short* __restrict__ w2t1,
                         unsigned short* __restrict__ xb,
                         float* __restrict__ ctab, float* __restrict__ stab,
                         unsigned short* __restrict__ c1bb, unsigned short* __restrict__ c2bb,
                         unsigned short* __restrict__ rmswb, unsigned short* __restrict__ zpg) {
  int job = blockIdx.y;
  if (job == 0 || job == 1) {
    const float* w = (job == 0) ? c1w : c2w;
    unsigned short* o0 = (job == 0) ? w1t0 : w2t0;
    unsigned short* o1 = (job == 0) ? w1t1 : w2t1;
    long i = (long)blockIdx.x * 256 + threadIdx.x;
    f32x4 v = *(const f32x4*)(w + i*4);
    ushort2v a = { f2b(v[0]), f2b(v[2]) };
    ushort2v b = { f2b(v[1]), f2b(v[3]) };
    *(ushort2v*)(o0 + i*2) = a;
    *(ushort2v*)(o1 + i*2) = b;
  } else if (job == 2) {
    long i = (long)blockIdx.x * 256 + threadIdx.x;
    #pragma unroll
    for (int rep = 0; rep < 2; ++rep) {
      long idx = i + (long)rep * 1048576L;
      f32x4 v = *(const f32x4*)(x + idx*4);
      ushort4v o = { f2b(v[0]), f2b(v[1]), f2b(v[2]), f2b(v[3]) };
      *(ushort4v*)(xb + idx*4) = o;
    }
  } else {
    int bx = blockIdx.x;
    if (bx < 512) {
      int t = bx * 4 + (threadIdx.x >> 6);
      int i = threadIdx.x & 63;
      float pos = (float)positions[t];
      float inv = powf(10000.0f, -(float)i / 64.0f);
      float ang = pos * inv;
      float sv, cv;
      sincosf(ang, &sv, &cv);
      ctab[t*64 + i] = cv;
      stab[t*64 + i] = sv;
    } else if (bx < 544) {
      int i = (bx - 512) * 256 + threadIdx.x;   // 0..8191
      if (i < 1024) c1bb[i] = f2b(c1b[i]);
      if (i < 2048) { c2bb[i] = f2b(c2b[i]); rmswb[i] = f2b(rmsw[i]); }
      zpg[i] = 0;                               // 8192-ushort zero page (kk-advancing reads)
    }
  }
}

// ---------------- 4x 2048x2048 transpose fp32 [K,N] -> bf16 [N,K], one dispatch ----------------
__global__ void transpose4(const float* __restrict__ s0, const float* __restrict__ s1,
                           const float* __restrict__ s2, const float* __restrict__ s3,
                           unsigned short* __restrict__ d0, unsigned short* __restrict__ d1,
                           unsigned short* __restrict__ d2, unsigned short* __restrict__ d3) {
  __shared__ unsigned short tl[64][73];
  const float* in; unsigned short* out; int perm;
  switch (blockIdx.z) {
    case 0:  in = s0; out = d0; perm = 1; break;
    case 1:  in = s1; out = d1; perm = 1; break;
    case 2:  in = s2; out = d2; perm = 0; break;
    default: in = s3; out = d3; perm = 0; break;
  }
  int n0 = blockIdx.x * 64, k0 = blockIdx.y * 64;
  int tid = threadIdx.x;
  int r = tid >> 3, c8 = (tid & 7) * 8;
  #pragma unroll
  for (int j = 0; j < 2; ++j) {
    int rr = r + j*32;
    const float* p = in + (size_t)(k0 + rr)*HID + n0 + c8;
    f32x4 v0 = *(const f32x4*)p;
    f32x4 v1 = *(const f32x4*)(p + 4);
    #pragma unroll
    for (int e = 0; e < 4; ++e) { tl[rr][c8 + e] = f2b(v0[e]); tl[rr][c8 + 4 + e] = f2b(v1[e]); }
  }
  __syncthreads();
  #pragma unroll
  for (int j = 0; j < 2; ++j) {
    int rr = r + j*32;
    int orow = n0 + rr;
    if (perm) {
      int s5 = (orow >> 5) & 3;
      s5 = (s5 == 1) ? 2 : (s5 == 2) ? 1 : s5;
      orow = (orow & ~127) | (s5 << 5) | (orow & 31);
    }
    short8 v;
    #pragma unroll
    for (int e = 0; e < 8; ++e) v[e] = (short)tl[c8 + e][rr];
    *(short8*)(out + (size_t)orow*HID + k0 + c8) = v;
  }
}

// ============ shared GEMM helpers (swizzle proven: bank-conflict 0, rounds 2-12) ============

static __device__ __forceinline__ int swz_scol(int lane) {
  return (((lane & 7) * 16) ^ (((lane >> 3) & 7) << 4)) >> 1;   // swizzled src col (ushorts)
}

static __device__ __forceinline__ void rd_af(const unsigned short* Ah, bf16x8 (&afr)[4][2],
                                             int wm, int lr, int col0, int axor) {
  #pragma unroll
  for (int mi = 0; mi < 4; ++mi) {
    const unsigned short* rp = Ah + (wm*64 + mi*16 + lr) * 64;
    #pragma unroll
    for (int kk = 0; kk < 2; ++kk)
      afr[mi][kk] = *(const bf16x8*)(rp + (((kk*64 + col0) ^ axor) >> 1));
  }
}
static __device__ __forceinline__ void rd_bf(const unsigned short* Bh, bf16x8 (&bfr)[2][2],
                                             int wn, int lr, int col0, int axor) {
  #pragma unroll
  for (int ni = 0; ni < 2; ++ni) {
    const unsigned short* rp = Bh + (wn*32 + ni*16 + lr) * 64;
    #pragma unroll
    for (int kk = 0; kk < 2; ++kk)
      bfr[ni][kk] = *(const bf16x8*)(rp + (((kk*64 + col0) ^ axor) >> 1));
  }
}
static __device__ __forceinline__ void mfma16(const bf16x8 (&afr)[4][2], const bf16x8 (&bfr)[2][2],
                                              f32x4 (&ac)[4][2]) {
  #pragma unroll
  for (int kk = 0; kk < 2; ++kk)
    #pragma unroll
    for (int mi = 0; mi < 4; ++mi)
      #pragma unroll
      for (int ni = 0; ni < 2; ++ni)
        ac[mi][ni] = __builtin_amdgcn_mfma_f32_16x16x32_bf16(afr[mi][kk], bfr[ni][kk], ac[mi][ni], 0, 0, 0);
}

// per-lane half-tile staging pointers (2 chunks/thread, 16KB per half)
static __device__ __forceinline__ void bld_A(const unsigned short** p, const unsigned short* Ap,
    int Ksz, int sh, int mbase, const unsigned short* zpg, int tid) {
  int lane = tid & 63;
  int scol = swz_scol(lane);
  #pragma unroll
  for (int j = 0; j < 2; ++j) {
    int row = ((tid >> 6) * 2 + j) * 8 + (lane >> 3);   // 0..127
    int gr = mbase + row;
    p[j] = (sh && ((gr & (S - 1)) == 0)) ? (zpg + scol)
                                         : (Ap + (size_t)(gr - sh)*Ksz + scol);
  }
}
static __device__ __forceinline__ void bld_B(const unsigned short** p, const unsigned short* Bp,
    int Ksz, int nbase, int tid) {
  int lane = tid & 63;
  int scol = swz_scol(lane);
  #pragma unroll
  for (int j = 0; j < 2; ++j) {
    int row = ((tid >> 6) * 2 + j) * 8 + (lane >> 3);
    p[j] = Bp + (size_t)(nbase + row)*Ksz + scol;
  }
}
static __device__ __forceinline__ void st_half(unsigned short* slot, const unsigned short** p, int tid) {
  int c0 = (tid >> 6) * 1024;
  gload_lds16(p[0], slot + c0);
  gload_lds16(p[1], slot + c0 + 512);
  p[0] += 64; p[1] += 64;
}

// ================= 256x128-tile 2-phase GEMM (8-phase-template variant) =================
// C = A1@B1t + A2@B2t (+bias)(+resid). 512 threads = 8 waves (wm 0..1 x wn 0..3).
// Wave C region: rows qm*128 + wm*64 + mi*16, cols wn*32 + ni*16 (qm = phase).
// LDS 96KB: 2 bufs x {A0 128x64 | A1 128x64 | B 128x64}. Per K-tile t (cur=buf[t&1]):
//   P1 (qm0): rd A0(8)+B(4) ; stage A1(t+1)->oth ; bar ; lgkm0 ; prio1 ; 16 MFMA ; prio0 ; bar
//   P2 (qm1): rd A1(8), B regs reused ; stage A0(t+2),B(t+2)->cur ; bar ; lgkm0 ; prio1 ;
//             16 MFMA ; prio0 ; vmcnt(4) ; bar
// Ledger: 6 stage instrs/tile; vmcnt(4)@tile-end leaves newest 2 halves {A0,B}(t+2) in
// flight, forces A1(t+1)+older landed => tile t+1 fully resident. Prologue: tile0
// {A0,A1,B} + tile1 {A0,B}; vmcnt(4) => tile0 landed. WAR: each region's write is >=1
// lgkm-drained barrier after its last read (A1(oth): read P2(t-1); A0/B(cur): read P1(t)).
// Tail (t+2>=nk stages nothing) drains vmcnt(0). Segment switch rebuilds per group.

static __device__ __forceinline__ void gemm128_core(
    unsigned short* lds,
    const unsigned short* __restrict__ A1s, const unsigned short* __restrict__ A2s,
    const unsigned short* __restrict__ B1s, const unsigned short* __restrict__ B2s,
    int K1, int K2,
    const unsigned short* __restrict__ bias, const unsigned short* __restrict__ resid,
    void* __restrict__ Cout, int outmode, int N, int m0, int n0,
    int a1shift, const unsigned short* __restrict__ zrow) {
  int tid = threadIdx.x;
  int lane = tid & 63, w = tid >> 6;
  int wm = w >> 2, wn = w & 3;
  int lr = lane & 15, g = lane >> 4;
  int col0 = g * 16;
  int axor = (lr & 7) << 4;
  int nk1 = K1 >> 6;                 // >= 16 at all call sites
  int nk = (K1 + K2) >> 6;
  f32x4 acc[2][4][2] = {};
  bf16x8 af[4][2], bf[2][2];

  const unsigned short* pA0[2];
  const unsigned short* pA1[2];
  const unsigned short* pB[2];
  bld_A(pA0, A1s, K1, a1shift, m0,       zrow, tid);
  bld_A(pA1, A1s, K1, a1shift, m0 + 128, zrow, tid);
  bld_B(pB,  B1s, K1, n0, tid);

  // buf b (ushorts): A0 @ b*24576, A1 @ +8192, B @ +16384
  st_half(lds + 0,     pA0, tid);          // tile0
  st_half(lds + 8192,  pA1, tid);
  st_half(lds + 16384, pB,  tid);
  st_half(lds + 24576 + 0,     pA0, tid);  // tile1 {A0,B}
  st_half(lds + 24576 + 16384, pB,  tid);
  asm volatile("s_waitcnt vmcnt(4)" ::: "memory");   // tile0 landed; tile1's 2 halves in flight
  __builtin_amdgcn_s_barrier();
  asm volatile("" ::: "memory");

  for (int t = 0; t < nk; ++t) {
    unsigned short* cur = lds + (t & 1) * 24576;
    unsigned short* oth = lds + ((t & 1) ^ 1) * 24576;

    // ---- P1 (qm=0): rd A0 + B ; stage A1(t+1) -> oth ----
    rd_af(cur,         af, wm, lr, col0, axor);
    rd_bf(cur + 16384, bf, wn, lr, col0, axor);
    if (t + 1 < nk) {
      if (t + 1 == nk1) bld_A(pA1, A2s, K2, 0, m0 + 128, zrow, tid);
      st_half(oth + 8192, pA1, tid);
    }
    __builtin_amdgcn_s_barrier();
    asm volatile("s_waitcnt lgkmcnt(0)" ::: "memory");
    __builtin_amdgcn_s_setprio(1);
    mfma16(af, bf, acc[0]);
    __builtin_amdgcn_s_setprio(0);
    __builtin_amdgcn_s_barrier();

    // ---- P2 (qm=1): rd A1 (B regs reused) ; stage A0(t+2), B(t+2) -> cur ; counted vmcnt ----
    rd_af(cur + 8192, af, wm, lr, col0, axor);
    if (t + 2 < nk) {
      if (t + 2 == nk1) { bld_A(pA0, A2s, K2, 0, m0, zrow, tid); bld_B(pB, B2s, K2, n0, tid); }
      st_half(cur,         pA0, tid);
      st_half(cur + 16384, pB,  tid);
    }
    __builtin_amdgcn_s_barrier();
    asm volatile("s_waitcnt lgkmcnt(0)" ::: "memory");
    __builtin_amdgcn_s_setprio(1);
    mfma16(af, bf, acc[1]);
    __builtin_amdgcn_s_setprio(0);
    if (t + 2 < nk) asm volatile("s_waitcnt vmcnt(4)" ::: "memory");
    else            asm volatile("s_waitcnt vmcnt(0)" ::: "memory");
    __builtin_amdgcn_s_barrier();
    asm volatile("" ::: "memory");
  }

  // ---- epilogue ----
  #pragma unroll
  for (int qm = 0; qm < 2; ++qm)
    #pragma unroll
    for (int mi = 0; mi < 4; ++mi) {
      int row0 = m0 + qm*128 + wm*64 + mi*16 + g*4;
      #pragma unroll
      for (int ni = 0; ni < 2; ++ni) {
        int col = n0 + wn*32 + ni*16 + lr;
        float bv = bias ? b2f(bias[col]) : 0.f;
        f32x4 a = acc[qm][mi][ni];
        if (outmode == 3) {
          int bb = row0 >> 11;
          int s0 = row0 & (S - 1);
          size_t base = ((size_t)bb * HID + col) * S + s0;
          ushort4v pk;
          #pragma unroll
          for (int j = 0; j < 4; ++j) pk[j] = f2b(a[j]);
          *(ushort4v*)((unsigned short*)Cout + base) = pk;
        } else {
          #pragma unroll
          for (int j = 0; j < 4; ++j) {
            size_t idx = (size_t)(row0 + j) * N + col;
            float v = a[j] + bv;
            if (resid) v += b2f(resid[idx]);
            if (outmode == 1) ((float*)Cout)[idx] = v;
            else ((unsigned short*)Cout)[idx] = f2b(v);
          }
        }
      }
    }
}

template<int SHIFT>
__launch_bounds__(512, 1)
__global__ void gemm128_bt(const unsigned short* __restrict__ A1,
                           const unsigned short* __restrict__ A2,
                           const unsigned short* __restrict__ B1,
                           const unsigned short* __restrict__ B2,
                           int K1, int K2,
                           const unsigned short* __restrict__ bias,
                           const unsigned short* __restrict__ resid,
                           void* __restrict__ Cout, int outmode, int N,
                           const unsigned short* __restrict__ zrow) {
  __shared__ __align__(16) unsigned short lds[49152];   // 96 KiB
  gemm128_core(lds, A1, A2, B1, B2, K1, K2, bias, resid, Cout, outmode, N,
               blockIdx.x*256, blockIdx.y*128, SHIFT, zrow);
}

// two independent GEMM jobs in one dispatch; heavy job MUST be j0 (dispatched first)
struct GemmJob {
  const unsigned short *A1, *A2, *B1, *B2;
  int K1, K2;
  const unsigned short *bias;
  void* Cout; int outmode; int N; int nby; int a1shift;
};

__launch_bounds__(512, 1)
__global__ void gemm128_dual(GemmJob j0, GemmJob j1, const unsigned short* __restrict__ zrow) {
  __shared__ __align__(16) unsigned short lds[49152];
  int by = blockIdx.y;
  GemmJob j;
  if (by < j0.nby) { j = j0; } else { j = j1; by -= j0.nby; }
  gemm128_core(lds, j.A1, j.A2, j.B1, j.B2, j.K1, j.K2, j.bias, nullptr,
               j.Cout, j.outmode, j.N, blockIdx.x*256, by*128, j.a1shift, zrow);
}

// ================= 256x256-tile 4-phase GEMM (qk projection; validated round 12) ============
struct HPtr { const unsigned short* p0; const unsigned short* p1; };
static __device__ __forceinline__ void hinit(HPtr& h, const unsigned short* base,
                                             int row0, int tid) {
  int lane = tid & 63;
  int scol = swz_scol(lane);
  int r0 = ((tid >> 6) * 2) * 8 + (lane >> 3);
  h.p0 = base + (size_t)(row0 + r0) * 2048 + scol;
  h.p1 = base + (size_t)(row0 + r0 + 8) * 2048 + scol;
}
static __device__ __forceinline__ void hstage(unsigned short* slot, HPtr& h, int tid) {
  int c0 = (tid >> 6) * 1024;
  gload_lds16(h.p0, slot + c0);
  gload_lds16(h.p1, slot + c0 + 512);
  h.p0 += 64; h.p1 += 64;
}

__launch_bounds__(512, 1)
__global__ void gemm256_bt(const unsigned short* __restrict__ A,
                           const unsigned short* __restrict__ B,
                           unsigned short* __restrict__ C, int N) {
  __shared__ __align__(16) unsigned short lds[65536];   // 128 KiB
  int tid = threadIdx.x;
  int lane = tid & 63, w = tid >> 6;
  int wm = w >> 2, wn = w & 3;
  int lr = lane & 15, g = lane >> 4;
  int col0 = g * 16;
  int axor = (lr & 7) << 4;
  int m0 = blockIdx.x * 256, n0 = blockIdx.y * 256;
  const int nk = 2048 >> 6;   // 32 K-tiles
  f32x4 acc[2][2][4][2] = {};           // [qm][qn][mi][ni]
  bf16x8 af[4][2], bf0[2][2], bf1[2][2];

  HPtr hA0, hA1, hB0, hB1;
  hinit(hA0, A, m0,       tid);
  hinit(hA1, A, m0 + 128, tid);
  hinit(hB0, B, n0,       tid);
  hinit(hB1, B, n0 + 128, tid);

  // buf b (ushorts): A0 @ b*32768, A1 @ +8192, B0 @ +16384, B1 @ +24576
  hstage(lds + 0,             hA0, tid);
  hstage(lds + 8192,          hA1, tid);
  hstage(lds + 16384,         hB0, tid);
  hstage(lds + 24576,         hB1, tid);
  hstage(lds + 32768 + 0,     hA0, tid);
  hstage(lds + 32768 + 16384, hB0, tid);
  hstage(lds + 32768 + 24576, hB1, tid);
  asm volatile("s_waitcnt vmcnt(6)" ::: "memory");   // tile0 landed; tile1's 3 halves in flight
  __builtin_amdgcn_s_barrier();
  asm volatile("" ::: "memory");

  for (int t = 0; t < nk; ++t) {
    unsigned short* cur = lds + (t & 1) * 32768;
    unsigned short* oth = lds + ((t & 1) ^ 1) * 32768;

    // ---- P1 (qm0,qn0): rd A0(8)+B0(4) ; stage A1(t+1) -> oth ----
    rd_af(cur,         af,  wm, lr, col0, axor);
    rd_bf(cur + 16384, bf0, wn, lr, col0, axor);
    if (t + 1 < nk) hstage(oth + 8192, hA1, tid);
    __builtin_amdgcn_s_barrier();
    asm volatile("s_waitcnt lgkmcnt(0)" ::: "memory");
    __builtin_amdgcn_s_setprio(1);
    mfma16(af, bf0, acc[0][0]);
    __builtin_amdgcn_s_setprio(0);
    __builtin_amdgcn_s_barrier();

    // ---- P2 (qm0,qn1): rd B1(4) (A regs reused) ; stage A0(t+2) -> cur ----
    rd_bf(cur + 24576, bf1, wn, lr, col0, axor);
    if (t + 2 < nk) hstage(cur, hA0, tid);
    __builtin_amdgcn_s_barrier();
    asm volatile("s_waitcnt lgkmcnt(0)" ::: "memory");
    __builtin_amdgcn_s_setprio(1);
    mfma16(af, bf1, acc[0][1]);
    __builtin_amdgcn_s_setprio(0);
    __builtin_amdgcn_s_barrier();

    // ---- P3 (qm1,qn1): rd A1(8) (B1 regs reused) ; stage B0(t+2) -> cur ----
    rd_af(cur + 8192, af, wm, lr, col0, axor);
    if (t + 2 < nk) hstage(cur + 16384, hB0, tid);
    __builtin_amdgcn_s_barrier();
    asm volatile("s_waitcnt lgkmcnt(0)" ::: "memory");
    __builtin_amdgcn_s_setprio(1);
    mfma16(af, bf1, acc[1][1]);
    __builtin_amdgcn_s_setprio(0);
    __builtin_amdgcn_s_barrier();

    // ---- P4 (qm1,qn0): all regs reused ; stage B1(t+2) -> cur ; counted vmcnt ----
    if (t + 2 < nk) hstage(cur + 24576, hB1, tid);
    __builtin_amdgcn_s_barrier();
    asm volatile("s_waitcnt lgkmcnt(0)" ::: "memory");
    __builtin_amdgcn_s_setprio(1);
    mfma16(af, bf0, acc[1][0]);
    __builtin_amdgcn_s_setprio(0);
    if (t + 2 < nk) asm volatile("s_waitcnt vmcnt(6)" ::: "memory");
    else            asm volatile("s_waitcnt vmcnt(0)" ::: "memory");
    __builtin_amdgcn_s_barrier();
    asm volatile("" ::: "memory");
  }

  // ---- epilogue: bf16 [row][N] ----
  #pragma unroll
  for (int qm = 0; qm < 2; ++qm)
    #pragma unroll
    for (int mi = 0; mi < 4; ++mi) {
      int row0 = m0 + qm*128 + wm*64 + mi*16 + g*4;
      #pragma unroll
      for (int qn = 0; qn < 2; ++qn)
        #pragma unroll
        for (int ni = 0; ni < 2; ++ni) {
          int col = n0 + qn*128 + wn*32 + ni*16 + lr;
          f32x4 a = acc[qm][qn][mi][ni];
          #pragma unroll
          for (int j = 0; j < 4; ++j)
            C[(size_t)(row0 + j) * N + col] = f2b(a[j]);
        }
    }
}

// ---------------- RMSNorm over bf16 rows -> bf16 (single-pass, short8) ----------------
__global__ void rmsnorm_rows(const unsigned short* __restrict__ y,
                             const unsigned short* __restrict__ w,
                             unsigned short* __restrict__ out) {
  int r = blockIdx.x;
  int c8 = threadIdx.x * 8;               // 256 threads x 8 = 2048
  const unsigned short* yr = y + (size_t)r * HID;
  short8 v = *(const short8*)(yr + c8);
  float f[8];
  float ss = 0.f;
  #pragma unroll
  for (int e = 0; e < 8; ++e) { f[e] = b2f((unsigned short)v[e]); ss += f[e]*f[e]; }
  #pragma unroll
  for (int o = 32; o; o >>= 1) ss += __shfl_xor(ss, o);
  __shared__ float red[4];
  if ((threadIdx.x & 63) == 0) red[threadIdx.x >> 6] = ss;
  __syncthreads();
  float tot = red[0] + red[1] + red[2] + red[3];
  float scale = rsqrtf(tot / (float)HID + 1e-6f);
  short8 wv = *(const short8*)(w + c8);
  short8 o8;
  #pragma unroll
  for (int e = 0; e < 8; ++e) o8[e] = (short)f2b(f[e] * scale * b2f((unsigned short)wv[e]));
  *(short8*)(out + (size_t)r*HID + c8) = o8;
}

// ---------------- RoPE from fused qk output [r][4096]; head h = cols h*256..+255 ----------------
__global__ void rope_rearrange(const unsigned short* __restrict__ qkf,
                               const float* __restrict__ ctab, const float* __restrict__ stab,
                               unsigned short* __restrict__ qr, unsigned short* __restrict__ kr) {
  int r = blockIdx.x;
  int t = r & (S - 1);
  int h = threadIdx.x >> 4;
  int i4 = (threadIdx.x & 15) * 4;
  int pc = (i4 & 31) + ((i4 >> 5) << 6);    // permuted col of x1 for elems i4..i4+3 (same 32-block)
  const unsigned short* qk = qkf + (size_t)r * (2*HID) + h * 256;
  f32x4 c = *(const f32x4*)(ctab + t*64 + i4);
  f32x4 s = *(const f32x4*)(stab + t*64 + i4);
  ushort4v q1 = *(const ushort4v*)(qk + pc);
  ushort4v q2 = *(const ushort4v*)(qk + pc + 32);
  ushort4v k1 = *(const ushort4v*)(qk + 128 + pc);
  ushort4v k2 = *(const ushort4v*)(qk + 128 + pc + 32);
  size_t o = (size_t)r * HID + (size_t)h * HD;
  const float SC = 0.08838834764831845f * 1.44269504088896340f;  // 1/sqrt(128) * log2(e)
  ushort4v oq1, oq2, ok1, ok2;
  #pragma unroll
  for (int e = 0; e < 4; ++e) {
    float a = b2f(q1[e]), b = b2f(q2[e]);
    float x = b2f(k1[e]), y = b2f(k2[e]);
    oq1[e] = f2b((a*c[e] - b*s[e]) * SC);
    oq2[e] = f2b((b*c[e] + a*s[e]) * SC);
    ok1[e] = f2b(x*c[e] - y*s[e]);
    ok2[e] = f2b(y*c[e] + x*s[e]);
  }
  *(ushort4v*)(qr + o + i4)      = oq1;
  *(ushort4v*)(qr + o + 64 + i4) = oq2;
  *(ushort4v*)(kr + o + i4)      = ok1;
  *(ushort4v*)(kr + o + 64 + i4) = ok2;
}

// ---------------- MFMA causal flash attention (16x16, DMA-staged, balanced pairs) ----------------
#define KT 64

static __device__ __forceinline__ void attn_pass(
    int qt, int b, int h, unsigned short* lds,
    const unsigned short* __restrict__ Qr, const unsigned short* __restrict__ Kr,
    const unsigned short* __restrict__ Vt, unsigned short* __restrict__ Out) {
  int tid = threadIdx.x, lane = tid & 63, w = tid >> 6;
  int q0 = qt * 64;
  size_t bS = (size_t)b * S;
  size_t ho = (size_t)h * HD;
  int lr = lane & 15, g = lane >> 4;
  int rsw = (lane & 7) << 3;                       // read-side swizzle (ushort units)
  // all waves past previous pass's LDS reads before re-staging the shared buffers
  __syncthreads();
  bf16x8 bq[4];
  {
    int qrow = q0 + w*16 + lr;
    const unsigned short* qp = Qr + (bS + qrow)*HID + ho + g*8;
    #pragma unroll
    for (int kk = 0; kk < 4; ++kk) bq[kk] = *(const bf16x8*)(qp + kk*32);
  }
  // staging pointers (pre-swizzled source cols; advance per tile)
  const unsigned short* kp[4];
  const unsigned short* vp[4];
  #pragma unroll
  for (int j = 0; j < 4; ++j) {
    int c = w*4 + j;                       // chunk 0..15 (1KB each)
    int rk = c*4 + (lane >> 4);            // K row 0..63
    int sck = ((lane & 15) * 8) ^ ((rk & 7) << 3);
    kp[j] = Kr + (bS + rk)*HID + ho + sck;
    int rv = c*8 + (lane >> 3);            // V row (d) 0..127
    int scv = ((lane & 7) * 8) ^ ((rv & 7) << 3);
    vp[j] = Vt + ((size_t)b*HID + ho + rv)*S + scv;
  }
  int cdst = (w*4) * 512;                  // this wave's chunk-group dest (ushorts)
  unsigned short* curK = lds;
  unsigned short* curV = lds + 8192;
  unsigned short* nxtK = lds + 16384;
  unsigned short* nxtV = lds + 24576;
  #pragma unroll
  for (int j = 0; j < 4; ++j) {            // prologue: tile 0 -> cur
    gload_lds16(kp[j], curK + cdst + j*512);
    gload_lds16(vp[j], curV + cdst + j*512);
    kp[j] += (size_t)KT * HID;
    vp[j] += KT;
  }
  f32x4 o[8] = {};                 // O: col(d)=lr+16*ni, row(q_local)=4g+reg
  float m = -1e30f, l = 0.f;
  unsigned short* PlW = lds + 32768 + w*1024;
  int ntiles = qt + 1;
  for (int kt = 0; kt < ntiles; ++kt) {
    // ---- single sync point: own DMA landed, then block-wide barrier ----
    asm volatile("s_waitcnt vmcnt(0)" ::: "memory");
    __builtin_amdgcn_s_barrier();
    asm volatile("" ::: "memory");
    if (kt + 1 < ntiles) {                 // issue next-tile DMA into the other buffer
      #pragma unroll
      for (int j = 0; j < 4; ++j) {
        gload_lds16(kp[j], nxtK + cdst + j*512);
        gload_lds16(vp[j], nxtV + cdst + j*512);
        kp[j] += (size_t)KT * HID;
        vp[j] += KT;
      }
    }
    f32x4 st[4] = {};
    __builtin_amdgcn_s_setprio(1);
    #pragma unroll
    for (int kk = 0; kk < 4; ++kk) {
      #pragma unroll
      for (int mi = 0; mi < 4; ++mi) {
        bf16x8 a = *(const bf16x8*)(&curK[(mi*16 + lr)*128 + ((kk*32 + g*8) ^ rsw)]);
        st[mi] = __builtin_amdgcn_mfma_f32_16x16x32_bf16(a, bq[kk], st[mi], 0, 0, 0);
      }
    }
    __builtin_amdgcn_s_setprio(0);
    bool lastt = (kt == ntiles - 1);
    float tm = -1e30f;
    #pragma unroll
    for (int mi = 0; mi < 4; ++mi)
      #pragma unroll
      for (int r = 0; r < 4; ++r) {
        float v = st[mi][r];
        if (lastt && (mi*16 + 4*g + r) > (w*16 + lr)) v = -1e30f;
        st[mi][r] = v;
        tm = fmaxf(tm, v);
      }
    tm = fmaxf(tm, __shfl_xor(tm, 16));
    tm = fmaxf(tm, __shfl_xor(tm, 32));
    if (!__all(tm - m <= 11.5f)) {
      float mn = fmaxf(m, tm);
      float sc = exp2f(m - mn);
      float s0 = __shfl(sc, 4*g+0), s1 = __shfl(sc, 4*g+1);
      float s2 = __shfl(sc, 4*g+2), s3 = __shfl(sc, 4*g+3);
      #pragma unroll
      for (int ni = 0; ni < 8; ++ni) {
        o[ni][0] *= s0; o[ni][1] *= s1; o[ni][2] *= s2; o[ni][3] *= s3;
      }
      l *= sc;
      m = mn;
    }
    float ts = 0.f;
    __bf16 pbf[4][4];
    #pragma unroll
    for (int mi = 0; mi < 4; ++mi)
      #pragma unroll
      for (int r = 0; r < 4; ++r) {
        float p = exp2f(st[mi][r] - m);
        ts += p;
        pbf[mi][r] = (__bf16)p;
      }
    ts += __shfl_xor(ts, 16);
    ts += __shfl_xor(ts, 32);
    l += ts;
    #pragma unroll
    for (int mi = 0; mi < 4; ++mi) {
      bf16x4 pk = { pbf[mi][0], pbf[mi][1], pbf[mi][2], pbf[mi][3] };
      *(bf16x4*)(&PlW[lr*64 + ((mi*16 + 4*g) ^ rsw)]) = pk;
    }
    asm volatile("" ::: "memory");   // compile-time fence: P stores before P reads
    __builtin_amdgcn_s_setprio(1);
    #pragma unroll
    for (int kk = 0; kk < 2; ++kk) {
      int pc = (kk*32 + g*8) ^ rsw;
      bf16x8 a = *(const bf16x8*)(&PlW[lr*64 + pc]);
      #pragma unroll
      for (int ni = 0; ni < 8; ++ni) {
        bf16x8 bv = *(const bf16x8*)(&curV[(ni*16 + lr)*64 + pc]);
        o[ni] = __builtin_amdgcn_mfma_f32_16x16x32_bf16(a, bv, o[ni], 0, 0, 0);
      }
    }
    __builtin_amdgcn_s_setprio(0);
    unsigned short* t0 = curK; curK = nxtK; nxtK = t0;
    unsigned short* t1 = curV; curV = nxtV; nxtV = t1;
  }
  float l0 = __shfl(l, 4*g+0), l1 = __shfl(l, 4*g+1);
  float l2 = __shfl(l, 4*g+2), l3 = __shfl(l, 4*g+3);
  float i0 = 1.f/l0, i1 = 1.f/l1, i2 = 1.f/l2, i3 = 1.f/l3;
  int rbase = q0 + w*16 + 4*g;
  #pragma unroll
  for (int ni = 0; ni < 8; ++ni) {
    size_t cbase = ho + ni*16 + lr;
    Out[(bS + rbase + 0)*HID + cbase] = f2b(o[ni][0]*i0);
    Out[(bS + rbase + 1)*HID + cbase] = f2b(o[ni][1]*i1);
    Out[(bS + rbase + 2)*HID + cbase] = f2b(o[ni][2]*i2);
    Out[(bS + rbase + 3)*HID + cbase] = f2b(o[ni][3]*i3);
  }
}

__launch_bounds__(256, 2)
__global__ void attn_mfma(const unsigned short* __restrict__ Qr,
                          const unsigned short* __restrict__ Kr,
                          const unsigned short* __restrict__ Vt,
                          unsigned short* __restrict__ Out) {
  // [0,8192) K0 | [8192,16384) V0 | [16384,24576) K1 | [24576,32768) V1 | [32768,36864) P
  __shared__ __align__(16) unsigned short lds[36864];
  int bh = blockIdx.x;
  int b = bh >> 4, h = bh & 15;
  int by = blockIdx.y;                       // 0..15
  attn_pass(31 - by, b, h, lds, Qr, Kr, Vt, Out);   // heavy tile
  attn_pass(by,      b, h, lds, Qr, Kr, Vt, Out);   // light tile; total = 33 KV-tiles/block
}

extern "C" void kernel_launch(void* const* d_in, const int* in_sizes, int n_in,
                              void* d_out, int out_size, void* d_ws, size_t ws_size,
                              hipStream_t stream) {
  const float* x_raw   = (const float*)d_in[0];
  const int* positions = (const int*)d_in[1];
  const float* wq_raw  = (const float*)d_in[2];
  const float* wk_raw  = (const float*)d_in[3];
  const float* wv_raw  = (const float*)d_in[4];
  const float* wo_raw  = (const float*)d_in[5];
  const float* c1w_raw = (const float*)d_in[6];
  const float* c1b_raw = (const float*)d_in[7];
  const float* c2w_raw = (const float*)d_in[8];
  const float* c2b_raw = (const float*)d_in[9];
  const float* rms_raw = (const float*)d_in[10];

  const size_t WS_NEEDED = 140000000;
  if (ws_size < WS_NEEDED) {
    long n = (long)out_size;
    fill_debug<<<dim3((unsigned)((n + 255) / 256)), dim3(256), 0, stream>>>((unsigned short*)d_out, n);
    return;
  }

  char* ws = (char*)d_ws;
  size_t off = 0;
  auto alloc = [&](size_t bytes) { char* p = ws + off; off += (bytes + 255) & ~(size_t)255; return p; };
  float* ctab          = (float*)alloc((size_t)S*64*4);
  float* stab          = (float*)alloc((size_t)S*64*4);
  unsigned short* wqkt = (unsigned short*)alloc((size_t)2*HID*HID*2);  // [wq^T ; wk^T], rope-permuted
  unsigned short* wvt  = (unsigned short*)alloc((size_t)HID*HID*2);
  unsigned short* wot  = (unsigned short*)alloc((size_t)HID*HID*2);
  unsigned short* w1t0 = (unsigned short*)alloc((size_t)1024*HID*2);
  unsigned short* w1t1 = (unsigned short*)alloc((size_t)1024*HID*2);
  unsigned short* w2t0 = (unsigned short*)alloc((size_t)HID*1024*2);
  unsigned short* w2t1 = (unsigned short*)alloc((size_t)HID*1024*2);
  unsigned short* xb   = (unsigned short*)alloc((size_t)ROWS*HID*2);   // reused as kr after conv2
  unsigned short* qrb  = (unsigned short*)alloc((size_t)ROWS*HID*2);   // q rotated
  unsigned short* o1   = (unsigned short*)alloc((size_t)ROWS*1024*2);
  unsigned short* yb   = (unsigned short*)alloc((size_t)ROWS*HID*2);   // reused as attn out
  unsigned short* hg   = (unsigned short*)alloc((size_t)ROWS*HID*2);
  unsigned short* qkf  = (unsigned short*)alloc((size_t)ROWS*2*HID*2); // fused q|k output
  unsigned short* vtg  = (unsigned short*)alloc((size_t)BATCH*HID*S*2);
  unsigned short* c1bb = (unsigned short*)alloc(1024*2);
  unsigned short* c2bb = (unsigned short*)alloc(2048*2);
  unsigned short* rmswb= (unsigned short*)alloc(2048*2);
  unsigned short* zpg  = (unsigned short*)alloc(8192*2);               // zero page (kk-advancing)
  unsigned short* krr  = xb;     // xb dead after conv2 (resid read)
  unsigned short* attn = yb;     // yb dead after rmsnorm

  dim3 b256(256);
  dim3 b512(512);
  prep_all<<<dim3(4096, 4), b256, 0, stream>>>(c1w_raw, c2w_raw, x_raw, positions,
                                               c1b_raw, c2b_raw, rms_raw,
                                               w1t0, w1t1, w2t0, w2t1, xb,
                                               ctab, stab, c1bb, c2bb, rmswb, zpg);
  transpose4<<<dim3(32,32,4), b256, 0, stream>>>(wq_raw, wk_raw, wv_raw, wo_raw,
                                                 wqkt, wqkt + (size_t)HID*HID, wvt, wot);
  // merged dispatch (256x128 2-phase): conv1 (N=1024, K=4096, shifted) [HEAVY j0]
  //                                  + V-projection (N=2048, K=2048, Vt layout)
  {
    GemmJob j0 = { xb, xb, w1t0, w1t1, HID, HID, c1bb, o1, 0, 1024, 8, 1 };
    GemmJob j1 = { xb, xb, wvt,  wvt,  HID, 0,   nullptr, vtg, 3, HID, 16, 0 };
    gemm128_dual<<<dim3(ROWS/256, 24), b512, 0, stream>>>(j0, j1, zpg);
  }
  // conv2 + resid: yb = shift(o1)@W2_0^T + o1@W2_1^T + b2 + xb    [4096 x 2048]
  gemm128_bt<1><<<dim3(ROWS/256, HID/128), b512, 0, stream>>>(o1, o1, w2t0, w2t1, 1024, 1024, c2bb, xb, yb, 0, HID, zpg);
  rmsnorm_rows<<<dim3(ROWS), b256, 0, stream>>>(yb, rmswb, hg);
  // fused q|k projection (256x256 4-phase): qkf = hg @ [wq|wk]   [4096 x 4096], 256 blocks
  gemm256_bt<<<dim3(ROWS/256, (2*HID)/256), b512, 0, stream>>>(hg, wqkt, qkf, 2*HID);
  rope_rearrange<<<dim3(ROWS), b256, 0, stream>>>(qkf, ctab, stab, qrb, krr);
  attn_mfma<<<dim3(BATCH*HEADS, 16), b256, 0, stream>>>(qrb, krr, vtg, attn);
  // output projection (256x128 2-phase): d_out = attn @ wo^T   [4096 x 2048], f32 out
  gemm128_bt<0><<<dim3(ROWS/256, HID/128), b512, 0, stream>>>(attn, attn, wot, wot, HID, 0, nullptr, nullptr, d_out, 1, HID, nullptr);
}

// Round 14
// 354.044 us; speedup vs baseline: 1.0537x; 1.0537x over previous
//
#include <hip/hip_runtime.h>

#define HID 2048
#define HEADS 16
#define HD 128
#define BATCH 2
#define S 2048
#define ROWS (BATCH*S)

typedef short short8 __attribute__((ext_vector_type(8)));
typedef unsigned short ushort4v __attribute__((ext_vector_type(4)));
typedef unsigned short ushort2v __attribute__((ext_vector_type(2)));
typedef float f32x4 __attribute__((ext_vector_type(4)));
typedef __bf16 bf16x8 __attribute__((ext_vector_type(8)));
typedef __bf16 bf16x4 __attribute__((ext_vector_type(4)));

static __device__ __forceinline__ float b2f(unsigned short u) {
  union { float f; unsigned int i; } v; v.i = ((unsigned int)u) << 16; return v.f;
}
static __device__ __forceinline__ unsigned short f2b(float f) {
  union { float f; unsigned int i; } v; v.f = f;
  unsigned int u = v.i;
  unsigned int r = ((u >> 16) & 1u) + 0x7fffu;
  return (unsigned short)((u + r) >> 16);
}

// async global->LDS, 16B per lane; LDS dest = wave-uniform base + lane*16 (global src is per-lane)
static __device__ __forceinline__ void gload_lds16(const unsigned short* g, unsigned short* l) {
  __builtin_amdgcn_global_load_lds(
      (const __attribute__((address_space(1))) unsigned int*)(const void*)g,
      (__attribute__((address_space(3))) unsigned int*)(void*)l,
      16, 0, 0);
}

// ---------------- debug fill (ws-size canary) ----------------
__global__ void fill_debug(unsigned short* __restrict__ out, long n) {
  long i = (long)blockIdx.x * blockDim.x + threadIdx.x;
  if (i < n) out[i] = 0x447A;  // bf16 1000.0
}

// ---------------- fused prep: conv repacks + x convert + rope tables + small converts ----------
__global__ void prep_all(const float* __restrict__ c1w, const float* __restrict__ c2w,
                         const float* __restrict__ x, const int* __restrict__ positions,
                         const float* __restrict__ c1b, const float* __restrict__ c2b,
                         const float* __restrict__ rmsw,
                         unsigned short* __restrict__ w1t0, unsigned short* __restrict__ w1t1,
                         unsigned short* __restrict__ w2t0, unsigned short* __restrict__ w2t1,
                         unsigned short* __restrict__ xb,
                         float* __restrict__ ctab, float* __restrict__ stab,
                         unsigned short* __restrict__ c1bb, unsigned short* __restrict__ c2bb,
                         unsigned short* __restrict__ rmswb, unsigned short* __restrict__ zpg) {
  int job = blockIdx.y;
  if (job == 0 || job == 1) {
    const float* w = (job == 0) ? c1w : c2w;
    unsigned short* o0 = (job == 0) ? w1t0 : w2t0;
    unsigned short* o1 = (job == 0) ? w1t1 : w2t1;
    long i = (long)blockIdx.x * 256 + threadIdx.x;
    f32x4 v = *(const f32x4*)(w + i*4);
    ushort2v a = { f2b(v[0]), f2b(v[2]) };
    ushort2v b = { f2b(v[1]), f2b(v[3]) };
    *(ushort2v*)(o0 + i*2) = a;
    *(ushort2v*)(o1 + i*2) = b;
  } else if (job == 2) {
    long i = (long)blockIdx.x * 256 + threadIdx.x;
    #pragma unroll
    for (int rep = 0; rep < 2; ++rep) {
      long idx = i + (long)rep * 1048576L;
      f32x4 v = *(const f32x4*)(x + idx*4);
      ushort4v o = { f2b(v[0]), f2b(v[1]), f2b(v[2]), f2b(v[3]) };
      *(ushort4v*)(xb + idx*4) = o;
    }
  } else {
    int bx = blockIdx.x;
    if (bx < 512) {
      int t = bx * 4 + (threadIdx.x >> 6);
      int i = threadIdx.x & 63;
      float pos = (float)positions[t];
      float inv = powf(10000.0f, -(float)i / 64.0f);
      float ang = pos * inv;
      float sv, cv;
      sincosf(ang, &sv, &cv);
      ctab[t*64 + i] = cv;
      stab[t*64 + i] = sv;
    } else if (bx < 544) {
      int i = (bx - 512) * 256 + threadIdx.x;   // 0..8191
      if (i < 1024) c1bb[i] = f2b(c1b[i]);
      if (i < 2048) { c2bb[i] = f2b(c2b[i]); rmswb[i] = f2b(rmsw[i]); }
      zpg[i] = 0;                               // 8192-ushort zero page (kk-advancing reads)
    }
  }
}

// ---------------- 4x 2048x2048 transpose fp32 [K,N] -> bf16 [N,K], one dispatch ----------------
__global__ void transpose4(const float* __restrict__ s0, const float* __restrict__ s1,
                           const float* __restrict__ s2, const float* __restrict__ s3,
                           unsigned short* __restrict__ d0, unsigned short* __restrict__ d1,
                           unsigned short* __restrict__ d2, unsigned short* __restrict__ d3) {
  __shared__ unsigned short tl[64][73];
  const float* in; unsigned short* out; int perm;
  switch (blockIdx.z) {
    case 0:  in = s0; out = d0; perm = 1; break;
    case 1:  in = s1; out = d1; perm = 1; break;
    case 2:  in = s2; out = d2; perm = 0; break;
    default: in = s3; out = d3; perm = 0; break;
  }
  int n0 = blockIdx.x * 64, k0 = blockIdx.y * 64;
  int tid = threadIdx.x;
  int r = tid >> 3, c8 = (tid & 7) * 8;
  #pragma unroll
  for (int j = 0; j < 2; ++j) {
    int rr = r + j*32;
    const float* p = in + (size_t)(k0 + rr)*HID + n0 + c8;
    f32x4 v0 = *(const f32x4*)p;
    f32x4 v1 = *(const f32x4*)(p + 4);
    #pragma unroll
    for (int e = 0; e < 4; ++e) { tl[rr][c8 + e] = f2b(v0[e]); tl[rr][c8 + 4 + e] = f2b(v1[e]); }
  }
  __syncthreads();
  #pragma unroll
  for (int j = 0; j < 2; ++j) {
    int rr = r + j*32;
    int orow = n0 + rr;
    if (perm) {
      int s5 = (orow >> 5) & 3;
      s5 = (s5 == 1) ? 2 : (s5 == 2) ? 1 : s5;
      orow = (orow & ~127) | (s5 << 5) | (orow & 31);
    }
    short8 v;
    #pragma unroll
    for (int e = 0; e < 8; ++e) v[e] = (short)tl[c8 + e][rr];
    *(short8*)(out + (size_t)orow*HID + k0 + c8) = v;
  }
}

// ============ shared GEMM helpers (swizzle proven: bank-conflict 0, rounds 2-13) ============

static __device__ __forceinline__ int swz_scol(int lane) {
  return (((lane & 7) * 16) ^ (((lane >> 3) & 7) << 4)) >> 1;   // swizzled src col (ushorts)
}

static __device__ __forceinline__ void rd_af(const unsigned short* Ah, bf16x8 (&afr)[4][2],
                                             int wm, int lr, int col0, int axor) {
  #pragma unroll
  for (int mi = 0; mi < 4; ++mi) {
    const unsigned short* rp = Ah + (wm*64 + mi*16 + lr) * 64;
    #pragma unroll
    for (int kk = 0; kk < 2; ++kk)
      afr[mi][kk] = *(const bf16x8*)(rp + (((kk*64 + col0) ^ axor) >> 1));
  }
}
static __device__ __forceinline__ void rd_bf(const unsigned short* Bh, bf16x8 (&bfr)[2][2],
                                             int wn, int lr, int col0, int axor) {
  #pragma unroll
  for (int ni = 0; ni < 2; ++ni) {
    const unsigned short* rp = Bh + (wn*32 + ni*16 + lr) * 64;
    #pragma unroll
    for (int kk = 0; kk < 2; ++kk)
      bfr[ni][kk] = *(const bf16x8*)(rp + (((kk*64 + col0) ^ axor) >> 1));
  }
}
static __device__ __forceinline__ void mfma16(const bf16x8 (&afr)[4][2], const bf16x8 (&bfr)[2][2],
                                              f32x4 (&ac)[4][2]) {
  #pragma unroll
  for (int kk = 0; kk < 2; ++kk)
    #pragma unroll
    for (int mi = 0; mi < 4; ++mi)
      #pragma unroll
      for (int ni = 0; ni < 2; ++ni)
        ac[mi][ni] = __builtin_amdgcn_mfma_f32_16x16x32_bf16(afr[mi][kk], bfr[ni][kk], ac[mi][ni], 0, 0, 0);
}

// ================= 128x256-tile GEMM, 3-deep pipeline, compiler-scheduled body =========
// Restored round-12 structure (round-13 lesson: the lockstep 2-phase variant regressed —
// the phase template only pays at 256^2 tile where read:MFMA = 0.375; at 32 MFMA/tile the
// single-sync compiler-scheduled region is strictly better).

struct SPtrs { const unsigned short* p[6]; };

static __device__ __forceinline__ void build_ptrs(SPtrs& sp,
    const unsigned short* Ap, const unsigned short* Bp, int Ksz, int sh,
    int m0, int n0, const unsigned short* zpg, int tid) {
  int lane = tid & 63;
  int scol = swz_scol(lane);
  #pragma unroll
  for (int j = 0; j < 2; ++j) {
    int row = ((tid >> 6) * 2 + j) * 8 + (lane >> 3);               // 0..127
    int gr = m0 + row;
    sp.p[j]     = (sh && ((gr & (S - 1)) == 0)) ? (zpg + scol)
                                                : (Ap + (size_t)(gr - sh)*Ksz + scol);
    sp.p[2 + j] = Bp + (size_t)(n0 + row)*Ksz + scol;
    sp.p[4 + j] = Bp + (size_t)(n0 + 128 + row)*Ksz + scol;
  }
}

static __device__ __forceinline__ void stage6(unsigned short* buf, SPtrs& sp, int tid) {
  int c0 = (tid >> 6) * 1024;            // ushort offset of this wave's 2-chunk pair
  gload_lds16(sp.p[0], buf + c0);
  gload_lds16(sp.p[1], buf + c0 + 512);
  gload_lds16(sp.p[2], buf + 8192  + c0);
  gload_lds16(sp.p[3], buf + 8192  + c0 + 512);
  gload_lds16(sp.p[4], buf + 16384 + c0);
  gload_lds16(sp.p[5], buf + 16384 + c0 + 512);
  #pragma unroll
  for (int i = 0; i < 6; ++i) sp.p[i] += 64;
}

static __device__ __forceinline__ void gemm8_core(
    unsigned short* lds,
    const unsigned short* __restrict__ A1, const unsigned short* __restrict__ A2,
    const unsigned short* __restrict__ B1, const unsigned short* __restrict__ B2,
    int K1, int K2,
    const unsigned short* __restrict__ bias, const unsigned short* __restrict__ resid,
    void* __restrict__ Cout, int outmode, int N, int m0, int n0,
    int a1shift, const unsigned short* __restrict__ zrow) {
  int tid = threadIdx.x;
  int lane = tid & 63, w = tid >> 6;
  int wm = w >> 2, wn = w & 3;
  int lr = lane & 15, g = lane >> 4;
  int col0 = g * 16;
  int axor = (lr & 7) << 4;
  int nk1 = K1 >> 6;
  int nk = (K1 + K2) >> 6;
  f32x4 acc[2][4][2] = {};
  bf16x8 afr[4][2], bfr0[2][2], bfr1[2][2];

  unsigned short* buf0 = lds;            // each buf: A @0, B0 @8192, B1 @16384 (ushorts)
  unsigned short* buf1 = lds + 24576;
  unsigned short* buf2 = lds + 49152;

  SPtrs sp;
  build_ptrs(sp, A1, B1, K1, a1shift, m0, n0, zrow, tid);

  stage6(buf0, sp, tid);
  stage6(buf1, sp, tid);

  unsigned short* cur = buf0;
  unsigned short* nx1 = buf1;
  unsigned short* nx2 = buf2;
  for (int t = 0; t < nk; ++t) {
    if (t < nk - 1) asm volatile("s_waitcnt vmcnt(6)" ::: "memory");
    else            asm volatile("s_waitcnt vmcnt(0)" ::: "memory");
    __builtin_amdgcn_s_barrier();
    asm volatile("" ::: "memory");

    rd_af(cur,         afr,  wm, lr, col0, axor);
    rd_bf(cur + 8192,  bfr0, wn, lr, col0, axor);
    rd_bf(cur + 16384, bfr1, wn, lr, col0, axor);
    if (t + 2 < nk) {
      if (t + 2 == nk1) build_ptrs(sp, A2, B2, K2, 0, m0, n0, zrow, tid);
      stage6(nx2, sp, tid);
    }
    __builtin_amdgcn_s_setprio(1);
    mfma16(afr, bfr0, acc[0]);
    mfma16(afr, bfr1, acc[1]);
    __builtin_amdgcn_s_setprio(0);

    unsigned short* tmp = cur; cur = nx1; nx1 = nx2; nx2 = tmp;
  }

  #pragma unroll
  for (int qn = 0; qn < 2; ++qn)
    #pragma unroll
    for (int mi = 0; mi < 4; ++mi) {
      int row0 = m0 + wm*64 + mi*16 + g*4;
      #pragma unroll
      for (int ni = 0; ni < 2; ++ni) {
        int col = n0 + qn*128 + wn*32 + ni*16 + lr;
        float bv = bias ? b2f(bias[col]) : 0.f;
        f32x4 a = acc[qn][mi][ni];
        if (outmode == 3) {
          int bb = row0 >> 11;
          int s0 = row0 & (S - 1);
          size_t base = ((size_t)bb * HID + col) * S + s0;
          ushort4v pk;
          #pragma unroll
          for (int j = 0; j < 4; ++j) pk[j] = f2b(a[j]);
          *(ushort4v*)((unsigned short*)Cout + base) = pk;
        } else {
          #pragma unroll
          for (int j = 0; j < 4; ++j) {
            size_t idx = (size_t)(row0 + j) * N + col;
            float v = a[j] + bv;
            if (resid) v += b2f(resid[idx]);
            if (outmode == 1) ((float*)Cout)[idx] = v;
            else ((unsigned short*)Cout)[idx] = f2b(v);
          }
        }
      }
    }
}

template<int SHIFT>
__launch_bounds__(512, 1)
__global__ void gemm8_bt(const unsigned short* __restrict__ A1,
                         const unsigned short* __restrict__ A2,
                         const unsigned short* __restrict__ B1,
                         const unsigned short* __restrict__ B2,
                         int K1, int K2,
                         const unsigned short* __restrict__ bias,
                         const unsigned short* __restrict__ resid,
                         void* __restrict__ Cout, int outmode, int N,
                         const unsigned short* __restrict__ zrow) {
  __shared__ __align__(16) unsigned short lds[73728];   // 144 KiB, 3 bufs
  gemm8_core(lds, A1, A2, B1, B2, K1, K2, bias, resid, Cout, outmode, N,
             blockIdx.x*128, blockIdx.y*256, SHIFT, zrow);
}

// two independent GEMM jobs in one dispatch; heavy job MUST be j0 (dispatched first)
struct GemmJob {
  const unsigned short *A1, *A2, *B1, *B2;
  int K1, K2;
  const unsigned short *bias;
  void* Cout; int outmode; int N; int nby; int a1shift;
};

__launch_bounds__(512, 1)
__global__ void gemm8_dual(GemmJob j0, GemmJob j1, const unsigned short* __restrict__ zrow) {
  __shared__ __align__(16) unsigned short lds[73728];
  int by = blockIdx.y;
  GemmJob j;
  if (by < j0.nby) { j = j0; } else { j = j1; by -= j0.nby; }
  gemm8_core(lds, j.A1, j.A2, j.B1, j.B2, j.K1, j.K2, j.bias, nullptr,
             j.Cout, j.outmode, j.N, blockIdx.x*128, by*256, j.a1shift, zrow);
}

// ================= 256x256-tile 4-phase GEMM (qk projection; validated round 12) ============
// + T1 XCD-aware block swizzle (nwg=256, 256%8==0 -> simple bijective remap).
struct HPtr { const unsigned short* p0; const unsigned short* p1; };
static __device__ __forceinline__ void hinit(HPtr& h, const unsigned short* base,
                                             int row0, int tid) {
  int lane = tid & 63;
  int scol = swz_scol(lane);
  int r0 = ((tid >> 6) * 2) * 8 + (lane >> 3);
  h.p0 = base + (size_t)(row0 + r0) * 2048 + scol;
  h.p1 = base + (size_t)(row0 + r0 + 8) * 2048 + scol;
}
static __device__ __forceinline__ void hstage(unsigned short* slot, HPtr& h, int tid) {
  int c0 = (tid >> 6) * 1024;
  gload_lds16(h.p0, slot + c0);
  gload_lds16(h.p1, slot + c0 + 512);
  h.p0 += 64; h.p1 += 64;
}

__launch_bounds__(512, 1)
__global__ void gemm256_bt(const unsigned short* __restrict__ A,
                           const unsigned short* __restrict__ B,
                           unsigned short* __restrict__ C, int N) {
  __shared__ __align__(16) unsigned short lds[65536];   // 128 KiB
  int tid = threadIdx.x;
  int lane = tid & 63, w = tid >> 6;
  int wm = w >> 2, wn = w & 3;
  int lr = lane & 15, g = lane >> 4;
  int col0 = g * 16;
  int axor = (lr & 7) << 4;
  // T1 XCD swizzle: consecutive swizzled ids land on the same XCD's L2
  int nwg = gridDim.x * gridDim.y;
  int lin = blockIdx.y * gridDim.x + blockIdx.x;
  int cpx = nwg >> 3;
  int swz = (lin & 7) * cpx + (lin >> 3);
  int m0 = (swz % gridDim.x) * 256, n0 = (swz / gridDim.x) * 256;
  const int nk = 2048 >> 6;   // 32 K-tiles
  f32x4 acc[2][2][4][2] = {};           // [qm][qn][mi][ni]
  bf16x8 af[4][2], bf0[2][2], bf1[2][2];

  HPtr hA0, hA1, hB0, hB1;
  hinit(hA0, A, m0,       tid);
  hinit(hA1, A, m0 + 128, tid);
  hinit(hB0, B, n0,       tid);
  hinit(hB1, B, n0 + 128, tid);

  // buf b (ushorts): A0 @ b*32768, A1 @ +8192, B0 @ +16384, B1 @ +24576
  hstage(lds + 0,             hA0, tid);
  hstage(lds + 8192,          hA1, tid);
  hstage(lds + 16384,         hB0, tid);
  hstage(lds + 24576,         hB1, tid);
  hstage(lds + 32768 + 0,     hA0, tid);
  hstage(lds + 32768 + 16384, hB0, tid);
  hstage(lds + 32768 + 24576, hB1, tid);
  asm volatile("s_waitcnt vmcnt(6)" ::: "memory");   // tile0 landed; tile1's 3 halves in flight
  __builtin_amdgcn_s_barrier();
  asm volatile("" ::: "memory");

  for (int t = 0; t < nk; ++t) {
    unsigned short* cur = lds + (t & 1) * 32768;
    unsigned short* oth = lds + ((t & 1) ^ 1) * 32768;

    // ---- P1 (qm0,qn0): rd A0(8)+B0(4) ; stage A1(t+1) -> oth ----
    rd_af(cur,         af,  wm, lr, col0, axor);
    rd_bf(cur + 16384, bf0, wn, lr, col0, axor);
    if (t + 1 < nk) hstage(oth + 8192, hA1, tid);
    __builtin_amdgcn_s_barrier();
    asm volatile("s_waitcnt lgkmcnt(0)" ::: "memory");
    __builtin_amdgcn_s_setprio(1);
    mfma16(af, bf0, acc[0][0]);
    __builtin_amdgcn_s_setprio(0);
    __builtin_amdgcn_s_barrier();

    // ---- P2 (qm0,qn1): rd B1(4) (A regs reused) ; stage A0(t+2) -> cur ----
    rd_bf(cur + 24576, bf1, wn, lr, col0, axor);
    if (t + 2 < nk) hstage(cur, hA0, tid);
    __builtin_amdgcn_s_barrier();
    asm volatile("s_waitcnt lgkmcnt(0)" ::: "memory");
    __builtin_amdgcn_s_setprio(1);
    mfma16(af, bf1, acc[0][1]);
    __builtin_amdgcn_s_setprio(0);
    __builtin_amdgcn_s_barrier();

    // ---- P3 (qm1,qn1): rd A1(8) (B1 regs reused) ; stage B0(t+2) -> cur ----
    rd_af(cur + 8192, af, wm, lr, col0, axor);
    if (t + 2 < nk) hstage(cur + 16384, hB0, tid);
    __builtin_amdgcn_s_barrier();
    asm volatile("s_waitcnt lgkmcnt(0)" ::: "memory");
    __builtin_amdgcn_s_setprio(1);
    mfma16(af, bf1, acc[1][1]);
    __builtin_amdgcn_s_setprio(0);
    __builtin_amdgcn_s_barrier();

    // ---- P4 (qm1,qn0): all regs reused ; stage B1(t+2) -> cur ; counted vmcnt ----
    if (t + 2 < nk) hstage(cur + 24576, hB1, tid);
    __builtin_amdgcn_s_barrier();
    asm volatile("s_waitcnt lgkmcnt(0)" ::: "memory");
    __builtin_amdgcn_s_setprio(1);
    mfma16(af, bf0, acc[1][0]);
    __builtin_amdgcn_s_setprio(0);
    if (t + 2 < nk) asm volatile("s_waitcnt vmcnt(6)" ::: "memory");
    else            asm volatile("s_waitcnt vmcnt(0)" ::: "memory");
    __builtin_amdgcn_s_barrier();
    asm volatile("" ::: "memory");
  }

  // ---- epilogue: bf16 [row][N] ----
  #pragma unroll
  for (int qm = 0; qm < 2; ++qm)
    #pragma unroll
    for (int mi = 0; mi < 4; ++mi) {
      int row0 = m0 + qm*128 + wm*64 + mi*16 + g*4;
      #pragma unroll
      for (int qn = 0; qn < 2; ++qn)
        #pragma unroll
        for (int ni = 0; ni < 2; ++ni) {
          int col = n0 + qn*128 + wn*32 + ni*16 + lr;
          f32x4 a = acc[qm][qn][mi][ni];
          #pragma unroll
          for (int j = 0; j < 4; ++j)
            C[(size_t)(row0 + j) * N + col] = f2b(a[j]);
        }
    }
}

// ---------------- RMSNorm over bf16 rows -> bf16 (single-pass, short8) ----------------
__global__ void rmsnorm_rows(const unsigned short* __restrict__ y,
                             const unsigned short* __restrict__ w,
                             unsigned short* __restrict__ out) {
  int r = blockIdx.x;
  int c8 = threadIdx.x * 8;               // 256 threads x 8 = 2048
  const unsigned short* yr = y + (size_t)r * HID;
  short8 v = *(const short8*)(yr + c8);
  float f[8];
  float ss = 0.f;
  #pragma unroll
  for (int e = 0; e < 8; ++e) { f[e] = b2f((unsigned short)v[e]); ss += f[e]*f[e]; }
  #pragma unroll
  for (int o = 32; o; o >>= 1) ss += __shfl_xor(ss, o);
  __shared__ float red[4];
  if ((threadIdx.x & 63) == 0) red[threadIdx.x >> 6] = ss;
  __syncthreads();
  float tot = red[0] + red[1] + red[2] + red[3];
  float scale = rsqrtf(tot / (float)HID + 1e-6f);
  short8 wv = *(const short8*)(w + c8);
  short8 o8;
  #pragma unroll
  for (int e = 0; e < 8; ++e) o8[e] = (short)f2b(f[e] * scale * b2f((unsigned short)wv[e]));
  *(short8*)(out + (size_t)r*HID + c8) = o8;
}

// ---------------- RoPE from fused qk output [r][4096]; head h = cols h*256..+255 ----------------
__global__ void rope_rearrange(const unsigned short* __restrict__ qkf,
                               const float* __restrict__ ctab, const float* __restrict__ stab,
                               unsigned short* __restrict__ qr, unsigned short* __restrict__ kr) {
  int r = blockIdx.x;
  int t = r & (S - 1);
  int h = threadIdx.x >> 4;
  int i4 = (threadIdx.x & 15) * 4;
  int pc = (i4 & 31) + ((i4 >> 5) << 6);    // permuted col of x1 for elems i4..i4+3 (same 32-block)
  const unsigned short* qk = qkf + (size_t)r * (2*HID) + h * 256;
  f32x4 c = *(const f32x4*)(ctab + t*64 + i4);
  f32x4 s = *(const f32x4*)(stab + t*64 + i4);
  ushort4v q1 = *(const ushort4v*)(qk + pc);
  ushort4v q2 = *(const ushort4v*)(qk + pc + 32);
  ushort4v k1 = *(const ushort4v*)(qk + 128 + pc);
  ushort4v k2 = *(const ushort4v*)(qk + 128 + pc + 32);
  size_t o = (size_t)r * HID + (size_t)h * HD;
  const float SC = 0.08838834764831845f * 1.44269504088896340f;  // 1/sqrt(128) * log2(e)
  ushort4v oq1, oq2, ok1, ok2;
  #pragma unroll
  for (int e = 0; e < 4; ++e) {
    float a = b2f(q1[e]), b = b2f(q2[e]);
    float x = b2f(k1[e]), y = b2f(k2[e]);
    oq1[e] = f2b((a*c[e] - b*s[e]) * SC);
    oq2[e] = f2b((b*c[e] + a*s[e]) * SC);
    ok1[e] = f2b(x*c[e] - y*s[e]);
    ok2[e] = f2b(y*c[e] + x*s[e]);
  }
  *(ushort4v*)(qr + o + i4)      = oq1;
  *(ushort4v*)(qr + o + 64 + i4) = oq2;
  *(ushort4v*)(kr + o + i4)      = ok1;
  *(ushort4v*)(kr + o + 64 + i4) = ok2;
}

// ---------------- MFMA causal flash attention (16x16, DMA-staged, balanced pairs) ----------------
#define KT 64

static __device__ __forceinline__ void attn_pass(
    int qt, int b, int h, unsigned short* lds,
    const unsigned short* __restrict__ Qr, const unsigned short* __restrict__ Kr,
    const unsigned short* __restrict__ Vt, unsigned short* __restrict__ Out) {
  int tid = threadIdx.x, lane = tid & 63, w = tid >> 6;
  int q0 = qt * 64;
  size_t bS = (size_t)b * S;
  size_t ho = (size_t)h * HD;
  int lr = lane & 15, g = lane >> 4;
  int rsw = (lane & 7) << 3;                       // read-side swizzle (ushort units)
  // all waves past previous pass's LDS reads before re-staging the shared buffers
  __syncthreads();
  bf16x8 bq[4];
  {
    int qrow = q0 + w*16 + lr;
    const unsigned short* qp = Qr + (bS + qrow)*HID + ho + g*8;
    #pragma unroll
    for (int kk = 0; kk < 4; ++kk) bq[kk] = *(const bf16x8*)(qp + kk*32);
  }
  // staging pointers (pre-swizzled source cols; advance per tile)
  const unsigned short* kp[4];
  const unsigned short* vp[4];
  #pragma unroll
  for (int j = 0; j < 4; ++j) {
    int c = w*4 + j;                       // chunk 0..15 (1KB each)
    int rk = c*4 + (lane >> 4);            // K row 0..63
    int sck = ((lane & 15) * 8) ^ ((rk & 7) << 3);
    kp[j] = Kr + (bS + rk)*HID + ho + sck;
    int rv = c*8 + (lane >> 3);            // V row (d) 0..127
    int scv = ((lane & 7) * 8) ^ ((rv & 7) << 3);
    vp[j] = Vt + ((size_t)b*HID + ho + rv)*S + scv;
  }
  int cdst = (w*4) * 512;                  // this wave's chunk-group dest (ushorts)
  unsigned short* curK = lds;
  unsigned short* curV = lds + 8192;
  unsigned short* nxtK = lds + 16384;
  unsigned short* nxtV = lds + 24576;
  #pragma unroll
  for (int j = 0; j < 4; ++j) {            // prologue: tile 0 -> cur
    gload_lds16(kp[j], curK + cdst + j*512);
    gload_lds16(vp[j], curV + cdst + j*512);
    kp[j] += (size_t)KT * HID;
    vp[j] += KT;
  }
  f32x4 o[8] = {};                 // O: col(d)=lr+16*ni, row(q_local)=4g+reg
  float m = -1e30f, l = 0.f;
  unsigned short* PlW = lds + 32768 + w*1024;
  int ntiles = qt + 1;
  for (int kt = 0; kt < ntiles; ++kt) {
    // ---- single sync point: own DMA landed, then block-wide barrier ----
    asm volatile("s_waitcnt vmcnt(0)" ::: "memory");
    __builtin_amdgcn_s_barrier();
    asm volatile("" ::: "memory");
    if (kt + 1 < ntiles) {                 // issue next-tile DMA into the other buffer
      #pragma unroll
      for (int j = 0; j < 4; ++j) {
        gload_lds16(kp[j], nxtK + cdst + j*512);
        gload_lds16(vp[j], nxtV + cdst + j*512);
        kp[j] += (size_t)KT * HID;
        vp[j] += KT;
      }
    }
    f32x4 st[4] = {};
    __builtin_amdgcn_s_setprio(1);
    #pragma unroll
    for (int kk = 0; kk < 4; ++kk) {
      #pragma unroll
      for (int mi = 0; mi < 4; ++mi) {
        bf16x8 a = *(const bf16x8*)(&curK[(mi*16 + lr)*128 + ((kk*32 + g*8) ^ rsw)]);
        st[mi] = __builtin_amdgcn_mfma_f32_16x16x32_bf16(a, bq[kk], st[mi], 0, 0, 0);
      }
    }
    __builtin_amdgcn_s_setprio(0);
    bool lastt = (kt == ntiles - 1);
    float tm = -1e30f;
    #pragma unroll
    for (int mi = 0; mi < 4; ++mi)
      #pragma unroll
      for (int r = 0; r < 4; ++r) {
        float v = st[mi][r];
        if (lastt && (mi*16 + 4*g + r) > (w*16 + lr)) v = -1e30f;
        st[mi][r] = v;
        tm = fmaxf(tm, v);
      }
    tm = fmaxf(tm, __shfl_xor(tm, 16));
    tm = fmaxf(tm, __shfl_xor(tm, 32));
    if (!__all(tm - m <= 11.5f)) {
      float mn = fmaxf(m, tm);
      float sc = exp2f(m - mn);
      float s0 = __shfl(sc, 4*g+0), s1 = __shfl(sc, 4*g+1);
      float s2 = __shfl(sc, 4*g+2), s3 = __shfl(sc, 4*g+3);
      #pragma unroll
      for (int ni = 0; ni < 8; ++ni) {
        o[ni][0] *= s0; o[ni][1] *= s1; o[ni][2] *= s2; o[ni][3] *= s3;
      }
      l *= sc;
      m = mn;
    }
    float ts = 0.f;
    __bf16 pbf[4][4];
    #pragma unroll
    for (int mi = 0; mi < 4; ++mi)
      #pragma unroll
      for (int r = 0; r < 4; ++r) {
        float p = exp2f(st[mi][r] - m);
        ts += p;
        pbf[mi][r] = (__bf16)p;
      }
    ts += __shfl_xor(ts, 16);
    ts += __shfl_xor(ts, 32);
    l += ts;
    #pragma unroll
    for (int mi = 0; mi < 4; ++mi) {
      bf16x4 pk = { pbf[mi][0], pbf[mi][1], pbf[mi][2], pbf[mi][3] };
      *(bf16x4*)(&PlW[lr*64 + ((mi*16 + 4*g) ^ rsw)]) = pk;
    }
    asm volatile("" ::: "memory");   // compile-time fence: P stores before P reads
    __builtin_amdgcn_s_setprio(1);
    #pragma unroll
    for (int kk = 0; kk < 2; ++kk) {
      int pc = (kk*32 + g*8) ^ rsw;
      bf16x8 a = *(const bf16x8*)(&PlW[lr*64 + pc]);
      #pragma unroll
      for (int ni = 0; ni < 8; ++ni) {
        bf16x8 bv = *(const bf16x8*)(&curV[(ni*16 + lr)*64 + pc]);
        o[ni] = __builtin_amdgcn_mfma_f32_16x16x32_bf16(a, bv, o[ni], 0, 0, 0);
      }
    }
    __builtin_amdgcn_s_setprio(0);
    unsigned short* t0 = curK; curK = nxtK; nxtK = t0;
    unsigned short* t1 = curV; curV = nxtV; nxtV = t1;
  }
  float l0 = __shfl(l, 4*g+0), l1 = __shfl(l, 4*g+1);
  float l2 = __shfl(l, 4*g+2), l3 = __shfl(l, 4*g+3);
  float i0 = 1.f/l0, i1 = 1.f/l1, i2 = 1.f/l2, i3 = 1.f/l3;
  int rbase = q0 + w*16 + 4*g;
  #pragma unroll
  for (int ni = 0; ni < 8; ++ni) {
    size_t cbase = ho + ni*16 + lr;
    Out[(bS + rbase + 0)*HID + cbase] = f2b(o[ni][0]*i0);
    Out[(bS + rbase + 1)*HID + cbase] = f2b(o[ni][1]*i1);
    Out[(bS + rbase + 2)*HID + cbase] = f2b(o[ni][2]*i2);
    Out[(bS + rbase + 3)*HID + cbase] = f2b(o[ni][3]*i3);
  }
}

__launch_bounds__(256, 2)
__global__ void attn_mfma(const unsigned short* __restrict__ Qr,
                          const unsigned short* __restrict__ Kr,
                          const unsigned short* __restrict__ Vt,
                          unsigned short* __restrict__ Out) {
  // [0,8192) K0 | [8192,16384) V0 | [16384,24576) K1 | [24576,32768) V1 | [32768,36864) P
  __shared__ __align__(16) unsigned short lds[36864];
  int bh = blockIdx.x;
  int b = bh >> 4, h = bh & 15;
  int by = blockIdx.y;                       // 0..15
  attn_pass(31 - by, b, h, lds, Qr, Kr, Vt, Out);   // heavy tile
  attn_pass(by,      b, h, lds, Qr, Kr, Vt, Out);   // light tile; total = 33 KV-tiles/block
}

extern "C" void kernel_launch(void* const* d_in, const int* in_sizes, int n_in,
                              void* d_out, int out_size, void* d_ws, size_t ws_size,
                              hipStream_t stream) {
  const float* x_raw   = (const float*)d_in[0];
  const int* positions = (const int*)d_in[1];
  const float* wq_raw  = (const float*)d_in[2];
  const float* wk_raw  = (const float*)d_in[3];
  const float* wv_raw  = (const float*)d_in[4];
  const float* wo_raw  = (const float*)d_in[5];
  const float* c1w_raw = (const float*)d_in[6];
  const float* c1b_raw = (const float*)d_in[7];
  const float* c2w_raw = (const float*)d_in[8];
  const float* c2b_raw = (const float*)d_in[9];
  const float* rms_raw = (const float*)d_in[10];

  const size_t WS_NEEDED = 140000000;
  if (ws_size < WS_NEEDED) {
    long n = (long)out_size;
    fill_debug<<<dim3((unsigned)((n + 255) / 256)), dim3(256), 0, stream>>>((unsigned short*)d_out, n);
    return;
  }

  char* ws = (char*)d_ws;
  size_t off = 0;
  auto alloc = [&](size_t bytes) { char* p = ws + off; off += (bytes + 255) & ~(size_t)255; return p; };
  float* ctab          = (float*)alloc((size_t)S*64*4);
  float* stab          = (float*)alloc((size_t)S*64*4);
  unsigned short* wqkt = (unsigned short*)alloc((size_t)2*HID*HID*2);  // [wq^T ; wk^T], rope-permuted
  unsigned short* wvt  = (unsigned short*)alloc((size_t)HID*HID*2);
  unsigned short* wot  = (unsigned short*)alloc((size_t)HID*HID*2);
  unsigned short* w1t0 = (unsigned short*)alloc((size_t)1024*HID*2);
  unsigned short* w1t1 = (unsigned short*)alloc((size_t)1024*HID*2);
  unsigned short* w2t0 = (unsigned short*)alloc((size_t)HID*1024*2);
  unsigned short* w2t1 = (unsigned short*)alloc((size_t)HID*1024*2);
  unsigned short* xb   = (unsigned short*)alloc((size_t)ROWS*HID*2);   // reused as kr after conv2
  unsigned short* qrb  = (unsigned short*)alloc((size_t)ROWS*HID*2);   // q rotated
  unsigned short* o1   = (unsigned short*)alloc((size_t)ROWS*1024*2);
  unsigned short* yb   = (unsigned short*)alloc((size_t)ROWS*HID*2);   // reused as attn out
  unsigned short* hg   = (unsigned short*)alloc((size_t)ROWS*HID*2);
  unsigned short* qkf  = (unsigned short*)alloc((size_t)ROWS*2*HID*2); // fused q|k output
  unsigned short* vtg  = (unsigned short*)alloc((size_t)BATCH*HID*S*2);
  unsigned short* c1bb = (unsigned short*)alloc(1024*2);
  unsigned short* c2bb = (unsigned short*)alloc(2048*2);
  unsigned short* rmswb= (unsigned short*)alloc(2048*2);
  unsigned short* zpg  = (unsigned short*)alloc(8192*2);               // zero page (kk-advancing)
  unsigned short* krr  = xb;     // xb dead after conv2 (resid read)
  unsigned short* attn = yb;     // yb dead after rmsnorm

  dim3 b256(256);
  dim3 b512(512);
  prep_all<<<dim3(4096, 4), b256, 0, stream>>>(c1w_raw, c2w_raw, x_raw, positions,
                                               c1b_raw, c2b_raw, rms_raw,
                                               w1t0, w1t1, w2t0, w2t1, xb,
                                               ctab, stab, c1bb, c2bb, rmswb, zpg);
  transpose4<<<dim3(32,32,4), b256, 0, stream>>>(wq_raw, wk_raw, wv_raw, wo_raw,
                                                 wqkt, wqkt + (size_t)HID*HID, wvt, wot);
  // merged dispatch (128x256, 3-deep): conv1 (N=1024, K=4096, shifted) [HEAVY j0]
  //                                  + V-projection (N=2048, K=2048, Vt layout)
  {
    GemmJob j0 = { xb, xb, w1t0, w1t1, HID, HID, c1bb, o1, 0, 1024, 4, 1 };
    GemmJob j1 = { xb, xb, wvt,  wvt,  HID, 0,   nullptr, vtg, 3, HID, 8, 0 };
    gemm8_dual<<<dim3(ROWS/128, 12), b512, 0, stream>>>(j0, j1, zpg);
  }
  // conv2 + resid: yb = shift(o1)@W2_0^T + o1@W2_1^T + b2 + xb    [4096 x 2048]
  gemm8_bt<1><<<dim3(ROWS/128, HID/256), b512, 0, stream>>>(o1, o1, w2t0, w2t1, 1024, 1024, c2bb, xb, yb, 0, HID, zpg);
  rmsnorm_rows<<<dim3(ROWS), b256, 0, stream>>>(yb, rmswb, hg);
  // fused q|k projection (256x256 4-phase + XCD swizzle): qkf = hg @ [wq|wk]  [4096x4096]
  gemm256_bt<<<dim3(ROWS/256, (2*HID)/256), b512, 0, stream>>>(hg, wqkt, qkf, 2*HID);
  rope_rearrange<<<dim3(ROWS), b256, 0, stream>>>(qkf, ctab, stab, qrb, krr);
  attn_mfma<<<dim3(BATCH*HEADS, 16), b256, 0, stream>>>(qrb, krr, vtg, attn);
  // output projection: d_out = attn @ wo^T   [4096 x 2048], f32 out
  gemm8_bt<0><<<dim3(ROWS/128, HID/256), b512, 0, stream>>>(attn, attn, wot, wot, HID, 0, nullptr, nullptr, d_out, 1, HID, nullptr);
}

// Round 15
// 348.784 us; speedup vs baseline: 1.0696x; 1.0151x over previous
//
#include <hip/hip_runtime.h>

#define HID 2048
#define HEADS 16
#define HD 128
#define BATCH 2
#define S 2048
#define ROWS (BATCH*S)

typedef short short8 __attribute__((ext_vector_type(8)));
typedef unsigned short ushort4v __attribute__((ext_vector_type(4)));
typedef unsigned short ushort2v __attribute__((ext_vector_type(2)));
typedef float f32x4 __attribute__((ext_vector_type(4)));
typedef __bf16 bf16x8 __attribute__((ext_vector_type(8)));
typedef __bf16 bf16x4 __attribute__((ext_vector_type(4)));

static __device__ __forceinline__ float b2f(unsigned short u) {
  union { float f; unsigned int i; } v; v.i = ((unsigned int)u) << 16; return v.f;
}
static __device__ __forceinline__ unsigned short f2b(float f) {
  union { float f; unsigned int i; } v; v.f = f;
  unsigned int u = v.i;
  unsigned int r = ((u >> 16) & 1u) + 0x7fffu;
  return (unsigned short)((u + r) >> 16);
}

// async global->LDS, 16B per lane; LDS dest = wave-uniform base + lane*16 (global src is per-lane)
static __device__ __forceinline__ void gload_lds16(const unsigned short* g, unsigned short* l) {
  __builtin_amdgcn_global_load_lds(
      (const __attribute__((address_space(1))) unsigned int*)(const void*)g,
      (__attribute__((address_space(3))) unsigned int*)(void*)l,
      16, 0, 0);
}

// ---------------- debug fill (ws-size canary) ----------------
__global__ void fill_debug(unsigned short* __restrict__ out, long n) {
  long i = (long)blockIdx.x * blockDim.x + threadIdx.x;
  if (i < n) out[i] = 0x447A;  // bf16 1000.0
}

// ---------------- fused prep: conv repacks + x convert + rope tables + small converts ----------
__global__ void prep_all(const float* __restrict__ c1w, const float* __restrict__ c2w,
                         const float* __restrict__ x, const int* __restrict__ positions,
                         const float* __restrict__ c1b, const float* __restrict__ c2b,
                         const float* __restrict__ rmsw,
                         unsigned short* __restrict__ w1t0, unsigned short* __restrict__ w1t1,
                         unsigned short* __restrict__ w2t0, unsigned short* __restrict__ w2t1,
                         unsigned short* __restrict__ xb,
                         float* __restrict__ ctab, float* __restrict__ stab,
                         unsigned short* __restrict__ c1bb, unsigned short* __restrict__ c2bb,
                         unsigned short* __restrict__ rmswb, unsigned short* __restrict__ zpg) {
  int job = blockIdx.y;
  if (job == 0 || job == 1) {
    const float* w = (job == 0) ? c1w : c2w;
    unsigned short* o0 = (job == 0) ? w1t0 : w2t0;
    unsigned short* o1 = (job == 0) ? w1t1 : w2t1;
    long i = (long)blockIdx.x * 256 + threadIdx.x;
    f32x4 v = *(const f32x4*)(w + i*4);
    ushort2v a = { f2b(v[0]), f2b(v[2]) };
    ushort2v b = { f2b(v[1]), f2b(v[3]) };
    *(ushort2v*)(o0 + i*2) = a;
    *(ushort2v*)(o1 + i*2) = b;
  } else if (job == 2) {
    long i = (long)blockIdx.x * 256 + threadIdx.x;
    #pragma unroll
    for (int rep = 0; rep < 2; ++rep) {
      long idx = i + (long)rep * 1048576L;
      f32x4 v = *(const f32x4*)(x + idx*4);
      ushort4v o = { f2b(v[0]), f2b(v[1]), f2b(v[2]), f2b(v[3]) };
      *(ushort4v*)(xb + idx*4) = o;
    }
  } else {
    int bx = blockIdx.x;
    if (bx < 512) {
      int t = bx * 4 + (threadIdx.x >> 6);
      int i = threadIdx.x & 63;
      float pos = (float)positions[t];
      float inv = powf(10000.0f, -(float)i / 64.0f);
      float ang = pos * inv;
      float sv, cv;
      sincosf(ang, &sv, &cv);
      ctab[t*64 + i] = cv;
      stab[t*64 + i] = sv;
    } else if (bx < 544) {
      int i = (bx - 512) * 256 + threadIdx.x;   // 0..8191
      if (i < 1024) c1bb[i] = f2b(c1b[i]);
      if (i < 2048) { c2bb[i] = f2b(c2b[i]); rmswb[i] = f2b(rmsw[i]); }
      zpg[i] = 0;                               // 8192-ushort zero page (kk-advancing reads)
    }
  }
}

// ---------------- 4x 2048x2048 transpose fp32 [K,N] -> bf16 [N,K], one dispatch ----------------
__global__ void transpose4(const float* __restrict__ s0, const float* __restrict__ s1,
                           const float* __restrict__ s2, const float* __restrict__ s3,
                           unsigned short* __restrict__ d0, unsigned short* __restrict__ d1,
                           unsigned short* __restrict__ d2, unsigned short* __restrict__ d3) {
  __shared__ unsigned short tl[64][73];
  const float* in; unsigned short* out; int perm;
  switch (blockIdx.z) {
    case 0:  in = s0; out = d0; perm = 1; break;
    case 1:  in = s1; out = d1; perm = 1; break;
    case 2:  in = s2; out = d2; perm = 0; break;
    default: in = s3; out = d3; perm = 0; break;
  }
  int n0 = blockIdx.x * 64, k0 = blockIdx.y * 64;
  int tid = threadIdx.x;
  int r = tid >> 3, c8 = (tid & 7) * 8;
  #pragma unroll
  for (int j = 0; j < 2; ++j) {
    int rr = r + j*32;
    const float* p = in + (size_t)(k0 + rr)*HID + n0 + c8;
    f32x4 v0 = *(const f32x4*)p;
    f32x4 v1 = *(const f32x4*)(p + 4);
    #pragma unroll
    for (int e = 0; e < 4; ++e) { tl[rr][c8 + e] = f2b(v0[e]); tl[rr][c8 + 4 + e] = f2b(v1[e]); }
  }
  __syncthreads();
  #pragma unroll
  for (int j = 0; j < 2; ++j) {
    int rr = r + j*32;
    int orow = n0 + rr;
    if (perm) {
      int s5 = (orow >> 5) & 3;
      s5 = (s5 == 1) ? 2 : (s5 == 2) ? 1 : s5;
      orow = (orow & ~127) | (s5 << 5) | (orow & 31);
    }
    short8 v;
    #pragma unroll
    for (int e = 0; e < 8; ++e) v[e] = (short)tl[c8 + e][rr];
    *(short8*)(out + (size_t)orow*HID + k0 + c8) = v;
  }
}

// ============ shared GEMM helpers (swizzle proven: bank-conflict 0, rounds 2-14) ============

static __device__ __forceinline__ int swz_scol(int lane) {
  return (((lane & 7) * 16) ^ (((lane >> 3) & 7) << 4)) >> 1;   // swizzled src col (ushorts)
}

static __device__ __forceinline__ void rd_af(const unsigned short* Ah, bf16x8 (&afr)[4][2],
                                             int wm, int lr, int col0, int axor) {
  #pragma unroll
  for (int mi = 0; mi < 4; ++mi) {
    const unsigned short* rp = Ah + (wm*64 + mi*16 + lr) * 64;
    #pragma unroll
    for (int kk = 0; kk < 2; ++kk)
      afr[mi][kk] = *(const bf16x8*)(rp + (((kk*64 + col0) ^ axor) >> 1));
  }
}
static __device__ __forceinline__ void rd_bf(const unsigned short* Bh, bf16x8 (&bfr)[2][2],
                                             int wn, int lr, int col0, int axor) {
  #pragma unroll
  for (int ni = 0; ni < 2; ++ni) {
    const unsigned short* rp = Bh + (wn*32 + ni*16 + lr) * 64;
    #pragma unroll
    for (int kk = 0; kk < 2; ++kk)
      bfr[ni][kk] = *(const bf16x8*)(rp + (((kk*64 + col0) ^ axor) >> 1));
  }
}
static __device__ __forceinline__ void mfma16(const bf16x8 (&afr)[4][2], const bf16x8 (&bfr)[2][2],
                                              f32x4 (&ac)[4][2]) {
  #pragma unroll
  for (int kk = 0; kk < 2; ++kk)
    #pragma unroll
    for (int mi = 0; mi < 4; ++mi)
      #pragma unroll
      for (int ni = 0; ni < 2; ++ni)
        ac[mi][ni] = __builtin_amdgcn_mfma_f32_16x16x32_bf16(afr[mi][kk], bfr[ni][kk], ac[mi][ni], 0, 0, 0);
}

// ================= 128x256-tile GEMM, 3-deep pipeline, compiler-scheduled body =========
// (validated rounds 4-14; used for conv2 and wo where grids need 256 blocks of 128x256)

struct SPtrs { const unsigned short* p[6]; };

static __device__ __forceinline__ void build_ptrs(SPtrs& sp,
    const unsigned short* Ap, const unsigned short* Bp, int Ksz, int sh,
    int m0, int n0, const unsigned short* zpg, int tid) {
  int lane = tid & 63;
  int scol = swz_scol(lane);
  #pragma unroll
  for (int j = 0; j < 2; ++j) {
    int row = ((tid >> 6) * 2 + j) * 8 + (lane >> 3);               // 0..127
    int gr = m0 + row;
    sp.p[j]     = (sh && ((gr & (S - 1)) == 0)) ? (zpg + scol)
                                                : (Ap + (size_t)(gr - sh)*Ksz + scol);
    sp.p[2 + j] = Bp + (size_t)(n0 + row)*Ksz + scol;
    sp.p[4 + j] = Bp + (size_t)(n0 + 128 + row)*Ksz + scol;
  }
}

static __device__ __forceinline__ void stage6(unsigned short* buf, SPtrs& sp, int tid) {
  int c0 = (tid >> 6) * 1024;            // ushort offset of this wave's 2-chunk pair
  gload_lds16(sp.p[0], buf + c0);
  gload_lds16(sp.p[1], buf + c0 + 512);
  gload_lds16(sp.p[2], buf + 8192  + c0);
  gload_lds16(sp.p[3], buf + 8192  + c0 + 512);
  gload_lds16(sp.p[4], buf + 16384 + c0);
  gload_lds16(sp.p[5], buf + 16384 + c0 + 512);
  #pragma unroll
  for (int i = 0; i < 6; ++i) sp.p[i] += 64;
}

static __device__ __forceinline__ void gemm8_core(
    unsigned short* lds,
    const unsigned short* __restrict__ A1, const unsigned short* __restrict__ A2,
    const unsigned short* __restrict__ B1, const unsigned short* __restrict__ B2,
    int K1, int K2,
    const unsigned short* __restrict__ bias, const unsigned short* __restrict__ resid,
    void* __restrict__ Cout, int outmode, int N, int m0, int n0,
    int a1shift, const unsigned short* __restrict__ zrow) {
  int tid = threadIdx.x;
  int lane = tid & 63, w = tid >> 6;
  int wm = w >> 2, wn = w & 3;
  int lr = lane & 15, g = lane >> 4;
  int col0 = g * 16;
  int axor = (lr & 7) << 4;
  int nk1 = K1 >> 6;
  int nk = (K1 + K2) >> 6;
  f32x4 acc[2][4][2] = {};
  bf16x8 afr[4][2], bfr0[2][2], bfr1[2][2];

  unsigned short* buf0 = lds;            // each buf: A @0, B0 @8192, B1 @16384 (ushorts)
  unsigned short* buf1 = lds + 24576;
  unsigned short* buf2 = lds + 49152;

  SPtrs sp;
  build_ptrs(sp, A1, B1, K1, a1shift, m0, n0, zrow, tid);

  stage6(buf0, sp, tid);
  stage6(buf1, sp, tid);

  unsigned short* cur = buf0;
  unsigned short* nx1 = buf1;
  unsigned short* nx2 = buf2;
  for (int t = 0; t < nk; ++t) {
    if (t < nk - 1) asm volatile("s_waitcnt vmcnt(6)" ::: "memory");
    else            asm volatile("s_waitcnt vmcnt(0)" ::: "memory");
    __builtin_amdgcn_s_barrier();
    asm volatile("" ::: "memory");

    rd_af(cur,         afr,  wm, lr, col0, axor);
    rd_bf(cur + 8192,  bfr0, wn, lr, col0, axor);
    rd_bf(cur + 16384, bfr1, wn, lr, col0, axor);
    if (t + 2 < nk) {
      if (t + 2 == nk1) build_ptrs(sp, A2, B2, K2, 0, m0, n0, zrow, tid);
      stage6(nx2, sp, tid);
    }
    __builtin_amdgcn_s_setprio(1);
    mfma16(afr, bfr0, acc[0]);
    mfma16(afr, bfr1, acc[1]);
    __builtin_amdgcn_s_setprio(0);

    unsigned short* tmp = cur; cur = nx1; nx1 = nx2; nx2 = tmp;
  }

  #pragma unroll
  for (int qn = 0; qn < 2; ++qn)
    #pragma unroll
    for (int mi = 0; mi < 4; ++mi) {
      int row0 = m0 + wm*64 + mi*16 + g*4;
      #pragma unroll
      for (int ni = 0; ni < 2; ++ni) {
        int col = n0 + qn*128 + wn*32 + ni*16 + lr;
        float bv = bias ? b2f(bias[col]) : 0.f;
        f32x4 a = acc[qn][mi][ni];
        #pragma unroll
        for (int j = 0; j < 4; ++j) {
          size_t idx = (size_t)(row0 + j) * N + col;
          float v = a[j] + bv;
          if (resid) v += b2f(resid[idx]);
          if (outmode == 1) ((float*)Cout)[idx] = v;
          else ((unsigned short*)Cout)[idx] = f2b(v);
        }
      }
    }
}

template<int SHIFT>
__launch_bounds__(512, 1)
__global__ void gemm8_bt(const unsigned short* __restrict__ A1,
                         const unsigned short* __restrict__ A2,
                         const unsigned short* __restrict__ B1,
                         const unsigned short* __restrict__ B2,
                         int K1, int K2,
                         const unsigned short* __restrict__ bias,
                         const unsigned short* __restrict__ resid,
                         void* __restrict__ Cout, int outmode, int N,
                         const unsigned short* __restrict__ zrow) {
  __shared__ __align__(16) unsigned short lds[73728];   // 144 KiB, 3 bufs
  gemm8_core(lds, A1, A2, B1, B2, K1, K2, bias, resid, Cout, outmode, N,
             blockIdx.x*128, blockIdx.y*256, SHIFT, zrow);
}

// ============ 256x256-tile 4-phase core (validated round 12/14 on qk) ============
struct HPtr { const unsigned short* p0; const unsigned short* p1; };
static __device__ __forceinline__ void hinit(HPtr& h, const unsigned short* base,
                                             int row0, int tid) {
  int lane = tid & 63;
  int scol = swz_scol(lane);
  int r0 = ((tid >> 6) * 2) * 8 + (lane >> 3);
  h.p0 = base + (size_t)(row0 + r0) * 2048 + scol;
  h.p1 = base + (size_t)(row0 + r0 + 8) * 2048 + scol;
}
// shifted variant: reads row-1 (zero page at batch starts); zpg reads advance with kk
static __device__ __forceinline__ void hinit_sh(HPtr& h, const unsigned short* base,
                                                int row0, const unsigned short* zpg, int tid) {
  int lane = tid & 63;
  int scol = swz_scol(lane);
  int r0 = ((tid >> 6) * 2) * 8 + (lane >> 3);
  int g0 = row0 + r0, g1 = row0 + r0 + 8;
  h.p0 = ((g0 & (S - 1)) == 0) ? (zpg + scol) : (base + (size_t)(g0 - 1) * 2048 + scol);
  h.p1 = ((g1 & (S - 1)) == 0) ? (zpg + scol) : (base + (size_t)(g1 - 1) * 2048 + scol);
}
static __device__ __forceinline__ void hstage(unsigned short* slot, HPtr& h, int tid) {
  int c0 = (tid >> 6) * 1024;
  gload_lds16(h.p0, slot + c0);
  gload_lds16(h.p1, slot + c0 + 512);
  h.p0 += 64; h.p1 += 64;
}

// core K-loop shared by gemm256_bt and gemm256_trio (K=2048, 32 tiles)
static __device__ __forceinline__ void gemm256_loop(
    unsigned short* lds, HPtr& hA0, HPtr& hA1, HPtr& hB0, HPtr& hB1,
    f32x4 (&acc)[2][2][4][2], int wm, int wn, int lr, int col0, int axor, int tid) {
  bf16x8 af[4][2], bf0[2][2], bf1[2][2];
  const int nk = 2048 >> 6;
  // prologue: tile0 {A0,A1,B0,B1} -> buf0 ; tile1 {A0,B0,B1} -> buf1
  hstage(lds + 0,             hA0, tid);
  hstage(lds + 8192,          hA1, tid);
  hstage(lds + 16384,         hB0, tid);
  hstage(lds + 24576,         hB1, tid);
  hstage(lds + 32768 + 0,     hA0, tid);
  hstage(lds + 32768 + 16384, hB0, tid);
  hstage(lds + 32768 + 24576, hB1, tid);
  asm volatile("s_waitcnt vmcnt(6)" ::: "memory");   // tile0 landed; tile1's 3 halves in flight
  __builtin_amdgcn_s_barrier();
  asm volatile("" ::: "memory");

  for (int t = 0; t < nk; ++t) {
    unsigned short* cur = lds + (t & 1) * 32768;
    unsigned short* oth = lds + ((t & 1) ^ 1) * 32768;

    // ---- P1 (qm0,qn0): rd A0(8)+B0(4) ; stage A1(t+1) -> oth ----
    rd_af(cur,         af,  wm, lr, col0, axor);
    rd_bf(cur + 16384, bf0, wn, lr, col0, axor);
    if (t + 1 < nk) hstage(oth + 8192, hA1, tid);
    __builtin_amdgcn_s_barrier();
    asm volatile("s_waitcnt lgkmcnt(0)" ::: "memory");
    __builtin_amdgcn_s_setprio(1);
    mfma16(af, bf0, acc[0][0]);
    __builtin_amdgcn_s_setprio(0);
    __builtin_amdgcn_s_barrier();

    // ---- P2 (qm0,qn1): rd B1(4) (A regs reused) ; stage A0(t+2) -> cur ----
    rd_bf(cur + 24576, bf1, wn, lr, col0, axor);
    if (t + 2 < nk) hstage(cur, hA0, tid);
    __builtin_amdgcn_s_barrier();
    asm volatile("s_waitcnt lgkmcnt(0)" ::: "memory");
    __builtin_amdgcn_s_setprio(1);
    mfma16(af, bf1, acc[0][1]);
    __builtin_amdgcn_s_setprio(0);
    __builtin_amdgcn_s_barrier();

    // ---- P3 (qm1,qn1): rd A1(8) (B1 regs reused) ; stage B0(t+2) -> cur ----
    rd_af(cur + 8192, af, wm, lr, col0, axor);
    if (t + 2 < nk) hstage(cur + 16384, hB0, tid);
    __builtin_amdgcn_s_barrier();
    asm volatile("s_waitcnt lgkmcnt(0)" ::: "memory");
    __builtin_amdgcn_s_setprio(1);
    mfma16(af, bf1, acc[1][1]);
    __builtin_amdgcn_s_setprio(0);
    __builtin_amdgcn_s_barrier();

    // ---- P4 (qm1,qn0): all regs reused ; stage B1(t+2) -> cur ; counted vmcnt ----
    if (t + 2 < nk) hstage(cur + 24576, hB1, tid);
    __builtin_amdgcn_s_barrier();
    asm volatile("s_waitcnt lgkmcnt(0)" ::: "memory");
    __builtin_amdgcn_s_setprio(1);
    mfma16(af, bf0, acc[1][0]);
    __builtin_amdgcn_s_setprio(0);
    if (t + 2 < nk) asm volatile("s_waitcnt vmcnt(6)" ::: "memory");
    else            asm volatile("s_waitcnt vmcnt(0)" ::: "memory");
    __builtin_amdgcn_s_barrier();
    asm volatile("" ::: "memory");
  }
}

// ---- qk projection: C = A @ B^T, bf16 out, + T1 XCD swizzle (validated round 14) ----
__launch_bounds__(512, 1)
__global__ void gemm256_bt(const unsigned short* __restrict__ A,
                           const unsigned short* __restrict__ B,
                           unsigned short* __restrict__ C, int N) {
  __shared__ __align__(16) unsigned short lds[65536];   // 128 KiB
  int tid = threadIdx.x;
  int lane = tid & 63, w = tid >> 6;
  int wm = w >> 2, wn = w & 3;
  int lr = lane & 15, g = lane >> 4;
  int col0 = g * 16;
  int axor = (lr & 7) << 4;
  int nwg = gridDim.x * gridDim.y;
  int lin = blockIdx.y * gridDim.x + blockIdx.x;
  int cpx = nwg >> 3;
  int swz = (lin & 7) * cpx + (lin >> 3);
  int m0 = (swz % gridDim.x) * 256, n0 = (swz / gridDim.x) * 256;
  f32x4 acc[2][2][4][2] = {};           // [qm][qn][mi][ni]

  HPtr hA0, hA1, hB0, hB1;
  hinit(hA0, A, m0,       tid);
  hinit(hA1, A, m0 + 128, tid);
  hinit(hB0, B, n0,       tid);
  hinit(hB1, B, n0 + 128, tid);
  gemm256_loop(lds, hA0, hA1, hB0, hB1, acc, wm, wn, lr, col0, axor, tid);

  #pragma unroll
  for (int qm = 0; qm < 2; ++qm)
    #pragma unroll
    for (int mi = 0; mi < 4; ++mi) {
      int row0 = m0 + qm*128 + wm*64 + mi*16 + g*4;
      #pragma unroll
      for (int qn = 0; qn < 2; ++qn)
        #pragma unroll
        for (int ni = 0; ni < 2; ++ni) {
          int col = n0 + qn*128 + wn*32 + ni*16 + lr;
          f32x4 a = acc[qm][qn][mi][ni];
          #pragma unroll
          for (int j = 0; j < 4; ++j)
            C[(size_t)(row0 + j) * N + col] = f2b(a[j]);
        }
    }
}

// ---- trio: conv1-pieceA (shifted, 64 tiles) + conv1-pieceB (64) + V-proj (128, Vt out) ----
// All uniform K=2048 256^2 tiles -> 256 blocks, exactly 1/CU (the validated gemm256 regime).
// conv1 = shift(x)@W1_0 + x@W1_1 is ALREADY a sum of two K=2048 GEMMs -> compute as bf16
// partials (o1a,o1b in dead qkf space); add_bias pass reconstitutes o1 (+bias). Numerics:
// per-piece std ~0.9, bf16 round ~2e-3, damped ~0.02*sqrt(1024) through conv2 -> ~1e-3 on
// yb vs 0.069 threshold (current margin 4.4x).
__launch_bounds__(512, 1)
__global__ void gemm256_trio(const unsigned short* __restrict__ xb,
                             const unsigned short* __restrict__ w1t0,
                             const unsigned short* __restrict__ w1t1,
                             const unsigned short* __restrict__ wvt,
                             unsigned short* __restrict__ o1a,
                             unsigned short* __restrict__ o1b,
                             unsigned short* __restrict__ vtg,
                             const unsigned short* __restrict__ zpg) {
  __shared__ __align__(16) unsigned short lds[65536];   // 128 KiB
  int tid = threadIdx.x;
  int lane = tid & 63, w = tid >> 6;
  int wm = w >> 2, wn = w & 3;
  int lr = lane & 15, g = lane >> 4;
  int col0 = g * 16;
  int axor = (lr & 7) << 4;
  // XCD swizzle over the flat 256-block grid, then job decode
  int lin = blockIdx.x;
  int swz = (lin & 7) * 32 + (lin >> 3);
  int job, s;
  if (swz < 64)       { job = 0; s = swz; }
  else if (swz < 128) { job = 1; s = swz - 64; }
  else                { job = 2; s = swz - 128; }
  int m0 = (s & 15) * 256;
  int n0 = (s >> 4) * 256;            // job<2: 0..3 ; job2: 0..7
  f32x4 acc[2][2][4][2] = {};

  HPtr hA0, hA1, hB0, hB1;
  if (job == 0) { hinit_sh(hA0, xb, m0, zpg, tid); hinit_sh(hA1, xb, m0 + 128, zpg, tid); }
  else          { hinit(hA0, xb, m0, tid);         hinit(hA1, xb, m0 + 128, tid); }
  const unsigned short* B = (job == 0) ? w1t0 : (job == 1) ? w1t1 : wvt;
  hinit(hB0, B, n0,       tid);
  hinit(hB1, B, n0 + 128, tid);
  gemm256_loop(lds, hA0, hA1, hB0, hB1, acc, wm, wn, lr, col0, axor, tid);

  if (job < 2) {
    unsigned short* C = (job == 0) ? o1a : o1b;   // bf16 [4096][1024] partial
    #pragma unroll
    for (int qm = 0; qm < 2; ++qm)
      #pragma unroll
      for (int mi = 0; mi < 4; ++mi) {
        int row0 = m0 + qm*128 + wm*64 + mi*16 + g*4;
        #pragma unroll
        for (int qn = 0; qn < 2; ++qn)
          #pragma unroll
          for (int ni = 0; ni < 2; ++ni) {
            int col = n0 + qn*128 + wn*32 + ni*16 + lr;
            f32x4 a = acc[qm][qn][mi][ni];
            #pragma unroll
            for (int j = 0; j < 4; ++j)
              C[(size_t)(row0 + j) * 1024 + col] = f2b(a[j]);
          }
      }
  } else {
    // Vt layout: [(b*HID + col)][S], rows row0..+3 consecutive s
    #pragma unroll
    for (int qm = 0; qm < 2; ++qm)
      #pragma unroll
      for (int mi = 0; mi < 4; ++mi) {
        int row0 = m0 + qm*128 + wm*64 + mi*16 + g*4;
        int bb = row0 >> 11;
        int s0 = row0 & (S - 1);
        #pragma unroll
        for (int qn = 0; qn < 2; ++qn)
          #pragma unroll
          for (int ni = 0; ni < 2; ++ni) {
            int col = n0 + qn*128 + wn*32 + ni*16 + lr;
            size_t base = ((size_t)bb * HID + col) * S + s0;
            f32x4 a = acc[qm][qn][mi][ni];
            ushort4v pk;
            #pragma unroll
            for (int j = 0; j < 4; ++j) pk[j] = f2b(a[j]);
            *(ushort4v*)(vtg + base) = pk;
          }
      }
  }
}

// ---- o1 = o1a + o1b + bias (bf16, 4096x1024) ----
__global__ void add_bias(const unsigned short* __restrict__ a,
                         const unsigned short* __restrict__ b,
                         const unsigned short* __restrict__ bias,
                         unsigned short* __restrict__ o) {
  long i8 = ((long)blockIdx.x * 256 + threadIdx.x) * 8;   // over 4096*1024
  short8 va = *(const short8*)(a + i8);
  short8 vb = *(const short8*)(b + i8);
  short8 wb = *(const short8*)(bias + (i8 & 1023));
  short8 vo;
  #pragma unroll
  for (int e = 0; e < 8; ++e)
    vo[e] = (short)f2b(b2f((unsigned short)va[e]) + b2f((unsigned short)vb[e])
                       + b2f((unsigned short)wb[e]));
  *(short8*)(o + i8) = vo;
}

// ---------------- RMSNorm over bf16 rows -> bf16 (single-pass, short8) ----------------
__global__ void rmsnorm_rows(const unsigned short* __restrict__ y,
                             const unsigned short* __restrict__ w,
                             unsigned short* __restrict__ out) {
  int r = blockIdx.x;
  int c8 = threadIdx.x * 8;               // 256 threads x 8 = 2048
  const unsigned short* yr = y + (size_t)r * HID;
  short8 v = *(const short8*)(yr + c8);
  float f[8];
  float ss = 0.f;
  #pragma unroll
  for (int e = 0; e < 8; ++e) { f[e] = b2f((unsigned short)v[e]); ss += f[e]*f[e]; }
  #pragma unroll
  for (int o = 32; o; o >>= 1) ss += __shfl_xor(ss, o);
  __shared__ float red[4];
  if ((threadIdx.x & 63) == 0) red[threadIdx.x >> 6] = ss;
  __syncthreads();
  float tot = red[0] + red[1] + red[2] + red[3];
  float scale = rsqrtf(tot / (float)HID + 1e-6f);
  short8 wv = *(const short8*)(w + c8);
  short8 o8;
  #pragma unroll
  for (int e = 0; e < 8; ++e) o8[e] = (short)f2b(f[e] * scale * b2f((unsigned short)wv[e]));
  *(short8*)(out + (size_t)r*HID + c8) = o8;
}

// ---------------- RoPE from fused qk output [r][4096]; head h = cols h*256..+255 ----------------
__global__ void rope_rearrange(const unsigned short* __restrict__ qkf,
                               const float* __restrict__ ctab, const float* __restrict__ stab,
                               unsigned short* __restrict__ qr, unsigned short* __restrict__ kr) {
  int r = blockIdx.x;
  int t = r & (S - 1);
  int h = threadIdx.x >> 4;
  int i4 = (threadIdx.x & 15) * 4;
  int pc = (i4 & 31) + ((i4 >> 5) << 6);    // permuted col of x1 for elems i4..i4+3 (same 32-block)
  const unsigned short* qk = qkf + (size_t)r * (2*HID) + h * 256;
  f32x4 c = *(const f32x4*)(ctab + t*64 + i4);
  f32x4 s = *(const f32x4*)(stab + t*64 + i4);
  ushort4v q1 = *(const ushort4v*)(qk + pc);
  ushort4v q2 = *(const ushort4v*)(qk + pc + 32);
  ushort4v k1 = *(const ushort4v*)(qk + 128 + pc);
  ushort4v k2 = *(const ushort4v*)(qk + 128 + pc + 32);
  size_t o = (size_t)r * HID + (size_t)h * HD;
  const float SC = 0.08838834764831845f * 1.44269504088896340f;  // 1/sqrt(128) * log2(e)
  ushort4v oq1, oq2, ok1, ok2;
  #pragma unroll
  for (int e = 0; e < 4; ++e) {
    float a = b2f(q1[e]), b = b2f(q2[e]);
    float x = b2f(k1[e]), y = b2f(k2[e]);
    oq1[e] = f2b((a*c[e] - b*s[e]) * SC);
    oq2[e] = f2b((b*c[e] + a*s[e]) * SC);
    ok1[e] = f2b(x*c[e] - y*s[e]);
    ok2[e] = f2b(y*c[e] + x*s[e]);
  }
  *(ushort4v*)(qr + o + i4)      = oq1;
  *(ushort4v*)(qr + o + 64 + i4) = oq2;
  *(ushort4v*)(kr + o + i4)      = ok1;
  *(ushort4v*)(kr + o + 64 + i4) = ok2;
}

// ---------------- MFMA causal flash attention (16x16, DMA-staged, balanced pairs) ----------------
#define KT 64

static __device__ __forceinline__ void attn_pass(
    int qt, int b, int h, unsigned short* lds,
    const unsigned short* __restrict__ Qr, const unsigned short* __restrict__ Kr,
    const unsigned short* __restrict__ Vt, unsigned short* __restrict__ Out) {
  int tid = threadIdx.x, lane = tid & 63, w = tid >> 6;
  int q0 = qt * 64;
  size_t bS = (size_t)b * S;
  size_t ho = (size_t)h * HD;
  int lr = lane & 15, g = lane >> 4;
  int rsw = (lane & 7) << 3;                       // read-side swizzle (ushort units)
  // all waves past previous pass's LDS reads before re-staging the shared buffers
  __syncthreads();
  bf16x8 bq[4];
  {
    int qrow = q0 + w*16 + lr;
    const unsigned short* qp = Qr + (bS + qrow)*HID + ho + g*8;
    #pragma unroll
    for (int kk = 0; kk < 4; ++kk) bq[kk] = *(const bf16x8*)(qp + kk*32);
  }
  // staging pointers (pre-swizzled source cols; advance per tile)
  const unsigned short* kp[4];
  const unsigned short* vp[4];
  #pragma unroll
  for (int j = 0; j < 4; ++j) {
    int c = w*4 + j;                       // chunk 0..15 (1KB each)
    int rk = c*4 + (lane >> 4);            // K row 0..63
    int sck = ((lane & 15) * 8) ^ ((rk & 7) << 3);
    kp[j] = Kr + (bS + rk)*HID + ho + sck;
    int rv = c*8 + (lane >> 3);            // V row (d) 0..127
    int scv = ((lane & 7) * 8) ^ ((rv & 7) << 3);
    vp[j] = Vt + ((size_t)b*HID + ho + rv)*S + scv;
  }
  int cdst = (w*4) * 512;                  // this wave's chunk-group dest (ushorts)
  unsigned short* curK = lds;
  unsigned short* curV = lds + 8192;
  unsigned short* nxtK = lds + 16384;
  unsigned short* nxtV = lds + 24576;
  #pragma unroll
  for (int j = 0; j < 4; ++j) {            // prologue: tile 0 -> cur
    gload_lds16(kp[j], curK + cdst + j*512);
    gload_lds16(vp[j], curV + cdst + j*512);
    kp[j] += (size_t)KT * HID;
    vp[j] += KT;
  }
  f32x4 o[8] = {};                 // O: col(d)=lr+16*ni, row(q_local)=4g+reg
  float m = -1e30f, l = 0.f;
  unsigned short* PlW = lds + 32768 + w*1024;
  int ntiles = qt + 1;
  for (int kt = 0; kt < ntiles; ++kt) {
    // ---- single sync point: own DMA landed, then block-wide barrier ----
    asm volatile("s_waitcnt vmcnt(0)" ::: "memory");
    __builtin_amdgcn_s_barrier();
    asm volatile("" ::: "memory");
    if (kt + 1 < ntiles) {                 // issue next-tile DMA into the other buffer
      #pragma unroll
      for (int j = 0; j < 4; ++j) {
        gload_lds16(kp[j], nxtK + cdst + j*512);
        gload_lds16(vp[j], nxtV + cdst + j*512);
        kp[j] += (size_t)KT * HID;
        vp[j] += KT;
      }
    }
    f32x4 st[4] = {};
    __builtin_amdgcn_s_setprio(1);
    #pragma unroll
    for (int kk = 0; kk < 4; ++kk) {
      #pragma unroll
      for (int mi = 0; mi < 4; ++mi) {
        bf16x8 a = *(const bf16x8*)(&curK[(mi*16 + lr)*128 + ((kk*32 + g*8) ^ rsw)]);
        st[mi] = __builtin_amdgcn_mfma_f32_16x16x32_bf16(a, bq[kk], st[mi], 0, 0, 0);
      }
    }
    __builtin_amdgcn_s_setprio(0);
    bool lastt = (kt == ntiles - 1);
    float tm = -1e30f;
    #pragma unroll
    for (int mi = 0; mi < 4; ++mi)
      #pragma unroll
      for (int r = 0; r < 4; ++r) {
        float v = st[mi][r];
        if (lastt && (mi*16 + 4*g + r) > (w*16 + lr)) v = -1e30f;
        st[mi][r] = v;
        tm = fmaxf(tm, v);
      }
    tm = fmaxf(tm, __shfl_xor(tm, 16));
    tm = fmaxf(tm, __shfl_xor(tm, 32));
    if (!__all(tm - m <= 11.5f)) {
      float mn = fmaxf(m, tm);
      float sc = exp2f(m - mn);
      float s0 = __shfl(sc, 4*g+0), s1 = __shfl(sc, 4*g+1);
      float s2 = __shfl(sc, 4*g+2), s3 = __shfl(sc, 4*g+3);
      #pragma unroll
      for (int ni = 0; ni < 8; ++ni) {
        o[ni][0] *= s0; o[ni][1] *= s1; o[ni][2] *= s2; o[ni][3] *= s3;
      }
      l *= sc;
      m = mn;
    }
    float ts = 0.f;
    __bf16 pbf[4][4];
    #pragma unroll
    for (int mi = 0; mi < 4; ++mi)
      #pragma unroll
      for (int r = 0; r < 4; ++r) {
        float p = exp2f(st[mi][r] - m);
        ts += p;
        pbf[mi][r] = (__bf16)p;
      }
    ts += __shfl_xor(ts, 16);
    ts += __shfl_xor(ts, 32);
    l += ts;
    #pragma unroll
    for (int mi = 0; mi < 4; ++mi) {
      bf16x4 pk = { pbf[mi][0], pbf[mi][1], pbf[mi][2], pbf[mi][3] };
      *(bf16x4*)(&PlW[lr*64 + ((mi*16 + 4*g) ^ rsw)]) = pk;
    }
    asm volatile("" ::: "memory");   // compile-time fence: P stores before P reads
    __builtin_amdgcn_s_setprio(1);
    #pragma unroll
    for (int kk = 0; kk < 2; ++kk) {
      int pc = (kk*32 + g*8) ^ rsw;
      bf16x8 a = *(const bf16x8*)(&PlW[lr*64 + pc]);
      #pragma unroll
      for (int ni = 0; ni < 8; ++ni) {
        bf16x8 bv = *(const bf16x8*)(&curV[(ni*16 + lr)*64 + pc]);
        o[ni] = __builtin_amdgcn_mfma_f32_16x16x32_bf16(a, bv, o[ni], 0, 0, 0);
      }
    }
    __builtin_amdgcn_s_setprio(0);
    unsigned short* t0 = curK; curK = nxtK; nxtK = t0;
    unsigned short* t1 = curV; curV = nxtV; nxtV = t1;
  }
  float l0 = __shfl(l, 4*g+0), l1 = __shfl(l, 4*g+1);
  float l2 = __shfl(l, 4*g+2), l3 = __shfl(l, 4*g+3);
  float i0 = 1.f/l0, i1 = 1.f/l1, i2 = 1.f/l2, i3 = 1.f/l3;
  int rbase = q0 + w*16 + 4*g;
  #pragma unroll
  for (int ni = 0; ni < 8; ++ni) {
    size_t cbase = ho + ni*16 + lr;
    Out[(bS + rbase + 0)*HID + cbase] = f2b(o[ni][0]*i0);
    Out[(bS + rbase + 1)*HID + cbase] = f2b(o[ni][1]*i1);
    Out[(bS + rbase + 2)*HID + cbase] = f2b(o[ni][2]*i2);
    Out[(bS + rbase + 3)*HID + cbase] = f2b(o[ni][3]*i3);
  }
}

__launch_bounds__(256, 2)
__global__ void attn_mfma(const unsigned short* __restrict__ Qr,
                          const unsigned short* __restrict__ Kr,
                          const unsigned short* __restrict__ Vt,
                          unsigned short* __restrict__ Out) {
  // [0,8192) K0 | [8192,16384) V0 | [16384,24576) K1 | [24576,32768) V1 | [32768,36864) P
  __shared__ __align__(16) unsigned short lds[36864];
  int bh = blockIdx.x;
  int b = bh >> 4, h = bh & 15;
  int by = blockIdx.y;                       // 0..15
  attn_pass(31 - by, b, h, lds, Qr, Kr, Vt, Out);   // heavy tile
  attn_pass(by,      b, h, lds, Qr, Kr, Vt, Out);   // light tile; total = 33 KV-tiles/block
}

extern "C" void kernel_launch(void* const* d_in, const int* in_sizes, int n_in,
                              void* d_out, int out_size, void* d_ws, size_t ws_size,
                              hipStream_t stream) {
  const float* x_raw   = (const float*)d_in[0];
  const int* positions = (const int*)d_in[1];
  const float* wq_raw  = (const float*)d_in[2];
  const float* wk_raw  = (const float*)d_in[3];
  const float* wv_raw  = (const float*)d_in[4];
  const float* wo_raw  = (const float*)d_in[5];
  const float* c1w_raw = (const float*)d_in[6];
  const float* c1b_raw = (const float*)d_in[7];
  const float* c2w_raw = (const float*)d_in[8];
  const float* c2b_raw = (const float*)d_in[9];
  const float* rms_raw = (const float*)d_in[10];

  const size_t WS_NEEDED = 140000000;
  if (ws_size < WS_NEEDED) {
    long n = (long)out_size;
    fill_debug<<<dim3((unsigned)((n + 255) / 256)), dim3(256), 0, stream>>>((unsigned short*)d_out, n);
    return;
  }

  char* ws = (char*)d_ws;
  size_t off = 0;
  auto alloc = [&](size_t bytes) { char* p = ws + off; off += (bytes + 255) & ~(size_t)255; return p; };
  float* ctab          = (float*)alloc((size_t)S*64*4);
  float* stab          = (float*)alloc((size_t)S*64*4);
  unsigned short* wqkt = (unsigned short*)alloc((size_t)2*HID*HID*2);  // [wq^T ; wk^T], rope-permuted
  unsigned short* wvt  = (unsigned short*)alloc((size_t)HID*HID*2);
  unsigned short* wot  = (unsigned short*)alloc((size_t)HID*HID*2);
  unsigned short* w1t0 = (unsigned short*)alloc((size_t)1024*HID*2);
  unsigned short* w1t1 = (unsigned short*)alloc((size_t)1024*HID*2);
  unsigned short* w2t0 = (unsigned short*)alloc((size_t)HID*1024*2);
  unsigned short* w2t1 = (unsigned short*)alloc((size_t)HID*1024*2);
  unsigned short* xb   = (unsigned short*)alloc((size_t)ROWS*HID*2);   // reused as kr after conv2
  unsigned short* qrb  = (unsigned short*)alloc((size_t)ROWS*HID*2);   // q rotated
  unsigned short* o1   = (unsigned short*)alloc((size_t)ROWS*1024*2);
  unsigned short* yb   = (unsigned short*)alloc((size_t)ROWS*HID*2);   // reused as attn out
  unsigned short* hg   = (unsigned short*)alloc((size_t)ROWS*HID*2);
  unsigned short* qkf  = (unsigned short*)alloc((size_t)ROWS*2*HID*2); // fused q|k output
  unsigned short* vtg  = (unsigned short*)alloc((size_t)BATCH*HID*S*2);
  unsigned short* c1bb = (unsigned short*)alloc(1024*2);
  unsigned short* c2bb = (unsigned short*)alloc(2048*2);
  unsigned short* rmswb= (unsigned short*)alloc(2048*2);
  unsigned short* zpg  = (unsigned short*)alloc(8192*2);               // zero page (kk-advancing)
  unsigned short* krr  = xb;     // xb dead after conv2 (resid read)
  unsigned short* attn = yb;     // yb dead after rmsnorm
  unsigned short* o1a  = qkf;                              // conv1 partials live in dead qkf
  unsigned short* o1b  = qkf + (size_t)ROWS*1024;

  dim3 b256(256);
  dim3 b512(512);
  prep_all<<<dim3(4096, 4), b256, 0, stream>>>(c1w_raw, c2w_raw, x_raw, positions,
                                               c1b_raw, c2b_raw, rms_raw,
                                               w1t0, w1t1, w2t0, w2t1, xb,
                                               ctab, stab, c1bb, c2bb, rmswb, zpg);
  transpose4<<<dim3(32,32,4), b256, 0, stream>>>(wq_raw, wk_raw, wv_raw, wo_raw,
                                                 wqkt, wqkt + (size_t)HID*HID, wvt, wot);
  // trio (256^2 4-phase, 256 uniform K=2048 blocks): conv1-pieceA/B partials + V-proj
  gemm256_trio<<<dim3(256), b512, 0, stream>>>(xb, w1t0, w1t1, wvt, o1a, o1b, vtg, zpg);
  // o1 = o1a + o1b + bias
  add_bias<<<dim3(ROWS*1024/8/256), b256, 0, stream>>>(o1a, o1b, c1bb, o1);
  // conv2 + resid: yb = shift(o1)@W2_0^T + o1@W2_1^T + b2 + xb    [4096 x 2048]
  gemm8_bt<1><<<dim3(ROWS/128, HID/256), b512, 0, stream>>>(o1, o1, w2t0, w2t1, 1024, 1024, c2bb, xb, yb, 0, HID, zpg);
  rmsnorm_rows<<<dim3(ROWS), b256, 0, stream>>>(yb, rmswb, hg);
  // fused q|k projection (256x256 4-phase + XCD swizzle): qkf = hg @ [wq|wk]  [4096x4096]
  gemm256_bt<<<dim3(ROWS/256, (2*HID)/256), b512, 0, stream>>>(hg, wqkt, qkf, 2*HID);
  rope_rearrange<<<dim3(ROWS), b256, 0, stream>>>(qkf, ctab, stab, qrb, krr);
  attn_mfma<<<dim3(BATCH*HEADS, 16), b256, 0, stream>>>(qrb, krr, vtg, attn);
  // output projection: d_out = attn @ wo^T   [4096 x 2048], f32 out
  gemm8_bt<0><<<dim3(ROWS/128, HID/256), b512, 0, stream>>>(attn, attn, wot, wot, HID, 0, nullptr, nullptr, d_out, 1, HID, nullptr);
}

// Round 16
// 339.063 us; speedup vs baseline: 1.1003x; 1.0287x over previous
//
#include <hip/hip_runtime.h>

#define HID 2048
#define HEADS 16
#define HD 128
#define BATCH 2
#define S 2048
#define ROWS (BATCH*S)

typedef short short8 __attribute__((ext_vector_type(8)));
typedef unsigned short ushort4v __attribute__((ext_vector_type(4)));
typedef unsigned short ushort2v __attribute__((ext_vector_type(2)));
typedef float f32x4 __attribute__((ext_vector_type(4)));
typedef __bf16 bf16x8 __attribute__((ext_vector_type(8)));
typedef __bf16 bf16x4 __attribute__((ext_vector_type(4)));

static __device__ __forceinline__ float b2f(unsigned short u) {
  union { float f; unsigned int i; } v; v.i = ((unsigned int)u) << 16; return v.f;
}
static __device__ __forceinline__ unsigned short f2b(float f) {
  union { float f; unsigned int i; } v; v.f = f;
  unsigned int u = v.i;
  unsigned int r = ((u >> 16) & 1u) + 0x7fffu;
  return (unsigned short)((u + r) >> 16);
}

// async global->LDS, 16B per lane; LDS dest = wave-uniform base + lane*16 (global src is per-lane)
static __device__ __forceinline__ void gload_lds16(const unsigned short* g, unsigned short* l) {
  __builtin_amdgcn_global_load_lds(
      (const __attribute__((address_space(1))) unsigned int*)(const void*)g,
      (__attribute__((address_space(3))) unsigned int*)(void*)l,
      16, 0, 0);
}

// ---------------- debug fill (ws-size canary) ----------------
__global__ void fill_debug(unsigned short* __restrict__ out, long n) {
  long i = (long)blockIdx.x * blockDim.x + threadIdx.x;
  if (i < n) out[i] = 0x447A;  // bf16 1000.0
}

// ---------------- fused prep: conv repacks + x convert + rope tables + small converts ----------
__global__ void prep_all(const float* __restrict__ c1w, const float* __restrict__ c2w,
                         const float* __restrict__ x, const int* __restrict__ positions,
                         const float* __restrict__ c1b, const float* __restrict__ c2b,
                         const float* __restrict__ rmsw,
                         unsigned short* __restrict__ w1t0, unsigned short* __restrict__ w1t1,
                         unsigned short* __restrict__ w2t0, unsigned short* __restrict__ w2t1,
                         unsigned short* __restrict__ xb,
                         float* __restrict__ ctab, float* __restrict__ stab,
                         unsigned short* __restrict__ c1bb, unsigned short* __restrict__ c2bb,
                         unsigned short* __restrict__ rmswb, unsigned short* __restrict__ zpg) {
  int job = blockIdx.y;
  if (job == 0 || job == 1) {
    const float* w = (job == 0) ? c1w : c2w;
    unsigned short* o0 = (job == 0) ? w1t0 : w2t0;
    unsigned short* o1 = (job == 0) ? w1t1 : w2t1;
    long i = (long)blockIdx.x * 256 + threadIdx.x;
    f32x4 v = *(const f32x4*)(w + i*4);
    ushort2v a = { f2b(v[0]), f2b(v[2]) };
    ushort2v b = { f2b(v[1]), f2b(v[3]) };
    *(ushort2v*)(o0 + i*2) = a;
    *(ushort2v*)(o1 + i*2) = b;
  } else if (job == 2) {
    long i = (long)blockIdx.x * 256 + threadIdx.x;
    #pragma unroll
    for (int rep = 0; rep < 2; ++rep) {
      long idx = i + (long)rep * 1048576L;
      f32x4 v = *(const f32x4*)(x + idx*4);
      ushort4v o = { f2b(v[0]), f2b(v[1]), f2b(v[2]), f2b(v[3]) };
      *(ushort4v*)(xb + idx*4) = o;
    }
  } else {
    int bx = blockIdx.x;
    if (bx < 512) {
      int t = bx * 4 + (threadIdx.x >> 6);
      int i = threadIdx.x & 63;
      float pos = (float)positions[t];
      float inv = powf(10000.0f, -(float)i / 64.0f);
      float ang = pos * inv;
      float sv, cv;
      sincosf(ang, &sv, &cv);
      ctab[t*64 + i] = cv;
      stab[t*64 + i] = sv;
    } else if (bx < 544) {
      int i = (bx - 512) * 256 + threadIdx.x;   // 0..8191
      if (i < 1024) c1bb[i] = f2b(c1b[i]);
      if (i < 2048) { c2bb[i] = f2b(c2b[i]); rmswb[i] = f2b(rmsw[i]); }
      zpg[i] = 0;                               // 8192-ushort zero page (kk-advancing reads)
    }
  }
}

// ---------------- 4x 2048x2048 transpose fp32 [K,N] -> bf16 [N,K], one dispatch ----------------
__global__ void transpose4(const float* __restrict__ s0, const float* __restrict__ s1,
                           const float* __restrict__ s2, const float* __restrict__ s3,
                           unsigned short* __restrict__ d0, unsigned short* __restrict__ d1,
                           unsigned short* __restrict__ d2, unsigned short* __restrict__ d3) {
  __shared__ unsigned short tl[64][73];
  const float* in; unsigned short* out; int perm;
  switch (blockIdx.z) {
    case 0:  in = s0; out = d0; perm = 1; break;
    case 1:  in = s1; out = d1; perm = 1; break;
    case 2:  in = s2; out = d2; perm = 0; break;
    default: in = s3; out = d3; perm = 0; break;
  }
  int n0 = blockIdx.x * 64, k0 = blockIdx.y * 64;
  int tid = threadIdx.x;
  int r = tid >> 3, c8 = (tid & 7) * 8;
  #pragma unroll
  for (int j = 0; j < 2; ++j) {
    int rr = r + j*32;
    const float* p = in + (size_t)(k0 + rr)*HID + n0 + c8;
    f32x4 v0 = *(const f32x4*)p;
    f32x4 v1 = *(const f32x4*)(p + 4);
    #pragma unroll
    for (int e = 0; e < 4; ++e) { tl[rr][c8 + e] = f2b(v0[e]); tl[rr][c8 + 4 + e] = f2b(v1[e]); }
  }
  __syncthreads();
  #pragma unroll
  for (int j = 0; j < 2; ++j) {
    int rr = r + j*32;
    int orow = n0 + rr;
    if (perm) {
      int s5 = (orow >> 5) & 3;
      s5 = (s5 == 1) ? 2 : (s5 == 2) ? 1 : s5;
      orow = (orow & ~127) | (s5 << 5) | (orow & 31);
    }
    short8 v;
    #pragma unroll
    for (int e = 0; e < 8; ++e) v[e] = (short)tl[c8 + e][rr];
    *(short8*)(out + (size_t)orow*HID + k0 + c8) = v;
  }
}

// ============ shared GEMM helpers (swizzle proven: bank-conflict 0, rounds 2-15) ============

static __device__ __forceinline__ int swz_scol(int lane) {
  return (((lane & 7) * 16) ^ (((lane >> 3) & 7) << 4)) >> 1;   // swizzled src col (ushorts)
}

static __device__ __forceinline__ void rd_af(const unsigned short* Ah, bf16x8 (&afr)[4][2],
                                             int wm, int lr, int col0, int axor) {
  #pragma unroll
  for (int mi = 0; mi < 4; ++mi) {
    const unsigned short* rp = Ah + (wm*64 + mi*16 + lr) * 64;
    #pragma unroll
    for (int kk = 0; kk < 2; ++kk)
      afr[mi][kk] = *(const bf16x8*)(rp + (((kk*64 + col0) ^ axor) >> 1));
  }
}
static __device__ __forceinline__ void rd_bf(const unsigned short* Bh, bf16x8 (&bfr)[2][2],
                                             int wn, int lr, int col0, int axor) {
  #pragma unroll
  for (int ni = 0; ni < 2; ++ni) {
    const unsigned short* rp = Bh + (wn*32 + ni*16 + lr) * 64;
    #pragma unroll
    for (int kk = 0; kk < 2; ++kk)
      bfr[ni][kk] = *(const bf16x8*)(rp + (((kk*64 + col0) ^ axor) >> 1));
  }
}
static __device__ __forceinline__ void mfma16(const bf16x8 (&afr)[4][2], const bf16x8 (&bfr)[2][2],
                                              f32x4 (&ac)[4][2]) {
  #pragma unroll
  for (int kk = 0; kk < 2; ++kk)
    #pragma unroll
    for (int mi = 0; mi < 4; ++mi)
      #pragma unroll
      for (int ni = 0; ni < 2; ++ni)
        ac[mi][ni] = __builtin_amdgcn_mfma_f32_16x16x32_bf16(afr[mi][kk], bfr[ni][kk], ac[mi][ni], 0, 0, 0);
}

// ================= 128x256-tile GEMM, 3-deep pipeline, compiler-scheduled body =========
// (validated rounds 4-15; used for wo)

struct SPtrs { const unsigned short* p[6]; };

static __device__ __forceinline__ void build_ptrs(SPtrs& sp,
    const unsigned short* Ap, const unsigned short* Bp, int Ksz, int sh,
    int m0, int n0, const unsigned short* zpg, int tid) {
  int lane = tid & 63;
  int scol = swz_scol(lane);
  #pragma unroll
  for (int j = 0; j < 2; ++j) {
    int row = ((tid >> 6) * 2 + j) * 8 + (lane >> 3);               // 0..127
    int gr = m0 + row;
    sp.p[j]     = (sh && ((gr & (S - 1)) == 0)) ? (zpg + scol)
                                                : (Ap + (size_t)(gr - sh)*Ksz + scol);
    sp.p[2 + j] = Bp + (size_t)(n0 + row)*Ksz + scol;
    sp.p[4 + j] = Bp + (size_t)(n0 + 128 + row)*Ksz + scol;
  }
}

static __device__ __forceinline__ void stage6(unsigned short* buf, SPtrs& sp, int tid) {
  int c0 = (tid >> 6) * 1024;            // ushort offset of this wave's 2-chunk pair
  gload_lds16(sp.p[0], buf + c0);
  gload_lds16(sp.p[1], buf + c0 + 512);
  gload_lds16(sp.p[2], buf + 8192  + c0);
  gload_lds16(sp.p[3], buf + 8192  + c0 + 512);
  gload_lds16(sp.p[4], buf + 16384 + c0);
  gload_lds16(sp.p[5], buf + 16384 + c0 + 512);
  #pragma unroll
  for (int i = 0; i < 6; ++i) sp.p[i] += 64;
}

static __device__ __forceinline__ void gemm8_core(
    unsigned short* lds,
    const unsigned short* __restrict__ A1, const unsigned short* __restrict__ A2,
    const unsigned short* __restrict__ B1, const unsigned short* __restrict__ B2,
    int K1, int K2,
    const unsigned short* __restrict__ bias, const unsigned short* __restrict__ resid,
    void* __restrict__ Cout, int outmode, int N, int m0, int n0,
    int a1shift, const unsigned short* __restrict__ zrow) {
  int tid = threadIdx.x;
  int lane = tid & 63, w = tid >> 6;
  int wm = w >> 2, wn = w & 3;
  int lr = lane & 15, g = lane >> 4;
  int col0 = g * 16;
  int axor = (lr & 7) << 4;
  int nk1 = K1 >> 6;
  int nk = (K1 + K2) >> 6;
  f32x4 acc[2][4][2] = {};
  bf16x8 afr[4][2], bfr0[2][2], bfr1[2][2];

  unsigned short* buf0 = lds;            // each buf: A @0, B0 @8192, B1 @16384 (ushorts)
  unsigned short* buf1 = lds + 24576;
  unsigned short* buf2 = lds + 49152;

  SPtrs sp;
  build_ptrs(sp, A1, B1, K1, a1shift, m0, n0, zrow, tid);

  stage6(buf0, sp, tid);
  stage6(buf1, sp, tid);

  unsigned short* cur = buf0;
  unsigned short* nx1 = buf1;
  unsigned short* nx2 = buf2;
  for (int t = 0; t < nk; ++t) {
    if (t < nk - 1) asm volatile("s_waitcnt vmcnt(6)" ::: "memory");
    else            asm volatile("s_waitcnt vmcnt(0)" ::: "memory");
    __builtin_amdgcn_s_barrier();
    asm volatile("" ::: "memory");

    rd_af(cur,         afr,  wm, lr, col0, axor);
    rd_bf(cur + 8192,  bfr0, wn, lr, col0, axor);
    rd_bf(cur + 16384, bfr1, wn, lr, col0, axor);
    if (t + 2 < nk) {
      if (t + 2 == nk1) build_ptrs(sp, A2, B2, K2, 0, m0, n0, zrow, tid);
      stage6(nx2, sp, tid);
    }
    __builtin_amdgcn_s_setprio(1);
    mfma16(afr, bfr0, acc[0]);
    mfma16(afr, bfr1, acc[1]);
    __builtin_amdgcn_s_setprio(0);

    unsigned short* tmp = cur; cur = nx1; nx1 = nx2; nx2 = tmp;
  }

  #pragma unroll
  for (int qn = 0; qn < 2; ++qn)
    #pragma unroll
    for (int mi = 0; mi < 4; ++mi) {
      int row0 = m0 + wm*64 + mi*16 + g*4;
      #pragma unroll
      for (int ni = 0; ni < 2; ++ni) {
        int col = n0 + qn*128 + wn*32 + ni*16 + lr;
        float bv = bias ? b2f(bias[col]) : 0.f;
        f32x4 a = acc[qn][mi][ni];
        #pragma unroll
        for (int j = 0; j < 4; ++j) {
          size_t idx = (size_t)(row0 + j) * N + col;
          float v = a[j] + bv;
          if (resid) v += b2f(resid[idx]);
          if (outmode == 1) ((float*)Cout)[idx] = v;
          else ((unsigned short*)Cout)[idx] = f2b(v);
        }
      }
    }
}

template<int SHIFT>
__launch_bounds__(512, 1)
__global__ void gemm8_bt(const unsigned short* __restrict__ A1,
                         const unsigned short* __restrict__ A2,
                         const unsigned short* __restrict__ B1,
                         const unsigned short* __restrict__ B2,
                         int K1, int K2,
                         const unsigned short* __restrict__ bias,
                         const unsigned short* __restrict__ resid,
                         void* __restrict__ Cout, int outmode, int N,
                         const unsigned short* __restrict__ zrow) {
  __shared__ __align__(16) unsigned short lds[73728];   // 144 KiB, 3 bufs
  gemm8_core(lds, A1, A2, B1, B2, K1, K2, bias, resid, Cout, outmode, N,
             blockIdx.x*128, blockIdx.y*256, SHIFT, zrow);
}

// ============ 256x256-tile 4-phase core (validated rounds 12-15) ============
struct HPtr { const unsigned short* p0; const unsigned short* p1; };
static __device__ __forceinline__ void hinit(HPtr& h, const unsigned short* base,
                                             int row0, int Ksz, int tid) {
  int lane = tid & 63;
  int scol = swz_scol(lane);
  int r0 = ((tid >> 6) * 2) * 8 + (lane >> 3);
  h.p0 = base + (size_t)(row0 + r0) * Ksz + scol;
  h.p1 = base + (size_t)(row0 + r0 + 8) * Ksz + scol;
}
// shifted variant: reads row-1 (zero page at batch starts); zpg reads advance with kk
static __device__ __forceinline__ void hinit_sh(HPtr& h, const unsigned short* base,
                                                int row0, int Ksz,
                                                const unsigned short* zpg, int tid) {
  int lane = tid & 63;
  int scol = swz_scol(lane);
  int r0 = ((tid >> 6) * 2) * 8 + (lane >> 3);
  int g0 = row0 + r0, g1 = row0 + r0 + 8;
  h.p0 = ((g0 & (S - 1)) == 0) ? (zpg + scol) : (base + (size_t)(g0 - 1) * Ksz + scol);
  h.p1 = ((g1 & (S - 1)) == 0) ? (zpg + scol) : (base + (size_t)(g1 - 1) * Ksz + scol);
}
static __device__ __forceinline__ void hstage(unsigned short* slot, HPtr& h, int tid) {
  int c0 = (tid >> 6) * 1024;
  gload_lds16(h.p0, slot + c0);
  gload_lds16(h.p1, slot + c0 + 512);
  h.p0 += 64; h.p1 += 64;
}

// core K-loop (NKT 64-wide K-tiles), shared by qk / trio / duo
template<int NKT>
static __device__ __forceinline__ void gemm256_loop(
    unsigned short* lds, HPtr& hA0, HPtr& hA1, HPtr& hB0, HPtr& hB1,
    f32x4 (&acc)[2][2][4][2], int wm, int wn, int lr, int col0, int axor, int tid) {
  bf16x8 af[4][2], bf0[2][2], bf1[2][2];
  const int nk = NKT;
  // prologue: tile0 {A0,A1,B0,B1} -> buf0 ; tile1 {A0,B0,B1} -> buf1
  hstage(lds + 0,             hA0, tid);
  hstage(lds + 8192,          hA1, tid);
  hstage(lds + 16384,         hB0, tid);
  hstage(lds + 24576,         hB1, tid);
  hstage(lds + 32768 + 0,     hA0, tid);
  hstage(lds + 32768 + 16384, hB0, tid);
  hstage(lds + 32768 + 24576, hB1, tid);
  asm volatile("s_waitcnt vmcnt(6)" ::: "memory");   // tile0 landed; tile1's 3 halves in flight
  __builtin_amdgcn_s_barrier();
  asm volatile("" ::: "memory");

  for (int t = 0; t < nk; ++t) {
    unsigned short* cur = lds + (t & 1) * 32768;
    unsigned short* oth = lds + ((t & 1) ^ 1) * 32768;

    // ---- P1 (qm0,qn0): rd A0(8)+B0(4) ; stage A1(t+1) -> oth ----
    rd_af(cur,         af,  wm, lr, col0, axor);
    rd_bf(cur + 16384, bf0, wn, lr, col0, axor);
    if (t + 1 < nk) hstage(oth + 8192, hA1, tid);
    __builtin_amdgcn_s_barrier();
    asm volatile("s_waitcnt lgkmcnt(0)" ::: "memory");
    __builtin_amdgcn_s_setprio(1);
    mfma16(af, bf0, acc[0][0]);
    __builtin_amdgcn_s_setprio(0);
    __builtin_amdgcn_s_barrier();

    // ---- P2 (qm0,qn1): rd B1(4) (A regs reused) ; stage A0(t+2) -> cur ----
    rd_bf(cur + 24576, bf1, wn, lr, col0, axor);
    if (t + 2 < nk) hstage(cur, hA0, tid);
    __builtin_amdgcn_s_barrier();
    asm volatile("s_waitcnt lgkmcnt(0)" ::: "memory");
    __builtin_amdgcn_s_setprio(1);
    mfma16(af, bf1, acc[0][1]);
    __builtin_amdgcn_s_setprio(0);
    __builtin_amdgcn_s_barrier();

    // ---- P3 (qm1,qn1): rd A1(8) (B1 regs reused) ; stage B0(t+2) -> cur ----
    rd_af(cur + 8192, af, wm, lr, col0, axor);
    if (t + 2 < nk) hstage(cur + 16384, hB0, tid);
    __builtin_amdgcn_s_barrier();
    asm volatile("s_waitcnt lgkmcnt(0)" ::: "memory");
    __builtin_amdgcn_s_setprio(1);
    mfma16(af, bf1, acc[1][1]);
    __builtin_amdgcn_s_setprio(0);
    __builtin_amdgcn_s_barrier();

    // ---- P4 (qm1,qn0): all regs reused ; stage B1(t+2) -> cur ; counted vmcnt ----
    if (t + 2 < nk) hstage(cur + 24576, hB1, tid);
    __builtin_amdgcn_s_barrier();
    asm volatile("s_waitcnt lgkmcnt(0)" ::: "memory");
    __builtin_amdgcn_s_setprio(1);
    mfma16(af, bf0, acc[1][0]);
    __builtin_amdgcn_s_setprio(0);
    if (t + 2 < nk) asm volatile("s_waitcnt vmcnt(6)" ::: "memory");
    else            asm volatile("s_waitcnt vmcnt(0)" ::: "memory");
    __builtin_amdgcn_s_barrier();
    asm volatile("" ::: "memory");
  }
}

// ---- qk projection: C = A @ B^T (K=2048), bf16 out, + T1 XCD swizzle ----
__launch_bounds__(512, 1)
__global__ void gemm256_bt(const unsigned short* __restrict__ A,
                           const unsigned short* __restrict__ B,
                           unsigned short* __restrict__ C, int N) {
  __shared__ __align__(16) unsigned short lds[65536];   // 128 KiB
  int tid = threadIdx.x;
  int lane = tid & 63, w = tid >> 6;
  int wm = w >> 2, wn = w & 3;
  int lr = lane & 15, g = lane >> 4;
  int col0 = g * 16;
  int axor = (lr & 7) << 4;
  int nwg = gridDim.x * gridDim.y;
  int lin = blockIdx.y * gridDim.x + blockIdx.x;
  int cpx = nwg >> 3;
  int swz = (lin & 7) * cpx + (lin >> 3);
  int m0 = (swz % gridDim.x) * 256, n0 = (swz / gridDim.x) * 256;
  f32x4 acc[2][2][4][2] = {};           // [qm][qn][mi][ni]

  HPtr hA0, hA1, hB0, hB1;
  hinit(hA0, A, m0,       2048, tid);
  hinit(hA1, A, m0 + 128, 2048, tid);
  hinit(hB0, B, n0,       2048, tid);
  hinit(hB1, B, n0 + 128, 2048, tid);
  gemm256_loop<32>(lds, hA0, hA1, hB0, hB1, acc, wm, wn, lr, col0, axor, tid);

  #pragma unroll
  for (int qm = 0; qm < 2; ++qm)
    #pragma unroll
    for (int mi = 0; mi < 4; ++mi) {
      int row0 = m0 + qm*128 + wm*64 + mi*16 + g*4;
      #pragma unroll
      for (int qn = 0; qn < 2; ++qn)
        #pragma unroll
        for (int ni = 0; ni < 2; ++ni) {
          int col = n0 + qn*128 + wn*32 + ni*16 + lr;
          f32x4 a = acc[qm][qn][mi][ni];
          #pragma unroll
          for (int j = 0; j < 4; ++j)
            C[(size_t)(row0 + j) * N + col] = f2b(a[j]);
        }
    }
}

// ---- trio: conv1-pieceA (shifted) + conv1-pieceB + V-proj, uniform K=2048 (round 15) ----
__launch_bounds__(512, 1)
__global__ void gemm256_trio(const unsigned short* __restrict__ xb,
                             const unsigned short* __restrict__ w1t0,
                             const unsigned short* __restrict__ w1t1,
                             const unsigned short* __restrict__ wvt,
                             unsigned short* __restrict__ o1a,
                             unsigned short* __restrict__ o1b,
                             unsigned short* __restrict__ vtg,
                             const unsigned short* __restrict__ zpg) {
  __shared__ __align__(16) unsigned short lds[65536];   // 128 KiB
  int tid = threadIdx.x;
  int lane = tid & 63, w = tid >> 6;
  int wm = w >> 2, wn = w & 3;
  int lr = lane & 15, g = lane >> 4;
  int col0 = g * 16;
  int axor = (lr & 7) << 4;
  int lin = blockIdx.x;
  int swz = (lin & 7) * 32 + (lin >> 3);
  int job, s;
  if (swz < 64)       { job = 0; s = swz; }
  else if (swz < 128) { job = 1; s = swz - 64; }
  else                { job = 2; s = swz - 128; }
  int m0 = (s & 15) * 256;
  int n0 = (s >> 4) * 256;
  f32x4 acc[2][2][4][2] = {};

  HPtr hA0, hA1, hB0, hB1;
  if (job == 0) { hinit_sh(hA0, xb, m0, 2048, zpg, tid); hinit_sh(hA1, xb, m0 + 128, 2048, zpg, tid); }
  else          { hinit(hA0, xb, m0, 2048, tid);         hinit(hA1, xb, m0 + 128, 2048, tid); }
  const unsigned short* B = (job == 0) ? w1t0 : (job == 1) ? w1t1 : wvt;
  hinit(hB0, B, n0,       2048, tid);
  hinit(hB1, B, n0 + 128, 2048, tid);
  gemm256_loop<32>(lds, hA0, hA1, hB0, hB1, acc, wm, wn, lr, col0, axor, tid);

  if (job < 2) {
    unsigned short* C = (job == 0) ? o1a : o1b;   // bf16 [4096][1024] partial
    #pragma unroll
    for (int qm = 0; qm < 2; ++qm)
      #pragma unroll
      for (int mi = 0; mi < 4; ++mi) {
        int row0 = m0 + qm*128 + wm*64 + mi*16 + g*4;
        #pragma unroll
        for (int qn = 0; qn < 2; ++qn)
          #pragma unroll
          for (int ni = 0; ni < 2; ++ni) {
            int col = n0 + qn*128 + wn*32 + ni*16 + lr;
            f32x4 a = acc[qm][qn][mi][ni];
            #pragma unroll
            for (int j = 0; j < 4; ++j)
              C[(size_t)(row0 + j) * 1024 + col] = f2b(a[j]);
          }
      }
  } else {
    // Vt layout: [(b*HID + col)][S], rows row0..+3 consecutive s
    #pragma unroll
    for (int qm = 0; qm < 2; ++qm)
      #pragma unroll
      for (int mi = 0; mi < 4; ++mi) {
        int row0 = m0 + qm*128 + wm*64 + mi*16 + g*4;
        int bb = row0 >> 11;
        int s0 = row0 & (S - 1);
        #pragma unroll
        for (int qn = 0; qn < 2; ++qn)
          #pragma unroll
          for (int ni = 0; ni < 2; ++ni) {
            int col = n0 + qn*128 + wn*32 + ni*16 + lr;
            size_t base = ((size_t)bb * HID + col) * S + s0;
            f32x4 a = acc[qm][qn][mi][ni];
            ushort4v pk;
            #pragma unroll
            for (int j = 0; j < 4; ++j) pk[j] = f2b(a[j]);
            *(ushort4v*)(vtg + base) = pk;
          }
      }
  }
}

// ---- duo: conv2-pieceA (shifted o1 @ W2_0) + conv2-pieceB (o1 @ W2_1), uniform K=1024 ----
// Same validated partial-sum pattern as trio (round-15 harness-validated numerics):
// 2 jobs x 128 tiles = 256 uniform 256^2 blocks (16 K-tiles each). Partials in dead qkf.
__launch_bounds__(512, 1)
__global__ void gemm256_duo(const unsigned short* __restrict__ o1,
                            const unsigned short* __restrict__ w2t0,
                            const unsigned short* __restrict__ w2t1,
                            unsigned short* __restrict__ pA,
                            unsigned short* __restrict__ pB,
                            const unsigned short* __restrict__ zpg) {
  __shared__ __align__(16) unsigned short lds[65536];   // 128 KiB
  int tid = threadIdx.x;
  int lane = tid & 63, w = tid >> 6;
  int wm = w >> 2, wn = w & 3;
  int lr = lane & 15, g = lane >> 4;
  int col0 = g * 16;
  int axor = (lr & 7) << 4;
  int lin = blockIdx.x;
  int swz = (lin & 7) * 32 + (lin >> 3);
  int job = swz >> 7;                 // 0: shifted @ W2_0 ; 1: direct @ W2_1
  int s = swz & 127;
  int m0 = (s & 15) * 256;            // 16 M-tiles
  int n0 = (s >> 4) * 256;            // 8 N-tiles
  f32x4 acc[2][2][4][2] = {};

  HPtr hA0, hA1, hB0, hB1;
  if (job == 0) { hinit_sh(hA0, o1, m0, 1024, zpg, tid); hinit_sh(hA1, o1, m0 + 128, 1024, zpg, tid); }
  else          { hinit(hA0, o1, m0, 1024, tid);         hinit(hA1, o1, m0 + 128, 1024, tid); }
  const unsigned short* B = (job == 0) ? w2t0 : w2t1;
  hinit(hB0, B, n0,       1024, tid);
  hinit(hB1, B, n0 + 128, 1024, tid);
  gemm256_loop<16>(lds, hA0, hA1, hB0, hB1, acc, wm, wn, lr, col0, axor, tid);

  unsigned short* C = (job == 0) ? pA : pB;       // bf16 [4096][2048] partial
  #pragma unroll
  for (int qm = 0; qm < 2; ++qm)
    #pragma unroll
    for (int mi = 0; mi < 4; ++mi) {
      int row0 = m0 + qm*128 + wm*64 + mi*16 + g*4;
      #pragma unroll
      for (int qn = 0; qn < 2; ++qn)
        #pragma unroll
        for (int ni = 0; ni < 2; ++ni) {
          int col = n0 + qn*128 + wn*32 + ni*16 + lr;
          f32x4 a = acc[qm][qn][mi][ni];
          #pragma unroll
          for (int j = 0; j < 4; ++j)
            C[(size_t)(row0 + j) * HID + col] = f2b(a[j]);
        }
    }
}

// ---- o1 = o1a + o1b + bias (bf16, 4096x1024) ----
__global__ void add_bias(const unsigned short* __restrict__ a,
                         const unsigned short* __restrict__ b,
                         const unsigned short* __restrict__ bias,
                         unsigned short* __restrict__ o) {
  long i8 = ((long)blockIdx.x * 256 + threadIdx.x) * 8;   // over 4096*1024
  short8 va = *(const short8*)(a + i8);
  short8 vb = *(const short8*)(b + i8);
  short8 wb = *(const short8*)(bias + (i8 & 1023));
  short8 vo;
  #pragma unroll
  for (int e = 0; e < 8; ++e)
    vo[e] = (short)f2b(b2f((unsigned short)va[e]) + b2f((unsigned short)vb[e])
                       + b2f((unsigned short)wb[e]));
  *(short8*)(o + i8) = vo;
}

// ---- fused: hg = rmsnorm(pA + pB + bias + resid) * w  (replaces add pass + rmsnorm) ----
__global__ void rms_fuse(const unsigned short* __restrict__ pA,
                         const unsigned short* __restrict__ pB,
                         const unsigned short* __restrict__ bias,
                         const unsigned short* __restrict__ resid,
                         const unsigned short* __restrict__ w,
                         unsigned short* __restrict__ out) {
  int r = blockIdx.x;
  int c8 = threadIdx.x * 8;               // 256 threads x 8 = 2048
  size_t base = (size_t)r * HID + c8;
  short8 va = *(const short8*)(pA + base);
  short8 vb = *(const short8*)(pB + base);
  short8 vx = *(const short8*)(resid + base);
  short8 vbi = *(const short8*)(bias + c8);
  float f[8];
  float ss = 0.f;
  #pragma unroll
  for (int e = 0; e < 8; ++e) {
    f[e] = b2f((unsigned short)va[e]) + b2f((unsigned short)vb[e])
         + b2f((unsigned short)vbi[e]) + b2f((unsigned short)vx[e]);
    ss += f[e]*f[e];
  }
  #pragma unroll
  for (int o = 32; o; o >>= 1) ss += __shfl_xor(ss, o);
  __shared__ float red[4];
  if ((threadIdx.x & 63) == 0) red[threadIdx.x >> 6] = ss;
  __syncthreads();
  float tot = red[0] + red[1] + red[2] + red[3];
  float scale = rsqrtf(tot / (float)HID + 1e-6f);
  short8 wv = *(const short8*)(w + c8);
  short8 o8;
  #pragma unroll
  for (int e = 0; e < 8; ++e) o8[e] = (short)f2b(f[e] * scale * b2f((unsigned short)wv[e]));
  *(short8*)(out + base) = o8;
}

// ---------------- RoPE from fused qk output [r][4096]; head h = cols h*256..+255 ----------------
__global__ void rope_rearrange(const unsigned short* __restrict__ qkf,
                               const float* __restrict__ ctab, const float* __restrict__ stab,
                               unsigned short* __restrict__ qr, unsigned short* __restrict__ kr) {
  int r = blockIdx.x;
  int t = r & (S - 1);
  int h = threadIdx.x >> 4;
  int i4 = (threadIdx.x & 15) * 4;
  int pc = (i4 & 31) + ((i4 >> 5) << 6);    // permuted col of x1 for elems i4..i4+3 (same 32-block)
  const unsigned short* qk = qkf + (size_t)r * (2*HID) + h * 256;
  f32x4 c = *(const f32x4*)(ctab + t*64 + i4);
  f32x4 s = *(const f32x4*)(stab + t*64 + i4);
  ushort4v q1 = *(const ushort4v*)(qk + pc);
  ushort4v q2 = *(const ushort4v*)(qk + pc + 32);
  ushort4v k1 = *(const ushort4v*)(qk + 128 + pc);
  ushort4v k2 = *(const ushort4v*)(qk + 128 + pc + 32);
  size_t o = (size_t)r * HID + (size_t)h * HD;
  const float SC = 0.08838834764831845f * 1.44269504088896340f;  // 1/sqrt(128) * log2(e)
  ushort4v oq1, oq2, ok1, ok2;
  #pragma unroll
  for (int e = 0; e < 4; ++e) {
    float a = b2f(q1[e]), b = b2f(q2[e]);
    float x = b2f(k1[e]), y = b2f(k2[e]);
    oq1[e] = f2b((a*c[e] - b*s[e]) * SC);
    oq2[e] = f2b((b*c[e] + a*s[e]) * SC);
    ok1[e] = f2b(x*c[e] - y*s[e]);
    ok2[e] = f2b(y*c[e] + x*s[e]);
  }
  *(ushort4v*)(qr + o + i4)      = oq1;
  *(ushort4v*)(qr + o + 64 + i4) = oq2;
  *(ushort4v*)(kr + o + i4)      = ok1;
  *(ushort4v*)(kr + o + 64 + i4) = ok2;
}

// ---------------- MFMA causal flash attention (16x16, DMA-staged, balanced pairs) ----------------
#define KT 64

static __device__ __forceinline__ void attn_pass(
    int qt, int b, int h, unsigned short* lds,
    const unsigned short* __restrict__ Qr, const unsigned short* __restrict__ Kr,
    const unsigned short* __restrict__ Vt, unsigned short* __restrict__ Out) {
  int tid = threadIdx.x, lane = tid & 63, w = tid >> 6;
  int q0 = qt * 64;
  size_t bS = (size_t)b * S;
  size_t ho = (size_t)h * HD;
  int lr = lane & 15, g = lane >> 4;
  int rsw = (lane & 7) << 3;                       // read-side swizzle (ushort units)
  // all waves past previous pass's LDS reads before re-staging the shared buffers
  __syncthreads();
  bf16x8 bq[4];
  {
    int qrow = q0 + w*16 + lr;
    const unsigned short* qp = Qr + (bS + qrow)*HID + ho + g*8;
    #pragma unroll
    for (int kk = 0; kk < 4; ++kk) bq[kk] = *(const bf16x8*)(qp + kk*32);
  }
  // staging pointers (pre-swizzled source cols; advance per tile)
  const unsigned short* kp[4];
  const unsigned short* vp[4];
  #pragma unroll
  for (int j = 0; j < 4; ++j) {
    int c = w*4 + j;                       // chunk 0..15 (1KB each)
    int rk = c*4 + (lane >> 4);            // K row 0..63
    int sck = ((lane & 15) * 8) ^ ((rk & 7) << 3);
    kp[j] = Kr + (bS + rk)*HID + ho + sck;
    int rv = c*8 + (lane >> 3);            // V row (d) 0..127
    int scv = ((lane & 7) * 8) ^ ((rv & 7) << 3);
    vp[j] = Vt + ((size_t)b*HID + ho + rv)*S + scv;
  }
  int cdst = (w*4) * 512;                  // this wave's chunk-group dest (ushorts)
  unsigned short* curK = lds;
  unsigned short* curV = lds + 8192;
  unsigned short* nxtK = lds + 16384;
  unsigned short* nxtV = lds + 24576;
  #pragma unroll
  for (int j = 0; j < 4; ++j) {            // prologue: tile 0 -> cur
    gload_lds16(kp[j], curK + cdst + j*512);
    gload_lds16(vp[j], curV + cdst + j*512);
    kp[j] += (size_t)KT * HID;
    vp[j] += KT;
  }
  f32x4 o[8] = {};                 // O: col(d)=lr+16*ni, row(q_local)=4g+reg
  float m = -1e30f, l = 0.f;
  unsigned short* PlW = lds + 32768 + w*1024;
  int ntiles = qt + 1;
  for (int kt = 0; kt < ntiles; ++kt) {
    // ---- single sync point: own DMA landed, then block-wide barrier ----
    asm volatile("s_waitcnt vmcnt(0)" ::: "memory");
    __builtin_amdgcn_s_barrier();
    asm volatile("" ::: "memory");
    if (kt + 1 < ntiles) {                 // issue next-tile DMA into the other buffer
      #pragma unroll
      for (int j = 0; j < 4; ++j) {
        gload_lds16(kp[j], nxtK + cdst + j*512);
        gload_lds16(vp[j], nxtV + cdst + j*512);
        kp[j] += (size_t)KT * HID;
        vp[j] += KT;
      }
    }
    f32x4 st[4] = {};
    __builtin_amdgcn_s_setprio(1);
    #pragma unroll
    for (int kk = 0; kk < 4; ++kk) {
      #pragma unroll
      for (int mi = 0; mi < 4; ++mi) {
        bf16x8 a = *(const bf16x8*)(&curK[(mi*16 + lr)*128 + ((kk*32 + g*8) ^ rsw)]);
        st[mi] = __builtin_amdgcn_mfma_f32_16x16x32_bf16(a, bq[kk], st[mi], 0, 0, 0);
      }
    }
    __builtin_amdgcn_s_setprio(0);
    bool lastt = (kt == ntiles - 1);
    float tm = -1e30f;
    #pragma unroll
    for (int mi = 0; mi < 4; ++mi)
      #pragma unroll
      for (int r = 0; r < 4; ++r) {
        float v = st[mi][r];
        if (lastt && (mi*16 + 4*g + r) > (w*16 + lr)) v = -1e30f;
        st[mi][r] = v;
        tm = fmaxf(tm, v);
      }
    tm = fmaxf(tm, __shfl_xor(tm, 16));
    tm = fmaxf(tm, __shfl_xor(tm, 32));
    if (!__all(tm - m <= 11.5f)) {
      float mn = fmaxf(m, tm);
      float sc = exp2f(m - mn);
      float s0 = __shfl(sc, 4*g+0), s1 = __shfl(sc, 4*g+1);
      float s2 = __shfl(sc, 4*g+2), s3 = __shfl(sc, 4*g+3);
      #pragma unroll
      for (int ni = 0; ni < 8; ++ni) {
        o[ni][0] *= s0; o[ni][1] *= s1; o[ni][2] *= s2; o[ni][3] *= s3;
      }
      l *= sc;
      m = mn;
    }
    float ts = 0.f;
    __bf16 pbf[4][4];
    #pragma unroll
    for (int mi = 0; mi < 4; ++mi)
      #pragma unroll
      for (int r = 0; r < 4; ++r) {
        float p = exp2f(st[mi][r] - m);
        ts += p;
        pbf[mi][r] = (__bf16)p;
      }
    ts += __shfl_xor(ts, 16);
    ts += __shfl_xor(ts, 32);
    l += ts;
    #pragma unroll
    for (int mi = 0; mi < 4; ++mi) {
      bf16x4 pk = { pbf[mi][0], pbf[mi][1], pbf[mi][2], pbf[mi][3] };
      *(bf16x4*)(&PlW[lr*64 + ((mi*16 + 4*g) ^ rsw)]) = pk;
    }
    asm volatile("" ::: "memory");   // compile-time fence: P stores before P reads
    __builtin_amdgcn_s_setprio(1);
    #pragma unroll
    for (int kk = 0; kk < 2; ++kk) {
      int pc = (kk*32 + g*8) ^ rsw;
      bf16x8 a = *(const bf16x8*)(&PlW[lr*64 + pc]);
      #pragma unroll
      for (int ni = 0; ni < 8; ++ni) {
        bf16x8 bv = *(const bf16x8*)(&curV[(ni*16 + lr)*64 + pc]);
        o[ni] = __builtin_amdgcn_mfma_f32_16x16x32_bf16(a, bv, o[ni], 0, 0, 0);
      }
    }
    __builtin_amdgcn_s_setprio(0);
    unsigned short* t0 = curK; curK = nxtK; nxtK = t0;
    unsigned short* t1 = curV; curV = nxtV; nxtV = t1;
  }
  float l0 = __shfl(l, 4*g+0), l1 = __shfl(l, 4*g+1);
  float l2 = __shfl(l, 4*g+2), l3 = __shfl(l, 4*g+3);
  float i0 = 1.f/l0, i1 = 1.f/l1, i2 = 1.f/l2, i3 = 1.f/l3;
  int rbase = q0 + w*16 + 4*g;
  #pragma unroll
  for (int ni = 0; ni < 8; ++ni) {
    size_t cbase = ho + ni*16 + lr;
    Out[(bS + rbase + 0)*HID + cbase] = f2b(o[ni][0]*i0);
    Out[(bS + rbase + 1)*HID + cbase] = f2b(o[ni][1]*i1);
    Out[(bS + rbase + 2)*HID + cbase] = f2b(o[ni][2]*i2);
    Out[(bS + rbase + 3)*HID + cbase] = f2b(o[ni][3]*i3);
  }
}

__launch_bounds__(256, 2)
__global__ void attn_mfma(const unsigned short* __restrict__ Qr,
                          const unsigned short* __restrict__ Kr,
                          const unsigned short* __restrict__ Vt,
                          unsigned short* __restrict__ Out) {
  // [0,8192) K0 | [8192,16384) V0 | [16384,24576) K1 | [24576,32768) V1 | [32768,36864) P
  __shared__ __align__(16) unsigned short lds[36864];
  int bh = blockIdx.x;
  int b = bh >> 4, h = bh & 15;
  int by = blockIdx.y;                       // 0..15
  attn_pass(31 - by, b, h, lds, Qr, Kr, Vt, Out);   // heavy tile
  attn_pass(by,      b, h, lds, Qr, Kr, Vt, Out);   // light tile; total = 33 KV-tiles/block
}

extern "C" void kernel_launch(void* const* d_in, const int* in_sizes, int n_in,
                              void* d_out, int out_size, void* d_ws, size_t ws_size,
                              hipStream_t stream) {
  const float* x_raw   = (const float*)d_in[0];
  const int* positions = (const int*)d_in[1];
  const float* wq_raw  = (const float*)d_in[2];
  const float* wk_raw  = (const float*)d_in[3];
  const float* wv_raw  = (const float*)d_in[4];
  const float* wo_raw  = (const float*)d_in[5];
  const float* c1w_raw = (const float*)d_in[6];
  const float* c1b_raw = (const float*)d_in[7];
  const float* c2w_raw = (const float*)d_in[8];
  const float* c2b_raw = (const float*)d_in[9];
  const float* rms_raw = (const float*)d_in[10];

  const size_t WS_NEEDED = 140000000;
  if (ws_size < WS_NEEDED) {
    long n = (long)out_size;
    fill_debug<<<dim3((unsigned)((n + 255) / 256)), dim3(256), 0, stream>>>((unsigned short*)d_out, n);
    return;
  }

  char* ws = (char*)d_ws;
  size_t off = 0;
  auto alloc = [&](size_t bytes) { char* p = ws + off; off += (bytes + 255) & ~(size_t)255; return p; };
  float* ctab          = (float*)alloc((size_t)S*64*4);
  float* stab          = (float*)alloc((size_t)S*64*4);
  unsigned short* wqkt = (unsigned short*)alloc((size_t)2*HID*HID*2);  // [wq^T ; wk^T], rope-permuted
  unsigned short* wvt  = (unsigned short*)alloc((size_t)HID*HID*2);
  unsigned short* wot  = (unsigned short*)alloc((size_t)HID*HID*2);
  unsigned short* w1t0 = (unsigned short*)alloc((size_t)1024*HID*2);
  unsigned short* w1t1 = (unsigned short*)alloc((size_t)1024*HID*2);
  unsigned short* w2t0 = (unsigned short*)alloc((size_t)HID*1024*2);
  unsigned short* w2t1 = (unsigned short*)alloc((size_t)HID*1024*2);
  unsigned short* xb   = (unsigned short*)alloc((size_t)ROWS*HID*2);   // reused as kr after conv2
  unsigned short* qrb  = (unsigned short*)alloc((size_t)ROWS*HID*2);   // q rotated
  unsigned short* o1   = (unsigned short*)alloc((size_t)ROWS*1024*2);
  unsigned short* yb   = (unsigned short*)alloc((size_t)ROWS*HID*2);   // attn out buffer
  unsigned short* hg   = (unsigned short*)alloc((size_t)ROWS*HID*2);
  unsigned short* qkf  = (unsigned short*)alloc((size_t)ROWS*2*HID*2); // fused q|k output
  unsigned short* vtg  = (unsigned short*)alloc((size_t)BATCH*HID*S*2);
  unsigned short* c1bb = (unsigned short*)alloc(1024*2);
  unsigned short* c2bb = (unsigned short*)alloc(2048*2);
  unsigned short* rmswb= (unsigned short*)alloc(2048*2);
  unsigned short* zpg  = (unsigned short*)alloc(8192*2);               // zero page (kk-advancing)
  unsigned short* krr  = xb;     // xb dead after rms_fuse (resid read)
  unsigned short* attn = yb;
  unsigned short* o1a  = qkf;                              // conv1 partials in dead qkf
  unsigned short* o1b  = qkf + (size_t)ROWS*1024;
  unsigned short* cpA  = qkf;                              // conv2 partials (after add_bias)
  unsigned short* cpB  = qkf + (size_t)ROWS*HID;

  dim3 b256(256);
  dim3 b512(512);
  prep_all<<<dim3(4096, 4), b256, 0, stream>>>(c1w_raw, c2w_raw, x_raw, positions,
                                               c1b_raw, c2b_raw, rms_raw,
                                               w1t0, w1t1, w2t0, w2t1, xb,
                                               ctab, stab, c1bb, c2bb, rmswb, zpg);
  transpose4<<<dim3(32,32,4), b256, 0, stream>>>(wq_raw, wk_raw, wv_raw, wo_raw,
                                                 wqkt, wqkt + (size_t)HID*HID, wvt, wot);
  // trio (256^2 4-phase, 256 uniform K=2048 blocks): conv1-pieceA/B partials + V-proj
  gemm256_trio<<<dim3(256), b512, 0, stream>>>(xb, w1t0, w1t1, wvt, o1a, o1b, vtg, zpg);
  // o1 = o1a + o1b + bias
  add_bias<<<dim3(ROWS*1024/8/256), b256, 0, stream>>>(o1a, o1b, c1bb, o1);
  // duo (256^2 4-phase, 256 uniform K=1024 blocks): conv2 partials pA = shift(o1)@W2_0,
  // pB = o1@W2_1 (partials overwrite o1a/o1b region after add_bias consumed them)
  gemm256_duo<<<dim3(256), b512, 0, stream>>>(o1, w2t0, w2t1, cpA, cpB, zpg);
  // fused: hg = rmsnorm(pA + pB + b2 + xb) * rmsw  (yb never materialized)
  rms_fuse<<<dim3(ROWS), b256, 0, stream>>>(cpA, cpB, c2bb, xb, rmswb, hg);
  // fused q|k projection (256x256 4-phase + XCD swizzle): qkf = hg @ [wq|wk]  [4096x4096]
  gemm256_bt<<<dim3(ROWS/256, (2*HID)/256), b512, 0, stream>>>(hg, wqkt, qkf, 2*HID);
  rope_rearrange<<<dim3(ROWS), b256, 0, stream>>>(qkf, ctab, stab, qrb, krr);
  attn_mfma<<<dim3(BATCH*HEADS, 16), b256, 0, stream>>>(qrb, krr, vtg, attn);
  // output projection: d_out = attn @ wo^T   [4096 x 2048], f32 out
  gemm8_bt<0><<<dim3(ROWS/128, HID/256), b512, 0, stream>>>(attn, attn, wot, wot, HID, 0, nullptr, nullptr, d_out, 1, HID, nullptr);
}

// Round 17
// 333.718 us; speedup vs baseline: 1.1179x; 1.0160x over previous
//
#include <hip/hip_runtime.h>

#define HID 2048
#define HEADS 16
#define HD 128
#define BATCH 2
#define S 2048
#define ROWS (BATCH*S)

typedef short short8 __attribute__((ext_vector_type(8)));
typedef unsigned short ushort4v __attribute__((ext_vector_type(4)));
typedef unsigned short ushort2v __attribute__((ext_vector_type(2)));
typedef float f32x4 __attribute__((ext_vector_type(4)));
typedef __bf16 bf16x8 __attribute__((ext_vector_type(8)));
typedef __bf16 bf16x4 __attribute__((ext_vector_type(4)));

static __device__ __forceinline__ float b2f(unsigned short u) {
  union { float f; unsigned int i; } v; v.i = ((unsigned int)u) << 16; return v.f;
}
static __device__ __forceinline__ unsigned short f2b(float f) {
  union { float f; unsigned int i; } v; v.f = f;
  unsigned int u = v.i;
  unsigned int r = ((u >> 16) & 1u) + 0x7fffu;
  return (unsigned short)((u + r) >> 16);
}

// async global->LDS, 16B per lane; LDS dest = wave-uniform base + lane*16 (global src is per-lane)
static __device__ __forceinline__ void gload_lds16(const unsigned short* g, unsigned short* l) {
  __builtin_amdgcn_global_load_lds(
      (const __attribute__((address_space(1))) unsigned int*)(const void*)g,
      (__attribute__((address_space(3))) unsigned int*)(void*)l,
      16, 0, 0);
}

// ---------------- debug fill (ws-size canary) ----------------
__global__ void fill_debug(unsigned short* __restrict__ out, long n) {
  long i = (long)blockIdx.x * blockDim.x + threadIdx.x;
  if (i < n) out[i] = 0x447A;  // bf16 1000.0
}

// ---------------- fused prep: conv repacks + x convert + rope tables + small converts ----------
__global__ void prep_all(const float* __restrict__ c1w, const float* __restrict__ c2w,
                         const float* __restrict__ x, const int* __restrict__ positions,
                         const float* __restrict__ c1b, const float* __restrict__ c2b,
                         const float* __restrict__ rmsw,
                         unsigned short* __restrict__ w1t0, unsigned short* __restrict__ w1t1,
                         unsigned short* __restrict__ w2t0, unsigned short* __restrict__ w2t1,
                         unsigned short* __restrict__ xb,
                         float* __restrict__ ctab, float* __restrict__ stab,
                         unsigned short* __restrict__ c1bb, unsigned short* __restrict__ c2bb,
                         unsigned short* __restrict__ rmswb, unsigned short* __restrict__ zpg) {
  int job = blockIdx.y;
  if (job == 0 || job == 1) {
    const float* w = (job == 0) ? c1w : c2w;
    unsigned short* o0 = (job == 0) ? w1t0 : w2t0;
    unsigned short* o1 = (job == 0) ? w1t1 : w2t1;
    long i = (long)blockIdx.x * 256 + threadIdx.x;
    f32x4 v = *(const f32x4*)(w + i*4);
    ushort2v a = { f2b(v[0]), f2b(v[2]) };
    ushort2v b = { f2b(v[1]), f2b(v[3]) };
    *(ushort2v*)(o0 + i*2) = a;
    *(ushort2v*)(o1 + i*2) = b;
  } else if (job == 2) {
    long i = (long)blockIdx.x * 256 + threadIdx.x;
    #pragma unroll
    for (int rep = 0; rep < 2; ++rep) {
      long idx = i + (long)rep * 1048576L;
      f32x4 v = *(const f32x4*)(x + idx*4);
      ushort4v o = { f2b(v[0]), f2b(v[1]), f2b(v[2]), f2b(v[3]) };
      *(ushort4v*)(xb + idx*4) = o;
    }
  } else {
    int bx = blockIdx.x;
    if (bx < 512) {
      int t = bx * 4 + (threadIdx.x >> 6);
      int i = threadIdx.x & 63;
      float pos = (float)positions[t];
      float inv = powf(10000.0f, -(float)i / 64.0f);
      float ang = pos * inv;
      float sv, cv;
      sincosf(ang, &sv, &cv);
      ctab[t*64 + i] = cv;
      stab[t*64 + i] = sv;
    } else if (bx < 544) {
      int i = (bx - 512) * 256 + threadIdx.x;   // 0..8191
      if (i < 1024) c1bb[i] = f2b(c1b[i]);
      if (i < 2048) { c2bb[i] = f2b(c2b[i]); rmswb[i] = f2b(rmsw[i]); }
      zpg[i] = 0;                               // 8192-ushort zero page (kk-advancing reads)
    }
  }
}

// ---------------- 4x 2048x2048 transpose fp32 [K,N] -> bf16 [N,K], one dispatch ----------------
__global__ void transpose4(const float* __restrict__ s0, const float* __restrict__ s1,
                           const float* __restrict__ s2, const float* __restrict__ s3,
                           unsigned short* __restrict__ d0, unsigned short* __restrict__ d1,
                           unsigned short* __restrict__ d2, unsigned short* __restrict__ d3) {
  __shared__ unsigned short tl[64][73];
  const float* in; unsigned short* out; int perm;
  switch (blockIdx.z) {
    case 0:  in = s0; out = d0; perm = 1; break;
    case 1:  in = s1; out = d1; perm = 1; break;
    case 2:  in = s2; out = d2; perm = 0; break;
    default: in = s3; out = d3; perm = 0; break;
  }
  int n0 = blockIdx.x * 64, k0 = blockIdx.y * 64;
  int tid = threadIdx.x;
  int r = tid >> 3, c8 = (tid & 7) * 8;
  #pragma unroll
  for (int j = 0; j < 2; ++j) {
    int rr = r + j*32;
    const float* p = in + (size_t)(k0 + rr)*HID + n0 + c8;
    f32x4 v0 = *(const f32x4*)p;
    f32x4 v1 = *(const f32x4*)(p + 4);
    #pragma unroll
    for (int e = 0; e < 4; ++e) { tl[rr][c8 + e] = f2b(v0[e]); tl[rr][c8 + 4 + e] = f2b(v1[e]); }
  }
  __syncthreads();
  #pragma unroll
  for (int j = 0; j < 2; ++j) {
    int rr = r + j*32;
    int orow = n0 + rr;
    if (perm) {
      int s5 = (orow >> 5) & 3;
      s5 = (s5 == 1) ? 2 : (s5 == 2) ? 1 : s5;
      orow = (orow & ~127) | (s5 << 5) | (orow & 31);
    }
    short8 v;
    #pragma unroll
    for (int e = 0; e < 8; ++e) v[e] = (short)tl[c8 + e][rr];
    *(short8*)(out + (size_t)orow*HID + k0 + c8) = v;
  }
}

// ============ shared GEMM helpers (swizzle proven: bank-conflict 0, rounds 2-16) ============

static __device__ __forceinline__ int swz_scol(int lane) {
  return (((lane & 7) * 16) ^ (((lane >> 3) & 7) << 4)) >> 1;   // swizzled src col (ushorts)
}

static __device__ __forceinline__ void rd_af(const unsigned short* Ah, bf16x8 (&afr)[4][2],
                                             int wm, int lr, int col0, int axor) {
  #pragma unroll
  for (int mi = 0; mi < 4; ++mi) {
    const unsigned short* rp = Ah + (wm*64 + mi*16 + lr) * 64;
    #pragma unroll
    for (int kk = 0; kk < 2; ++kk)
      afr[mi][kk] = *(const bf16x8*)(rp + (((kk*64 + col0) ^ axor) >> 1));
  }
}
static __device__ __forceinline__ void rd_bf(const unsigned short* Bh, bf16x8 (&bfr)[2][2],
                                             int wn, int lr, int col0, int axor) {
  #pragma unroll
  for (int ni = 0; ni < 2; ++ni) {
    const unsigned short* rp = Bh + (wn*32 + ni*16 + lr) * 64;
    #pragma unroll
    for (int kk = 0; kk < 2; ++kk)
      bfr[ni][kk] = *(const bf16x8*)(rp + (((kk*64 + col0) ^ axor) >> 1));
  }
}
static __device__ __forceinline__ void mfma16(const bf16x8 (&afr)[4][2], const bf16x8 (&bfr)[2][2],
                                              f32x4 (&ac)[4][2]) {
  #pragma unroll
  for (int kk = 0; kk < 2; ++kk)
    #pragma unroll
    for (int mi = 0; mi < 4; ++mi)
      #pragma unroll
      for (int ni = 0; ni < 2; ++ni)
        ac[mi][ni] = __builtin_amdgcn_mfma_f32_16x16x32_bf16(afr[mi][kk], bfr[ni][kk], ac[mi][ni], 0, 0, 0);
}

// ================= 128x256-tile GEMM, 3-deep pipeline, compiler-scheduled body =========
// (validated rounds 4-16; used for wo)

struct SPtrs { const unsigned short* p[6]; };

static __device__ __forceinline__ void build_ptrs(SPtrs& sp,
    const unsigned short* Ap, const unsigned short* Bp, int Ksz, int sh,
    int m0, int n0, const unsigned short* zpg, int tid) {
  int lane = tid & 63;
  int scol = swz_scol(lane);
  #pragma unroll
  for (int j = 0; j < 2; ++j) {
    int row = ((tid >> 6) * 2 + j) * 8 + (lane >> 3);               // 0..127
    int gr = m0 + row;
    sp.p[j]     = (sh && ((gr & (S - 1)) == 0)) ? (zpg + scol)
                                                : (Ap + (size_t)(gr - sh)*Ksz + scol);
    sp.p[2 + j] = Bp + (size_t)(n0 + row)*Ksz + scol;
    sp.p[4 + j] = Bp + (size_t)(n0 + 128 + row)*Ksz + scol;
  }
}

static __device__ __forceinline__ void stage6(unsigned short* buf, SPtrs& sp, int tid) {
  int c0 = (tid >> 6) * 1024;            // ushort offset of this wave's 2-chunk pair
  gload_lds16(sp.p[0], buf + c0);
  gload_lds16(sp.p[1], buf + c0 + 512);
  gload_lds16(sp.p[2], buf + 8192  + c0);
  gload_lds16(sp.p[3], buf + 8192  + c0 + 512);
  gload_lds16(sp.p[4], buf + 16384 + c0);
  gload_lds16(sp.p[5], buf + 16384 + c0 + 512);
  #pragma unroll
  for (int i = 0; i < 6; ++i) sp.p[i] += 64;
}

static __device__ __forceinline__ void gemm8_core(
    unsigned short* lds,
    const unsigned short* __restrict__ A1, const unsigned short* __restrict__ A2,
    const unsigned short* __restrict__ B1, const unsigned short* __restrict__ B2,
    int K1, int K2,
    const unsigned short* __restrict__ bias, const unsigned short* __restrict__ resid,
    void* __restrict__ Cout, int outmode, int N, int m0, int n0,
    int a1shift, const unsigned short* __restrict__ zrow) {
  int tid = threadIdx.x;
  int lane = tid & 63, w = tid >> 6;
  int wm = w >> 2, wn = w & 3;
  int lr = lane & 15, g = lane >> 4;
  int col0 = g * 16;
  int axor = (lr & 7) << 4;
  int nk1 = K1 >> 6;
  int nk = (K1 + K2) >> 6;
  f32x4 acc[2][4][2] = {};
  bf16x8 afr[4][2], bfr0[2][2], bfr1[2][2];

  unsigned short* buf0 = lds;            // each buf: A @0, B0 @8192, B1 @16384 (ushorts)
  unsigned short* buf1 = lds + 24576;
  unsigned short* buf2 = lds + 49152;

  SPtrs sp;
  build_ptrs(sp, A1, B1, K1, a1shift, m0, n0, zrow, tid);

  stage6(buf0, sp, tid);
  stage6(buf1, sp, tid);

  unsigned short* cur = buf0;
  unsigned short* nx1 = buf1;
  unsigned short* nx2 = buf2;
  for (int t = 0; t < nk; ++t) {
    if (t < nk - 1) asm volatile("s_waitcnt vmcnt(6)" ::: "memory");
    else            asm volatile("s_waitcnt vmcnt(0)" ::: "memory");
    __builtin_amdgcn_s_barrier();
    asm volatile("" ::: "memory");

    rd_af(cur,         afr,  wm, lr, col0, axor);
    rd_bf(cur + 8192,  bfr0, wn, lr, col0, axor);
    rd_bf(cur + 16384, bfr1, wn, lr, col0, axor);
    if (t + 2 < nk) {
      if (t + 2 == nk1) build_ptrs(sp, A2, B2, K2, 0, m0, n0, zrow, tid);
      stage6(nx2, sp, tid);
    }
    __builtin_amdgcn_s_setprio(1);
    mfma16(afr, bfr0, acc[0]);
    mfma16(afr, bfr1, acc[1]);
    __builtin_amdgcn_s_setprio(0);

    unsigned short* tmp = cur; cur = nx1; nx1 = nx2; nx2 = tmp;
  }

  #pragma unroll
  for (int qn = 0; qn < 2; ++qn)
    #pragma unroll
    for (int mi = 0; mi < 4; ++mi) {
      int row0 = m0 + wm*64 + mi*16 + g*4;
      #pragma unroll
      for (int ni = 0; ni < 2; ++ni) {
        int col = n0 + qn*128 + wn*32 + ni*16 + lr;
        float bv = bias ? b2f(bias[col]) : 0.f;
        f32x4 a = acc[qn][mi][ni];
        #pragma unroll
        for (int j = 0; j < 4; ++j) {
          size_t idx = (size_t)(row0 + j) * N + col;
          float v = a[j] + bv;
          if (resid) v += b2f(resid[idx]);
          if (outmode == 1) ((float*)Cout)[idx] = v;
          else ((unsigned short*)Cout)[idx] = f2b(v);
        }
      }
    }
}

template<int SHIFT>
__launch_bounds__(512, 1)
__global__ void gemm8_bt(const unsigned short* __restrict__ A1,
                         const unsigned short* __restrict__ A2,
                         const unsigned short* __restrict__ B1,
                         const unsigned short* __restrict__ B2,
                         int K1, int K2,
                         const unsigned short* __restrict__ bias,
                         const unsigned short* __restrict__ resid,
                         void* __restrict__ Cout, int outmode, int N,
                         const unsigned short* __restrict__ zrow) {
  __shared__ __align__(16) unsigned short lds[73728];   // 144 KiB, 3 bufs
  gemm8_core(lds, A1, A2, B1, B2, K1, K2, bias, resid, Cout, outmode, N,
             blockIdx.x*128, blockIdx.y*256, SHIFT, zrow);
}

// ============ 256x256-tile 4-phase core (validated rounds 12-16) ============
struct HPtr { const unsigned short* p0; const unsigned short* p1; };
static __device__ __forceinline__ void hinit(HPtr& h, const unsigned short* base,
                                             int row0, int Ksz, int tid) {
  int lane = tid & 63;
  int scol = swz_scol(lane);
  int r0 = ((tid >> 6) * 2) * 8 + (lane >> 3);
  h.p0 = base + (size_t)(row0 + r0) * Ksz + scol;
  h.p1 = base + (size_t)(row0 + r0 + 8) * Ksz + scol;
}
// shifted variant: reads row-1 (zero page at batch starts); zpg reads advance with kk
static __device__ __forceinline__ void hinit_sh(HPtr& h, const unsigned short* base,
                                                int row0, int Ksz,
                                                const unsigned short* zpg, int tid) {
  int lane = tid & 63;
  int scol = swz_scol(lane);
  int r0 = ((tid >> 6) * 2) * 8 + (lane >> 3);
  int g0 = row0 + r0, g1 = row0 + r0 + 8;
  h.p0 = ((g0 & (S - 1)) == 0) ? (zpg + scol) : (base + (size_t)(g0 - 1) * Ksz + scol);
  h.p1 = ((g1 & (S - 1)) == 0) ? (zpg + scol) : (base + (size_t)(g1 - 1) * Ksz + scol);
}
static __device__ __forceinline__ void hstage(unsigned short* slot, HPtr& h, int tid) {
  int c0 = (tid >> 6) * 1024;
  gload_lds16(h.p0, slot + c0);
  gload_lds16(h.p1, slot + c0 + 512);
  h.p0 += 64; h.p1 += 64;
}

// core K-loop (NKT 64-wide K-tiles), shared by qk / trio / duo
template<int NKT>
static __device__ __forceinline__ void gemm256_loop(
    unsigned short* lds, HPtr& hA0, HPtr& hA1, HPtr& hB0, HPtr& hB1,
    f32x4 (&acc)[2][2][4][2], int wm, int wn, int lr, int col0, int axor, int tid) {
  bf16x8 af[4][2], bf0[2][2], bf1[2][2];
  const int nk = NKT;
  // prologue: tile0 {A0,A1,B0,B1} -> buf0 ; tile1 {A0,B0,B1} -> buf1
  hstage(lds + 0,             hA0, tid);
  hstage(lds + 8192,          hA1, tid);
  hstage(lds + 16384,         hB0, tid);
  hstage(lds + 24576,         hB1, tid);
  hstage(lds + 32768 + 0,     hA0, tid);
  hstage(lds + 32768 + 16384, hB0, tid);
  hstage(lds + 32768 + 24576, hB1, tid);
  asm volatile("s_waitcnt vmcnt(6)" ::: "memory");   // tile0 landed; tile1's 3 halves in flight
  __builtin_amdgcn_s_barrier();
  asm volatile("" ::: "memory");

  for (int t = 0; t < nk; ++t) {
    unsigned short* cur = lds + (t & 1) * 32768;
    unsigned short* oth = lds + ((t & 1) ^ 1) * 32768;

    // ---- P1 (qm0,qn0): rd A0(8)+B0(4) ; stage A1(t+1) -> oth ----
    rd_af(cur,         af,  wm, lr, col0, axor);
    rd_bf(cur + 16384, bf0, wn, lr, col0, axor);
    if (t + 1 < nk) hstage(oth + 8192, hA1, tid);
    __builtin_amdgcn_s_barrier();
    asm volatile("s_waitcnt lgkmcnt(0)" ::: "memory");
    __builtin_amdgcn_s_setprio(1);
    mfma16(af, bf0, acc[0][0]);
    __builtin_amdgcn_s_setprio(0);
    __builtin_amdgcn_s_barrier();

    // ---- P2 (qm0,qn1): rd B1(4) (A regs reused) ; stage A0(t+2) -> cur ----
    rd_bf(cur + 24576, bf1, wn, lr, col0, axor);
    if (t + 2 < nk) hstage(cur, hA0, tid);
    __builtin_amdgcn_s_barrier();
    asm volatile("s_waitcnt lgkmcnt(0)" ::: "memory");
    __builtin_amdgcn_s_setprio(1);
    mfma16(af, bf1, acc[0][1]);
    __builtin_amdgcn_s_setprio(0);
    __builtin_amdgcn_s_barrier();

    // ---- P3 (qm1,qn1): rd A1(8) (B1 regs reused) ; stage B0(t+2) -> cur ----
    rd_af(cur + 8192, af, wm, lr, col0, axor);
    if (t + 2 < nk) hstage(cur + 16384, hB0, tid);
    __builtin_amdgcn_s_barrier();
    asm volatile("s_waitcnt lgkmcnt(0)" ::: "memory");
    __builtin_amdgcn_s_setprio(1);
    mfma16(af, bf1, acc[1][1]);
    __builtin_amdgcn_s_setprio(0);
    __builtin_amdgcn_s_barrier();

    // ---- P4 (qm1,qn0): all regs reused ; stage B1(t+2) -> cur ; counted vmcnt ----
    if (t + 2 < nk) hstage(cur + 24576, hB1, tid);
    __builtin_amdgcn_s_barrier();
    asm volatile("s_waitcnt lgkmcnt(0)" ::: "memory");
    __builtin_amdgcn_s_setprio(1);
    mfma16(af, bf0, acc[1][0]);
    __builtin_amdgcn_s_setprio(0);
    if (t + 2 < nk) asm volatile("s_waitcnt vmcnt(6)" ::: "memory");
    else            asm volatile("s_waitcnt vmcnt(0)" ::: "memory");
    __builtin_amdgcn_s_barrier();
    asm volatile("" ::: "memory");
  }
}

// ---- qk projection + FUSED RoPE: block = one head (n0 = h*256; qn0 = q half, qn1 = k half).
// After the K-loop, per (qm,qn): dump acc quadrant to LDS f32 [128][132] (2-way bank alias
// only), __syncthreads, each thread ropes 16 i-values (x1 = L[r][pc], x2 = L[r][pc+32],
// pc = (i&31)+((i>>5)<<6) — identical mapping to the retired rope_rearrange kernel) and
// writes bf16 to qr/kr. Q gets SC = rsqrt(128)*log2e pre-scale. Saves the 64MB rope
// round-trip + a dispatch. LDS is dead after the loop's final full-drain barrier.
__launch_bounds__(512, 1)
__global__ void gemm256_qk_rope(const unsigned short* __restrict__ A,
                                const unsigned short* __restrict__ B,
                                const float* __restrict__ ctab,
                                const float* __restrict__ stab,
                                unsigned short* __restrict__ qr,
                                unsigned short* __restrict__ kr) {
  __shared__ __align__(16) unsigned short lds[65536];   // 128 KiB
  int tid = threadIdx.x;
  int lane = tid & 63, w = tid >> 6;
  int wm = w >> 2, wn = w & 3;
  int lr = lane & 15, g = lane >> 4;
  int col0 = g * 16;
  int axor = (lr & 7) << 4;
  int nwg = gridDim.x * gridDim.y;
  int lin = blockIdx.y * gridDim.x + blockIdx.x;
  int cpx = nwg >> 3;
  int swz = (lin & 7) * cpx + (lin >> 3);
  int m0 = (swz % gridDim.x) * 256, n0 = (swz / gridDim.x) * 256;
  f32x4 acc[2][2][4][2] = {};           // [qm][qn][mi][ni]

  HPtr hA0, hA1, hB0, hB1;
  hinit(hA0, A, m0,       2048, tid);
  hinit(hA1, A, m0 + 128, 2048, tid);
  hinit(hB0, B, n0,       2048, tid);
  hinit(hB1, B, n0 + 128, 2048, tid);
  gemm256_loop<32>(lds, hA0, hA1, hB0, hB1, acc, wm, wn, lr, col0, axor, tid);

  // ---- fused RoPE epilogue ----
  float* L = (float*)lds;                // [128][132] f32 = 67.6KB
  const float SC = 0.08838834764831845f * 1.44269504088896340f;  // 1/sqrt(128) * log2(e)
  int h = n0 >> 8;
  int r2 = tid >> 2;                     // 0..127
  int ib = (tid & 3) * 16;               // i block 0/16/32/48
  #pragma unroll
  for (int qm = 0; qm < 2; ++qm) {
    #pragma unroll
    for (int qn = 0; qn < 2; ++qn) {
      #pragma unroll
      for (int mi = 0; mi < 4; ++mi)
        #pragma unroll
        for (int ni = 0; ni < 2; ++ni) {
          f32x4 a = acc[qm][qn][mi][ni];
          #pragma unroll
          for (int j = 0; j < 4; ++j)
            L[(wm*64 + mi*16 + g*4 + j)*132 + wn*32 + ni*16 + lr] = a[j];
        }
      __syncthreads();
      int rowg = m0 + qm*128 + r2;
      int t = rowg & (S - 1);
      size_t o = (size_t)rowg * HID + (size_t)h * HD;
      unsigned short* dst = (qn == 0) ? qr : kr;
      float sc = (qn == 0) ? SC : 1.0f;
      #pragma unroll
      for (int v4 = 0; v4 < 4; ++v4) {
        ushort4v w1, w2;
        #pragma unroll
        for (int e = 0; e < 4; ++e) {
          int i = ib + v4*4 + e;
          int pc = (i & 31) + ((i >> 5) << 6);
          float x1 = L[r2*132 + pc];
          float x2 = L[r2*132 + pc + 32];
          float cc = ctab[t*64 + i];
          float sn = stab[t*64 + i];
          w1[e] = f2b((x1*cc - x2*sn) * sc);
          w2[e] = f2b((x2*cc + x1*sn) * sc);
        }
        *(ushort4v*)(dst + o + ib + v4*4)      = w1;
        *(ushort4v*)(dst + o + 64 + ib + v4*4) = w2;
      }
      __syncthreads();
    }
  }
}

// ---- trio: conv1-pieceA (shifted) + conv1-pieceB + V-proj, uniform K=2048 (round 15) ----
__launch_bounds__(512, 1)
__global__ void gemm256_trio(const unsigned short* __restrict__ xb,
                             const unsigned short* __restrict__ w1t0,
                             const unsigned short* __restrict__ w1t1,
                             const unsigned short* __restrict__ wvt,
                             unsigned short* __restrict__ o1a,
                             unsigned short* __restrict__ o1b,
                             unsigned short* __restrict__ vtg,
                             const unsigned short* __restrict__ zpg) {
  __shared__ __align__(16) unsigned short lds[65536];   // 128 KiB
  int tid = threadIdx.x;
  int lane = tid & 63, w = tid >> 6;
  int wm = w >> 2, wn = w & 3;
  int lr = lane & 15, g = lane >> 4;
  int col0 = g * 16;
  int axor = (lr & 7) << 4;
  int lin = blockIdx.x;
  int swz = (lin & 7) * 32 + (lin >> 3);
  int job, s;
  if (swz < 64)       { job = 0; s = swz; }
  else if (swz < 128) { job = 1; s = swz - 64; }
  else                { job = 2; s = swz - 128; }
  int m0 = (s & 15) * 256;
  int n0 = (s >> 4) * 256;
  f32x4 acc[2][2][4][2] = {};

  HPtr hA0, hA1, hB0, hB1;
  if (job == 0) { hinit_sh(hA0, xb, m0, 2048, zpg, tid); hinit_sh(hA1, xb, m0 + 128, 2048, zpg, tid); }
  else          { hinit(hA0, xb, m0, 2048, tid);         hinit(hA1, xb, m0 + 128, 2048, tid); }
  const unsigned short* B = (job == 0) ? w1t0 : (job == 1) ? w1t1 : wvt;
  hinit(hB0, B, n0,       2048, tid);
  hinit(hB1, B, n0 + 128, 2048, tid);
  gemm256_loop<32>(lds, hA0, hA1, hB0, hB1, acc, wm, wn, lr, col0, axor, tid);

  if (job < 2) {
    unsigned short* C = (job == 0) ? o1a : o1b;   // bf16 [4096][1024] partial
    #pragma unroll
    for (int qm = 0; qm < 2; ++qm)
      #pragma unroll
      for (int mi = 0; mi < 4; ++mi) {
        int row0 = m0 + qm*128 + wm*64 + mi*16 + g*4;
        #pragma unroll
        for (int qn = 0; qn < 2; ++qn)
          #pragma unroll
          for (int ni = 0; ni < 2; ++ni) {
            int col = n0 + qn*128 + wn*32 + ni*16 + lr;
            f32x4 a = acc[qm][qn][mi][ni];
            #pragma unroll
            for (int j = 0; j < 4; ++j)
              C[(size_t)(row0 + j) * 1024 + col] = f2b(a[j]);
          }
      }
  } else {
    // Vt layout: [(b*HID + col)][S], rows row0..+3 consecutive s
    #pragma unroll
    for (int qm = 0; qm < 2; ++qm)
      #pragma unroll
      for (int mi = 0; mi < 4; ++mi) {
        int row0 = m0 + qm*128 + wm*64 + mi*16 + g*4;
        int bb = row0 >> 11;
        int s0 = row0 & (S - 1);
        #pragma unroll
        for (int qn = 0; qn < 2; ++qn)
          #pragma unroll
          for (int ni = 0; ni < 2; ++ni) {
            int col = n0 + qn*128 + wn*32 + ni*16 + lr;
            size_t base = ((size_t)bb * HID + col) * S + s0;
            f32x4 a = acc[qm][qn][mi][ni];
            ushort4v pk;
            #pragma unroll
            for (int j = 0; j < 4; ++j) pk[j] = f2b(a[j]);
            *(ushort4v*)(vtg + base) = pk;
          }
      }
  }
}

// ---- duo: conv2-pieceA (shifted o1 @ W2_0) + conv2-pieceB (o1 @ W2_1), uniform K=1024 ----
__launch_bounds__(512, 1)
__global__ void gemm256_duo(const unsigned short* __restrict__ o1,
                            const unsigned short* __restrict__ w2t0,
                            const unsigned short* __restrict__ w2t1,
                            unsigned short* __restrict__ pA,
                            unsigned short* __restrict__ pB,
                            const unsigned short* __restrict__ zpg) {
  __shared__ __align__(16) unsigned short lds[65536];   // 128 KiB
  int tid = threadIdx.x;
  int lane = tid & 63, w = tid >> 6;
  int wm = w >> 2, wn = w & 3;
  int lr = lane & 15, g = lane >> 4;
  int col0 = g * 16;
  int axor = (lr & 7) << 4;
  int lin = blockIdx.x;
  int swz = (lin & 7) * 32 + (lin >> 3);
  int job = swz >> 7;                 // 0: shifted @ W2_0 ; 1: direct @ W2_1
  int s = swz & 127;
  int m0 = (s & 15) * 256;            // 16 M-tiles
  int n0 = (s >> 4) * 256;            // 8 N-tiles
  f32x4 acc[2][2][4][2] = {};

  HPtr hA0, hA1, hB0, hB1;
  if (job == 0) { hinit_sh(hA0, o1, m0, 1024, zpg, tid); hinit_sh(hA1, o1, m0 + 128, 1024, zpg, tid); }
  else          { hinit(hA0, o1, m0, 1024, tid);         hinit(hA1, o1, m0 + 128, 1024, tid); }
  const unsigned short* B = (job == 0) ? w2t0 : w2t1;
  hinit(hB0, B, n0,       1024, tid);
  hinit(hB1, B, n0 + 128, 1024, tid);
  gemm256_loop<16>(lds, hA0, hA1, hB0, hB1, acc, wm, wn, lr, col0, axor, tid);

  unsigned short* C = (job == 0) ? pA : pB;       // bf16 [4096][2048] partial
  #pragma unroll
  for (int qm = 0; qm < 2; ++qm)
    #pragma unroll
    for (int mi = 0; mi < 4; ++mi) {
      int row0 = m0 + qm*128 + wm*64 + mi*16 + g*4;
      #pragma unroll
      for (int qn = 0; qn < 2; ++qn)
        #pragma unroll
        for (int ni = 0; ni < 2; ++ni) {
          int col = n0 + qn*128 + wn*32 + ni*16 + lr;
          f32x4 a = acc[qm][qn][mi][ni];
          #pragma unroll
          for (int j = 0; j < 4; ++j)
            C[(size_t)(row0 + j) * HID + col] = f2b(a[j]);
        }
    }
}

// ---- o1 = o1a + o1b + bias (bf16, 4096x1024) ----
__global__ void add_bias(const unsigned short* __restrict__ a,
                         const unsigned short* __restrict__ b,
                         const unsigned short* __restrict__ bias,
                         unsigned short* __restrict__ o) {
  long i8 = ((long)blockIdx.x * 256 + threadIdx.x) * 8;   // over 4096*1024
  short8 va = *(const short8*)(a + i8);
  short8 vb = *(const short8*)(b + i8);
  short8 wb = *(const short8*)(bias + (i8 & 1023));
  short8 vo;
  #pragma unroll
  for (int e = 0; e < 8; ++e)
    vo[e] = (short)f2b(b2f((unsigned short)va[e]) + b2f((unsigned short)vb[e])
                       + b2f((unsigned short)wb[e]));
  *(short8*)(o + i8) = vo;
}

// ---- fused: hg = rmsnorm(pA + pB + bias + resid) * w  (replaces add pass + rmsnorm) ----
__global__ void rms_fuse(const unsigned short* __restrict__ pA,
                         const unsigned short* __restrict__ pB,
                         const unsigned short* __restrict__ bias,
                         const unsigned short* __restrict__ resid,
                         const unsigned short* __restrict__ w,
                         unsigned short* __restrict__ out) {
  int r = blockIdx.x;
  int c8 = threadIdx.x * 8;               // 256 threads x 8 = 2048
  size_t base = (size_t)r * HID + c8;
  short8 va = *(const short8*)(pA + base);
  short8 vb = *(const short8*)(pB + base);
  short8 vx = *(const short8*)(resid + base);
  short8 vbi = *(const short8*)(bias + c8);
  float f[8];
  float ss = 0.f;
  #pragma unroll
  for (int e = 0; e < 8; ++e) {
    f[e] = b2f((unsigned short)va[e]) + b2f((unsigned short)vb[e])
         + b2f((unsigned short)vbi[e]) + b2f((unsigned short)vx[e]);
    ss += f[e]*f[e];
  }
  #pragma unroll
  for (int o = 32; o; o >>= 1) ss += __shfl_xor(ss, o);
  __shared__ float red[4];
  if ((threadIdx.x & 63) == 0) red[threadIdx.x >> 6] = ss;
  __syncthreads();
  float tot = red[0] + red[1] + red[2] + red[3];
  float scale = rsqrtf(tot / (float)HID + 1e-6f);
  short8 wv = *(const short8*)(w + c8);
  short8 o8;
  #pragma unroll
  for (int e = 0; e < 8; ++e) o8[e] = (short)f2b(f[e] * scale * b2f((unsigned short)wv[e]));
  *(short8*)(out + base) = o8;
}

// ---------------- MFMA causal flash attention (16x16, DMA-staged, balanced pairs) ----------------
#define KT 64

static __device__ __forceinline__ void attn_pass(
    int qt, int b, int h, unsigned short* lds,
    const unsigned short* __restrict__ Qr, const unsigned short* __restrict__ Kr,
    const unsigned short* __restrict__ Vt, unsigned short* __restrict__ Out) {
  int tid = threadIdx.x, lane = tid & 63, w = tid >> 6;
  int q0 = qt * 64;
  size_t bS = (size_t)b * S;
  size_t ho = (size_t)h * HD;
  int lr = lane & 15, g = lane >> 4;
  int rsw = (lane & 7) << 3;                       // read-side swizzle (ushort units)
  // all waves past previous pass's LDS reads before re-staging the shared buffers
  __syncthreads();
  bf16x8 bq[4];
  {
    int qrow = q0 + w*16 + lr;
    const unsigned short* qp = Qr + (bS + qrow)*HID + ho + g*8;
    #pragma unroll
    for (int kk = 0; kk < 4; ++kk) bq[kk] = *(const bf16x8*)(qp + kk*32);
  }
  // staging pointers (pre-swizzled source cols; advance per tile)
  const unsigned short* kp[4];
  const unsigned short* vp[4];
  #pragma unroll
  for (int j = 0; j < 4; ++j) {
    int c = w*4 + j;                       // chunk 0..15 (1KB each)
    int rk = c*4 + (lane >> 4);            // K row 0..63
    int sck = ((lane & 15) * 8) ^ ((rk & 7) << 3);
    kp[j] = Kr + (bS + rk)*HID + ho + sck;
    int rv = c*8 + (lane >> 3);            // V row (d) 0..127
    int scv = ((lane & 7) * 8) ^ ((rv & 7) << 3);
    vp[j] = Vt + ((size_t)b*HID + ho + rv)*S + scv;
  }
  int cdst = (w*4) * 512;                  // this wave's chunk-group dest (ushorts)
  unsigned short* curK = lds;
  unsigned short* curV = lds + 8192;
  unsigned short* nxtK = lds + 16384;
  unsigned short* nxtV = lds + 24576;
  #pragma unroll
  for (int j = 0; j < 4; ++j) {            // prologue: tile 0 -> cur
    gload_lds16(kp[j], curK + cdst + j*512);
    gload_lds16(vp[j], curV + cdst + j*512);
    kp[j] += (size_t)KT * HID;
    vp[j] += KT;
  }
  f32x4 o[8] = {};                 // O: col(d)=lr+16*ni, row(q_local)=4g+reg
  float m = -1e30f, l = 0.f;
  unsigned short* PlW = lds + 32768 + w*1024;
  int ntiles = qt + 1;
  for (int kt = 0; kt < ntiles; ++kt) {
    // ---- single sync point: own DMA landed, then block-wide barrier ----
    asm volatile("s_waitcnt vmcnt(0)" ::: "memory");
    __builtin_amdgcn_s_barrier();
    asm volatile("" ::: "memory");
    if (kt + 1 < ntiles) {                 // issue next-tile DMA into the other buffer
      #pragma unroll
      for (int j = 0; j < 4; ++j) {
        gload_lds16(kp[j], nxtK + cdst + j*512);
        gload_lds16(vp[j], nxtV + cdst + j*512);
        kp[j] += (size_t)KT * HID;
        vp[j] += KT;
      }
    }
    f32x4 st[4] = {};
    __builtin_amdgcn_s_setprio(1);
    #pragma unroll
    for (int kk = 0; kk < 4; ++kk) {
      #pragma unroll
      for (int mi = 0; mi < 4; ++mi) {
        bf16x8 a = *(const bf16x8*)(&curK[(mi*16 + lr)*128 + ((kk*32 + g*8) ^ rsw)]);
        st[mi] = __builtin_amdgcn_mfma_f32_16x16x32_bf16(a, bq[kk], st[mi], 0, 0, 0);
      }
    }
    __builtin_amdgcn_s_setprio(0);
    bool lastt = (kt == ntiles - 1);
    float tm = -1e30f;
    #pragma unroll
    for (int mi = 0; mi < 4; ++mi)
      #pragma unroll
      for (int r = 0; r < 4; ++r) {
        float v = st[mi][r];
        if (lastt && (mi*16 + 4*g + r) > (w*16 + lr)) v = -1e30f;
        st[mi][r] = v;
        tm = fmaxf(tm, v);
      }
    tm = fmaxf(tm, __shfl_xor(tm, 16));
    tm = fmaxf(tm, __shfl_xor(tm, 32));
    if (!__all(tm - m <= 11.5f)) {
      float mn = fmaxf(m, tm);
      float sc = exp2f(m - mn);
      float s0 = __shfl(sc, 4*g+0), s1 = __shfl(sc, 4*g+1);
      float s2 = __shfl(sc, 4*g+2), s3 = __shfl(sc, 4*g+3);
      #pragma unroll
      for (int ni = 0; ni < 8; ++ni) {
        o[ni][0] *= s0; o[ni][1] *= s1; o[ni][2] *= s2; o[ni][3] *= s3;
      }
      l *= sc;
      m = mn;
    }
    float ts = 0.f;
    __bf16 pbf[4][4];
    #pragma unroll
    for (int mi = 0; mi < 4; ++mi)
      #pragma unroll
      for (int r = 0; r < 4; ++r) {
        float p = exp2f(st[mi][r] - m);
        ts += p;
        pbf[mi][r] = (__bf16)p;
      }
    ts += __shfl_xor(ts, 16);
    ts += __shfl_xor(ts, 32);
    l += ts;
    #pragma unroll
    for (int mi = 0; mi < 4; ++mi) {
      bf16x4 pk = { pbf[mi][0], pbf[mi][1], pbf[mi][2], pbf[mi][3] };
      *(bf16x4*)(&PlW[lr*64 + ((mi*16 + 4*g) ^ rsw)]) = pk;
    }
    asm volatile("" ::: "memory");   // compile-time fence: P stores before P reads
    __builtin_amdgcn_s_setprio(1);
    #pragma unroll
    for (int kk = 0; kk < 2; ++kk) {
      int pc = (kk*32 + g*8) ^ rsw;
      bf16x8 a = *(const bf16x8*)(&PlW[lr*64 + pc]);
      #pragma unroll
      for (int ni = 0; ni < 8; ++ni) {
        bf16x8 bv = *(const bf16x8*)(&curV[(ni*16 + lr)*64 + pc]);
        o[ni] = __builtin_amdgcn_mfma_f32_16x16x32_bf16(a, bv, o[ni], 0, 0, 0);
      }
    }
    __builtin_amdgcn_s_setprio(0);
    unsigned short* t0 = curK; curK = nxtK; nxtK = t0;
    unsigned short* t1 = curV; curV = nxtV; nxtV = t1;
  }
  float l0 = __shfl(l, 4*g+0), l1 = __shfl(l, 4*g+1);
  float l2 = __shfl(l, 4*g+2), l3 = __shfl(l, 4*g+3);
  float i0 = 1.f/l0, i1 = 1.f/l1, i2 = 1.f/l2, i3 = 1.f/l3;
  int rbase = q0 + w*16 + 4*g;
  #pragma unroll
  for (int ni = 0; ni < 8; ++ni) {
    size_t cbase = ho + ni*16 + lr;
    Out[(bS + rbase + 0)*HID + cbase] = f2b(o[ni][0]*i0);
    Out[(bS + rbase + 1)*HID + cbase] = f2b(o[ni][1]*i1);
    Out[(bS + rbase + 2)*HID + cbase] = f2b(o[ni][2]*i2);
    Out[(bS + rbase + 3)*HID + cbase] = f2b(o[ni][3]*i3);
  }
}

__launch_bounds__(256, 2)
__global__ void attn_mfma(const unsigned short* __restrict__ Qr,
                          const unsigned short* __restrict__ Kr,
                          const unsigned short* __restrict__ Vt,
                          unsigned short* __restrict__ Out) {
  // [0,8192) K0 | [8192,16384) V0 | [16384,24576) K1 | [24576,32768) V1 | [32768,36864) P
  __shared__ __align__(16) unsigned short lds[36864];
  int bh = blockIdx.x;
  int b = bh >> 4, h = bh & 15;
  int by = blockIdx.y;                       // 0..15
  attn_pass(31 - by, b, h, lds, Qr, Kr, Vt, Out);   // heavy tile
  attn_pass(by,      b, h, lds, Qr, Kr, Vt, Out);   // light tile; total = 33 KV-tiles/block
}

extern "C" void kernel_launch(void* const* d_in, const int* in_sizes, int n_in,
                              void* d_out, int out_size, void* d_ws, size_t ws_size,
                              hipStream_t stream) {
  const float* x_raw   = (const float*)d_in[0];
  const int* positions = (const int*)d_in[1];
  const float* wq_raw  = (const float*)d_in[2];
  const float* wk_raw  = (const float*)d_in[3];
  const float* wv_raw  = (const float*)d_in[4];
  const float* wo_raw  = (const float*)d_in[5];
  const float* c1w_raw = (const float*)d_in[6];
  const float* c1b_raw = (const float*)d_in[7];
  const float* c2w_raw = (const float*)d_in[8];
  const float* c2b_raw = (const float*)d_in[9];
  const float* rms_raw = (const float*)d_in[10];

  const size_t WS_NEEDED = 140000000;
  if (ws_size < WS_NEEDED) {
    long n = (long)out_size;
    fill_debug<<<dim3((unsigned)((n + 255) / 256)), dim3(256), 0, stream>>>((unsigned short*)d_out, n);
    return;
  }

  char* ws = (char*)d_ws;
  size_t off = 0;
  auto alloc = [&](size_t bytes) { char* p = ws + off; off += (bytes + 255) & ~(size_t)255; return p; };
  float* ctab          = (float*)alloc((size_t)S*64*4);
  float* stab          = (float*)alloc((size_t)S*64*4);
  unsigned short* wqkt = (unsigned short*)alloc((size_t)2*HID*HID*2);  // [wq^T ; wk^T], rope-permuted
  unsigned short* wvt  = (unsigned short*)alloc((size_t)HID*HID*2);
  unsigned short* wot  = (unsigned short*)alloc((size_t)HID*HID*2);
  unsigned short* w1t0 = (unsigned short*)alloc((size_t)1024*HID*2);
  unsigned short* w1t1 = (unsigned short*)alloc((size_t)1024*HID*2);
  unsigned short* w2t0 = (unsigned short*)alloc((size_t)HID*1024*2);
  unsigned short* w2t1 = (unsigned short*)alloc((size_t)HID*1024*2);
  unsigned short* xb   = (unsigned short*)alloc((size_t)ROWS*HID*2);   // resid for rms_fuse; reused as kr
  unsigned short* qrb  = (unsigned short*)alloc((size_t)ROWS*HID*2);   // q rotated
  unsigned short* o1   = (unsigned short*)alloc((size_t)ROWS*1024*2);
  unsigned short* yb   = (unsigned short*)alloc((size_t)ROWS*HID*2);   // attn out buffer
  unsigned short* hg   = (unsigned short*)alloc((size_t)ROWS*HID*2);
  unsigned short* qkf  = (unsigned short*)alloc((size_t)ROWS*2*HID*2); // partial scratch (trio/duo)
  unsigned short* vtg  = (unsigned short*)alloc((size_t)BATCH*HID*S*2);
  unsigned short* c1bb = (unsigned short*)alloc(1024*2);
  unsigned short* c2bb = (unsigned short*)alloc(2048*2);
  unsigned short* rmswb= (unsigned short*)alloc(2048*2);
  unsigned short* zpg  = (unsigned short*)alloc(8192*2);               // zero page (kk-advancing)
  unsigned short* krr  = xb;     // xb dead after rms_fuse (resid read)
  unsigned short* attn = yb;
  unsigned short* o1a  = qkf;                              // conv1 partials in qkf scratch
  unsigned short* o1b  = qkf + (size_t)ROWS*1024;
  unsigned short* cpA  = qkf;                              // conv2 partials (after add_bias)
  unsigned short* cpB  = qkf + (size_t)ROWS*HID;

  dim3 b256(256);
  dim3 b512(512);
  prep_all<<<dim3(4096, 4), b256, 0, stream>>>(c1w_raw, c2w_raw, x_raw, positions,
                                               c1b_raw, c2b_raw, rms_raw,
                                               w1t0, w1t1, w2t0, w2t1, xb,
                                               ctab, stab, c1bb, c2bb, rmswb, zpg);
  transpose4<<<dim3(32,32,4), b256, 0, stream>>>(wq_raw, wk_raw, wv_raw, wo_raw,
                                                 wqkt, wqkt + (size_t)HID*HID, wvt, wot);
  // trio (256^2 4-phase, 256 uniform K=2048 blocks): conv1-pieceA/B partials + V-proj
  gemm256_trio<<<dim3(256), b512, 0, stream>>>(xb, w1t0, w1t1, wvt, o1a, o1b, vtg, zpg);
  // o1 = o1a + o1b + bias
  add_bias<<<dim3(ROWS*1024/8/256), b256, 0, stream>>>(o1a, o1b, c1bb, o1);
  // duo (256^2 4-phase, 256 uniform K=1024 blocks): conv2 partials
  gemm256_duo<<<dim3(256), b512, 0, stream>>>(o1, w2t0, w2t1, cpA, cpB, zpg);
  // fused: hg = rmsnorm(pA + pB + b2 + xb) * rmsw
  rms_fuse<<<dim3(ROWS), b256, 0, stream>>>(cpA, cpB, c2bb, xb, rmswb, hg);
  // fused q|k projection + RoPE (256x256 4-phase + XCD swizzle): qrb/krr directly
  gemm256_qk_rope<<<dim3(ROWS/256, (2*HID)/256), b512, 0, stream>>>(hg, wqkt, ctab, stab, qrb, krr);
  attn_mfma<<<dim3(BATCH*HEADS, 16), b256, 0, stream>>>(qrb, krr, vtg, attn);
  // output projection: d_out = attn @ wo^T   [4096 x 2048], f32 out
  gemm8_bt<0><<<dim3(ROWS/128, HID/256), b512, 0, stream>>>(attn, attn, wot, wot, HID, 0, nullptr, nullptr, d_out, 1, HID, nullptr);
}

// Round 18
// 329.665 us; speedup vs baseline: 1.1316x; 1.0123x over previous
//
#include <hip/hip_runtime.h>

#define HID 2048
#define HEADS 16
#define HD 128
#define BATCH 2
#define S 2048
#define ROWS (BATCH*S)

typedef short short8 __attribute__((ext_vector_type(8)));
typedef unsigned short ushort4v __attribute__((ext_vector_type(4)));
typedef unsigned short ushort2v __attribute__((ext_vector_type(2)));
typedef float f32x4 __attribute__((ext_vector_type(4)));
typedef __bf16 bf16x8 __attribute__((ext_vector_type(8)));
typedef __bf16 bf16x4 __attribute__((ext_vector_type(4)));

static __device__ __forceinline__ float b2f(unsigned short u) {
  union { float f; unsigned int i; } v; v.i = ((unsigned int)u) << 16; return v.f;
}
static __device__ __forceinline__ unsigned short f2b(float f) {
  union { float f; unsigned int i; } v; v.f = f;
  unsigned int u = v.i;
  unsigned int r = ((u >> 16) & 1u) + 0x7fffu;
  return (unsigned short)((u + r) >> 16);
}

// async global->LDS, 16B per lane; LDS dest = wave-uniform base + lane*16 (global src is per-lane)
static __device__ __forceinline__ void gload_lds16(const unsigned short* g, unsigned short* l) {
  __builtin_amdgcn_global_load_lds(
      (const __attribute__((address_space(1))) unsigned int*)(const void*)g,
      (__attribute__((address_space(3))) unsigned int*)(void*)l,
      16, 0, 0);
}

// ---------------- debug fill (ws-size canary) ----------------
__global__ void fill_debug(unsigned short* __restrict__ out, long n) {
  long i = (long)blockIdx.x * blockDim.x + threadIdx.x;
  if (i < n) out[i] = 0x447A;  // bf16 1000.0
}

// ---- merged prep: conv repacks + x convert + rope tables + converts + 4x weight transpose ----
// grid (4096, 5): y 0..3 = original prep jobs; y == 4 = the 4 weight transposes
// (mat = bx>>10, tile = ((bx>>5)&31, bx&31)).
__global__ void prep_combined(const float* __restrict__ c1w, const float* __restrict__ c2w,
                              const float* __restrict__ x, const int* __restrict__ positions,
                              const float* __restrict__ c1b, const float* __restrict__ c2b,
                              const float* __restrict__ rmsw,
                              const float* __restrict__ wq, const float* __restrict__ wk,
                              const float* __restrict__ wv, const float* __restrict__ wo,
                              unsigned short* __restrict__ w1t0, unsigned short* __restrict__ w1t1,
                              unsigned short* __restrict__ w2t0, unsigned short* __restrict__ w2t1,
                              unsigned short* __restrict__ xb,
                              float* __restrict__ ctab, float* __restrict__ stab,
                              unsigned short* __restrict__ c1bb, unsigned short* __restrict__ c2bb,
                              unsigned short* __restrict__ rmswb, unsigned short* __restrict__ zpg,
                              unsigned short* __restrict__ wqkt, unsigned short* __restrict__ wvt,
                              unsigned short* __restrict__ wot) {
  int job = blockIdx.y;
  if (job == 0 || job == 1) {
    const float* w = (job == 0) ? c1w : c2w;
    unsigned short* o0 = (job == 0) ? w1t0 : w2t0;
    unsigned short* o1 = (job == 0) ? w1t1 : w2t1;
    long i = (long)blockIdx.x * 256 + threadIdx.x;
    f32x4 v = *(const f32x4*)(w + i*4);
    ushort2v a = { f2b(v[0]), f2b(v[2]) };
    ushort2v b = { f2b(v[1]), f2b(v[3]) };
    *(ushort2v*)(o0 + i*2) = a;
    *(ushort2v*)(o1 + i*2) = b;
  } else if (job == 2) {
    long i = (long)blockIdx.x * 256 + threadIdx.x;
    #pragma unroll
    for (int rep = 0; rep < 2; ++rep) {
      long idx = i + (long)rep * 1048576L;
      f32x4 v = *(const f32x4*)(x + idx*4);
      ushort4v o = { f2b(v[0]), f2b(v[1]), f2b(v[2]), f2b(v[3]) };
      *(ushort4v*)(xb + idx*4) = o;
    }
  } else if (job == 3) {
    int bx = blockIdx.x;
    if (bx < 512) {
      int t = bx * 4 + (threadIdx.x >> 6);
      int i = threadIdx.x & 63;
      float pos = (float)positions[t];
      float inv = powf(10000.0f, -(float)i / 64.0f);
      float ang = pos * inv;
      float sv, cv;
      sincosf(ang, &sv, &cv);
      ctab[t*64 + i] = cv;
      stab[t*64 + i] = sv;
    } else if (bx < 544) {
      int i = (bx - 512) * 256 + threadIdx.x;   // 0..8191
      if (i < 1024) c1bb[i] = f2b(c1b[i]);
      if (i < 2048) { c2bb[i] = f2b(c2b[i]); rmswb[i] = f2b(rmsw[i]); }
      zpg[i] = 0;                               // 8192-ushort zero page (kk-advancing reads)
    }
  } else {
    // ---- weight transpose fp32 [K,N] -> bf16 [N,K] (4 matrices) ----
    __shared__ unsigned short tl[64][73];
    int bx = blockIdx.x;
    int mat = bx >> 10;
    int tx = (bx >> 5) & 31, ty = bx & 31;
    const float* in; unsigned short* out; int perm;
    switch (mat) {
      case 0:  in = wq; out = wqkt;                       perm = 1; break;
      case 1:  in = wk; out = wqkt + (size_t)HID*HID;     perm = 1; break;
      case 2:  in = wv; out = wvt;                        perm = 0; break;
      default: in = wo; out = wot;                        perm = 0; break;
    }
    int n0 = tx * 64, k0 = ty * 64;
    int tid = threadIdx.x;
    int r = tid >> 3, c8 = (tid & 7) * 8;
    #pragma unroll
    for (int j = 0; j < 2; ++j) {
      int rr = r + j*32;
      const float* p = in + (size_t)(k0 + rr)*HID + n0 + c8;
      f32x4 v0 = *(const f32x4*)p;
      f32x4 v1 = *(const f32x4*)(p + 4);
      #pragma unroll
      for (int e = 0; e < 4; ++e) { tl[rr][c8 + e] = f2b(v0[e]); tl[rr][c8 + 4 + e] = f2b(v1[e]); }
    }
    __syncthreads();
    #pragma unroll
    for (int j = 0; j < 2; ++j) {
      int rr = r + j*32;
      int orow = n0 + rr;
      if (perm) {
        int s5 = (orow >> 5) & 3;
        s5 = (s5 == 1) ? 2 : (s5 == 2) ? 1 : s5;
        orow = (orow & ~127) | (s5 << 5) | (orow & 31);
      }
      short8 v;
      #pragma unroll
      for (int e = 0; e < 8; ++e) v[e] = (short)tl[c8 + e][rr];
      *(short8*)(out + (size_t)orow*HID + k0 + c8) = v;
    }
  }
}

// ============ shared GEMM helpers (swizzle proven: bank-conflict 0, rounds 2-17) ============

static __device__ __forceinline__ int swz_scol(int lane) {
  return (((lane & 7) * 16) ^ (((lane >> 3) & 7) << 4)) >> 1;   // swizzled src col (ushorts)
}

static __device__ __forceinline__ void rd_af(const unsigned short* Ah, bf16x8 (&afr)[4][2],
                                             int wm, int lr, int col0, int axor) {
  #pragma unroll
  for (int mi = 0; mi < 4; ++mi) {
    const unsigned short* rp = Ah + (wm*64 + mi*16 + lr) * 64;
    #pragma unroll
    for (int kk = 0; kk < 2; ++kk)
      afr[mi][kk] = *(const bf16x8*)(rp + (((kk*64 + col0) ^ axor) >> 1));
  }
}
static __device__ __forceinline__ void rd_bf(const unsigned short* Bh, bf16x8 (&bfr)[2][2],
                                             int wn, int lr, int col0, int axor) {
  #pragma unroll
  for (int ni = 0; ni < 2; ++ni) {
    const unsigned short* rp = Bh + (wn*32 + ni*16 + lr) * 64;
    #pragma unroll
    for (int kk = 0; kk < 2; ++kk)
      bfr[ni][kk] = *(const bf16x8*)(rp + (((kk*64 + col0) ^ axor) >> 1));
  }
}
static __device__ __forceinline__ void mfma16(const bf16x8 (&afr)[4][2], const bf16x8 (&bfr)[2][2],
                                              f32x4 (&ac)[4][2]) {
  #pragma unroll
  for (int kk = 0; kk < 2; ++kk)
    #pragma unroll
    for (int mi = 0; mi < 4; ++mi)
      #pragma unroll
      for (int ni = 0; ni < 2; ++ni)
        ac[mi][ni] = __builtin_amdgcn_mfma_f32_16x16x32_bf16(afr[mi][kk], bfr[ni][kk], ac[mi][ni], 0, 0, 0);
}

// ================= 128x256-tile GEMM, 3-deep pipeline, compiler-scheduled body =========
// (validated rounds 4-17; used for wo)

struct SPtrs { const unsigned short* p[6]; };

static __device__ __forceinline__ void build_ptrs(SPtrs& sp,
    const unsigned short* Ap, const unsigned short* Bp, int Ksz, int sh,
    int m0, int n0, const unsigned short* zpg, int tid) {
  int lane = tid & 63;
  int scol = swz_scol(lane);
  #pragma unroll
  for (int j = 0; j < 2; ++j) {
    int row = ((tid >> 6) * 2 + j) * 8 + (lane >> 3);               // 0..127
    int gr = m0 + row;
    sp.p[j]     = (sh && ((gr & (S - 1)) == 0)) ? (zpg + scol)
                                                : (Ap + (size_t)(gr - sh)*Ksz + scol);
    sp.p[2 + j] = Bp + (size_t)(n0 + row)*Ksz + scol;
    sp.p[4 + j] = Bp + (size_t)(n0 + 128 + row)*Ksz + scol;
  }
}

static __device__ __forceinline__ void stage6(unsigned short* buf, SPtrs& sp, int tid) {
  int c0 = (tid >> 6) * 1024;            // ushort offset of this wave's 2-chunk pair
  gload_lds16(sp.p[0], buf + c0);
  gload_lds16(sp.p[1], buf + c0 + 512);
  gload_lds16(sp.p[2], buf + 8192  + c0);
  gload_lds16(sp.p[3], buf + 8192  + c0 + 512);
  gload_lds16(sp.p[4], buf + 16384 + c0);
  gload_lds16(sp.p[5], buf + 16384 + c0 + 512);
  #pragma unroll
  for (int i = 0; i < 6; ++i) sp.p[i] += 64;
}

static __device__ __forceinline__ void gemm8_core(
    unsigned short* lds,
    const unsigned short* __restrict__ A1, const unsigned short* __restrict__ A2,
    const unsigned short* __restrict__ B1, const unsigned short* __restrict__ B2,
    int K1, int K2,
    const unsigned short* __restrict__ bias, const unsigned short* __restrict__ resid,
    void* __restrict__ Cout, int outmode, int N, int m0, int n0,
    int a1shift, const unsigned short* __restrict__ zrow) {
  int tid = threadIdx.x;
  int lane = tid & 63, w = tid >> 6;
  int wm = w >> 2, wn = w & 3;
  int lr = lane & 15, g = lane >> 4;
  int col0 = g * 16;
  int axor = (lr & 7) << 4;
  int nk1 = K1 >> 6;
  int nk = (K1 + K2) >> 6;
  f32x4 acc[2][4][2] = {};
  bf16x8 afr[4][2], bfr0[2][2], bfr1[2][2];

  unsigned short* buf0 = lds;            // each buf: A @0, B0 @8192, B1 @16384 (ushorts)
  unsigned short* buf1 = lds + 24576;
  unsigned short* buf2 = lds + 49152;

  SPtrs sp;
  build_ptrs(sp, A1, B1, K1, a1shift, m0, n0, zrow, tid);

  stage6(buf0, sp, tid);
  stage6(buf1, sp, tid);

  unsigned short* cur = buf0;
  unsigned short* nx1 = buf1;
  unsigned short* nx2 = buf2;
  for (int t = 0; t < nk; ++t) {
    if (t < nk - 1) asm volatile("s_waitcnt vmcnt(6)" ::: "memory");
    else            asm volatile("s_waitcnt vmcnt(0)" ::: "memory");
    __builtin_amdgcn_s_barrier();
    asm volatile("" ::: "memory");

    rd_af(cur,         afr,  wm, lr, col0, axor);
    rd_bf(cur + 8192,  bfr0, wn, lr, col0, axor);
    rd_bf(cur + 16384, bfr1, wn, lr, col0, axor);
    if (t + 2 < nk) {
      if (t + 2 == nk1) build_ptrs(sp, A2, B2, K2, 0, m0, n0, zrow, tid);
      stage6(nx2, sp, tid);
    }
    __builtin_amdgcn_s_setprio(1);
    mfma16(afr, bfr0, acc[0]);
    mfma16(afr, bfr1, acc[1]);
    __builtin_amdgcn_s_setprio(0);

    unsigned short* tmp = cur; cur = nx1; nx1 = nx2; nx2 = tmp;
  }

  #pragma unroll
  for (int qn = 0; qn < 2; ++qn)
    #pragma unroll
    for (int mi = 0; mi < 4; ++mi) {
      int row0 = m0 + wm*64 + mi*16 + g*4;
      #pragma unroll
      for (int ni = 0; ni < 2; ++ni) {
        int col = n0 + qn*128 + wn*32 + ni*16 + lr;
        float bv = bias ? b2f(bias[col]) : 0.f;
        f32x4 a = acc[qn][mi][ni];
        #pragma unroll
        for (int j = 0; j < 4; ++j) {
          size_t idx = (size_t)(row0 + j) * N + col;
          float v = a[j] + bv;
          if (resid) v += b2f(resid[idx]);
          if (outmode == 1) ((float*)Cout)[idx] = v;
          else ((unsigned short*)Cout)[idx] = f2b(v);
        }
      }
    }
}

template<int SHIFT>
__launch_bounds__(512, 1)
__global__ void gemm8_bt(const unsigned short* __restrict__ A1,
                         const unsigned short* __restrict__ A2,
                         const unsigned short* __restrict__ B1,
                         const unsigned short* __restrict__ B2,
                         int K1, int K2,
                         const unsigned short* __restrict__ bias,
                         const unsigned short* __restrict__ resid,
                         void* __restrict__ Cout, int outmode, int N,
                         const unsigned short* __restrict__ zrow) {
  __shared__ __align__(16) unsigned short lds[73728];   // 144 KiB, 3 bufs
  gemm8_core(lds, A1, A2, B1, B2, K1, K2, bias, resid, Cout, outmode, N,
             blockIdx.x*128, blockIdx.y*256, SHIFT, zrow);
}

// ============ 256x256-tile 4-phase core (validated rounds 12-17) ============
struct HPtr { const unsigned short* p0; const unsigned short* p1; };
static __device__ __forceinline__ void hinit(HPtr& h, const unsigned short* base,
                                             int row0, int Ksz, int tid) {
  int lane = tid & 63;
  int scol = swz_scol(lane);
  int r0 = ((tid >> 6) * 2) * 8 + (lane >> 3);
  h.p0 = base + (size_t)(row0 + r0) * Ksz + scol;
  h.p1 = base + (size_t)(row0 + r0 + 8) * Ksz + scol;
}
// shifted variant: reads row-1 (zero page at batch starts); zpg reads advance with kk
static __device__ __forceinline__ void hinit_sh(HPtr& h, const unsigned short* base,
                                                int row0, int Ksz,
                                                const unsigned short* zpg, int tid) {
  int lane = tid & 63;
  int scol = swz_scol(lane);
  int r0 = ((tid >> 6) * 2) * 8 + (lane >> 3);
  int g0 = row0 + r0, g1 = row0 + r0 + 8;
  h.p0 = ((g0 & (S - 1)) == 0) ? (zpg + scol) : (base + (size_t)(g0 - 1) * Ksz + scol);
  h.p1 = ((g1 & (S - 1)) == 0) ? (zpg + scol) : (base + (size_t)(g1 - 1) * Ksz + scol);
}
static __device__ __forceinline__ void hstage(unsigned short* slot, HPtr& h, int tid) {
  int c0 = (tid >> 6) * 1024;
  gload_lds16(h.p0, slot + c0);
  gload_lds16(h.p1, slot + c0 + 512);
  h.p0 += 64; h.p1 += 64;
}

// core K-loop (NKT 64-wide K-tiles), shared by qk / trio / duo
template<int NKT>
static __device__ __forceinline__ void gemm256_loop(
    unsigned short* lds, HPtr& hA0, HPtr& hA1, HPtr& hB0, HPtr& hB1,
    f32x4 (&acc)[2][2][4][2], int wm, int wn, int lr, int col0, int axor, int tid) {
  bf16x8 af[4][2], bf0[2][2], bf1[2][2];
  const int nk = NKT;
  // prologue: tile0 {A0,A1,B0,B1} -> buf0 ; tile1 {A0,B0,B1} -> buf1
  hstage(lds + 0,             hA0, tid);
  hstage(lds + 8192,          hA1, tid);
  hstage(lds + 16384,         hB0, tid);
  hstage(lds + 24576,         hB1, tid);
  hstage(lds + 32768 + 0,     hA0, tid);
  hstage(lds + 32768 + 16384, hB0, tid);
  hstage(lds + 32768 + 24576, hB1, tid);
  asm volatile("s_waitcnt vmcnt(6)" ::: "memory");   // tile0 landed; tile1's 3 halves in flight
  __builtin_amdgcn_s_barrier();
  asm volatile("" ::: "memory");

  for (int t = 0; t < nk; ++t) {
    unsigned short* cur = lds + (t & 1) * 32768;
    unsigned short* oth = lds + ((t & 1) ^ 1) * 32768;

    // ---- P1 (qm0,qn0): rd A0(8)+B0(4) ; stage A1(t+1) -> oth ----
    rd_af(cur,         af,  wm, lr, col0, axor);
    rd_bf(cur + 16384, bf0, wn, lr, col0, axor);
    if (t + 1 < nk) hstage(oth + 8192, hA1, tid);
    __builtin_amdgcn_s_barrier();
    asm volatile("s_waitcnt lgkmcnt(0)" ::: "memory");
    __builtin_amdgcn_s_setprio(1);
    mfma16(af, bf0, acc[0][0]);
    __builtin_amdgcn_s_setprio(0);
    __builtin_amdgcn_s_barrier();

    // ---- P2 (qm0,qn1): rd B1(4) (A regs reused) ; stage A0(t+2) -> cur ----
    rd_bf(cur + 24576, bf1, wn, lr, col0, axor);
    if (t + 2 < nk) hstage(cur, hA0, tid);
    __builtin_amdgcn_s_barrier();
    asm volatile("s_waitcnt lgkmcnt(0)" ::: "memory");
    __builtin_amdgcn_s_setprio(1);
    mfma16(af, bf1, acc[0][1]);
    __builtin_amdgcn_s_setprio(0);
    __builtin_amdgcn_s_barrier();

    // ---- P3 (qm1,qn1): rd A1(8) (B1 regs reused) ; stage B0(t+2) -> cur ----
    rd_af(cur + 8192, af, wm, lr, col0, axor);
    if (t + 2 < nk) hstage(cur + 16384, hB0, tid);
    __builtin_amdgcn_s_barrier();
    asm volatile("s_waitcnt lgkmcnt(0)" ::: "memory");
    __builtin_amdgcn_s_setprio(1);
    mfma16(af, bf1, acc[1][1]);
    __builtin_amdgcn_s_setprio(0);
    __builtin_amdgcn_s_barrier();

    // ---- P4 (qm1,qn0): all regs reused ; stage B1(t+2) -> cur ; counted vmcnt ----
    if (t + 2 < nk) hstage(cur + 24576, hB1, tid);
    __builtin_amdgcn_s_barrier();
    asm volatile("s_waitcnt lgkmcnt(0)" ::: "memory");
    __builtin_amdgcn_s_setprio(1);
    mfma16(af, bf0, acc[1][0]);
    __builtin_amdgcn_s_setprio(0);
    if (t + 2 < nk) asm volatile("s_waitcnt vmcnt(6)" ::: "memory");
    else            asm volatile("s_waitcnt vmcnt(0)" ::: "memory");
    __builtin_amdgcn_s_barrier();
    asm volatile("" ::: "memory");
  }
}

// ---- qk projection + FUSED RoPE (validated round 17) ----
__launch_bounds__(512, 1)
__global__ void gemm256_qk_rope(const unsigned short* __restrict__ A,
                                const unsigned short* __restrict__ B,
                                const float* __restrict__ ctab,
                                const float* __restrict__ stab,
                                unsigned short* __restrict__ qr,
                                unsigned short* __restrict__ kr) {
  __shared__ __align__(16) unsigned short lds[65536];   // 128 KiB
  int tid = threadIdx.x;
  int lane = tid & 63, w = tid >> 6;
  int wm = w >> 2, wn = w & 3;
  int lr = lane & 15, g = lane >> 4;
  int col0 = g * 16;
  int axor = (lr & 7) << 4;
  int nwg = gridDim.x * gridDim.y;
  int lin = blockIdx.y * gridDim.x + blockIdx.x;
  int cpx = nwg >> 3;
  int swz = (lin & 7) * cpx + (lin >> 3);
  int m0 = (swz % gridDim.x) * 256, n0 = (swz / gridDim.x) * 256;
  f32x4 acc[2][2][4][2] = {};           // [qm][qn][mi][ni]

  HPtr hA0, hA1, hB0, hB1;
  hinit(hA0, A, m0,       2048, tid);
  hinit(hA1, A, m0 + 128, 2048, tid);
  hinit(hB0, B, n0,       2048, tid);
  hinit(hB1, B, n0 + 128, 2048, tid);
  gemm256_loop<32>(lds, hA0, hA1, hB0, hB1, acc, wm, wn, lr, col0, axor, tid);

  // ---- fused RoPE epilogue ----
  float* L = (float*)lds;                // [128][132] f32 = 67.6KB
  const float SC = 0.08838834764831845f * 1.44269504088896340f;  // 1/sqrt(128) * log2(e)
  int h = n0 >> 8;
  int r2 = tid >> 2;                     // 0..127
  int ib = (tid & 3) * 16;               // i block 0/16/32/48
  #pragma unroll
  for (int qm = 0; qm < 2; ++qm) {
    #pragma unroll
    for (int qn = 0; qn < 2; ++qn) {
      #pragma unroll
      for (int mi = 0; mi < 4; ++mi)
        #pragma unroll
        for (int ni = 0; ni < 2; ++ni) {
          f32x4 a = acc[qm][qn][mi][ni];
          #pragma unroll
          for (int j = 0; j < 4; ++j)
            L[(wm*64 + mi*16 + g*4 + j)*132 + wn*32 + ni*16 + lr] = a[j];
        }
      __syncthreads();
      int rowg = m0 + qm*128 + r2;
      int t = rowg & (S - 1);
      size_t o = (size_t)rowg * HID + (size_t)h * HD;
      unsigned short* dst = (qn == 0) ? qr : kr;
      float sc = (qn == 0) ? SC : 1.0f;
      #pragma unroll
      for (int v4 = 0; v4 < 4; ++v4) {
        ushort4v w1, w2;
        #pragma unroll
        for (int e = 0; e < 4; ++e) {
          int i = ib + v4*4 + e;
          int pc = (i & 31) + ((i >> 5) << 6);
          float x1 = L[r2*132 + pc];
          float x2 = L[r2*132 + pc + 32];
          float cc = ctab[t*64 + i];
          float sn = stab[t*64 + i];
          w1[e] = f2b((x1*cc - x2*sn) * sc);
          w2[e] = f2b((x2*cc + x1*sn) * sc);
        }
        *(ushort4v*)(dst + o + ib + v4*4)      = w1;
        *(ushort4v*)(dst + o + 64 + ib + v4*4) = w2;
      }
      __syncthreads();
    }
  }
}

// ---- trio: conv1-pieceA (shifted) + conv1-pieceB + V-proj, uniform K=2048 ----
// Round 18: job2 (Vt) epilogue rewritten to LDS-transpose + s-coalesced writes
// (qk_rope pattern). Old path wrote 8B fragments at 4KB stride -> up to 8x HBM write
// amplification. New: dump quadrant f32 [128][133] (133%32=5 -> 2 lanes/bank = free),
// wave w writes cols w*16..+15 with lane = s-local: 64x2B = 128B contiguous per store.
// Quadrants never straddle a batch (m0 multiple of 256). Bit-identical values.
__launch_bounds__(512, 1)
__global__ void gemm256_trio(const unsigned short* __restrict__ xb,
                             const unsigned short* __restrict__ w1t0,
                             const unsigned short* __restrict__ w1t1,
                             const unsigned short* __restrict__ wvt,
                             unsigned short* __restrict__ o1a,
                             unsigned short* __restrict__ o1b,
                             unsigned short* __restrict__ vtg,
                             const unsigned short* __restrict__ zpg) {
  __shared__ __align__(16) unsigned short lds[68608];   // max(128KB loop, 68.1KB epi) = 134 KiB... loop needs 64K ushorts
  // NOTE: loop uses 65536 ushorts (128KB); epilogue reuses as f32[128][133] = 68,096B. 65536*2=131072B >= both.
  int tid = threadIdx.x;
  int lane = tid & 63, w = tid >> 6;
  int wm = w >> 2, wn = w & 3;
  int lr = lane & 15, g = lane >> 4;
  int col0 = g * 16;
  int axor = (lr & 7) << 4;
  int lin = blockIdx.x;
  int swz = (lin & 7) * 32 + (lin >> 3);
  int job, s;
  if (swz < 64)       { job = 0; s = swz; }
  else if (swz < 128) { job = 1; s = swz - 64; }
  else                { job = 2; s = swz - 128; }
  int m0 = (s & 15) * 256;
  int n0 = (s >> 4) * 256;
  f32x4 acc[2][2][4][2] = {};

  HPtr hA0, hA1, hB0, hB1;
  if (job == 0) { hinit_sh(hA0, xb, m0, 2048, zpg, tid); hinit_sh(hA1, xb, m0 + 128, 2048, zpg, tid); }
  else          { hinit(hA0, xb, m0, 2048, tid);         hinit(hA1, xb, m0 + 128, 2048, tid); }
  const unsigned short* B = (job == 0) ? w1t0 : (job == 1) ? w1t1 : wvt;
  hinit(hB0, B, n0,       2048, tid);
  hinit(hB1, B, n0 + 128, 2048, tid);
  gemm256_loop<32>(lds, hA0, hA1, hB0, hB1, acc, wm, wn, lr, col0, axor, tid);

  if (job < 2) {
    unsigned short* C = (job == 0) ? o1a : o1b;   // bf16 [4096][1024] partial
    #pragma unroll
    for (int qm = 0; qm < 2; ++qm)
      #pragma unroll
      for (int mi = 0; mi < 4; ++mi) {
        int row0 = m0 + qm*128 + wm*64 + mi*16 + g*4;
        #pragma unroll
        for (int qn = 0; qn < 2; ++qn)
          #pragma unroll
          for (int ni = 0; ni < 2; ++ni) {
            int col = n0 + qn*128 + wn*32 + ni*16 + lr;
            f32x4 a = acc[qm][qn][mi][ni];
            #pragma unroll
            for (int j = 0; j < 4; ++j)
              C[(size_t)(row0 + j) * 1024 + col] = f2b(a[j]);
          }
      }
  } else {
    // ---- Vt epilogue: LDS transpose -> s-coalesced writes ----
    float* L = (float*)lds;               // [128][133] f32
    #pragma unroll
    for (int qm = 0; qm < 2; ++qm) {
      #pragma unroll
      for (int qn = 0; qn < 2; ++qn) {
        #pragma unroll
        for (int mi = 0; mi < 4; ++mi)
          #pragma unroll
          for (int ni = 0; ni < 2; ++ni) {
            f32x4 a = acc[qm][qn][mi][ni];
            #pragma unroll
            for (int j = 0; j < 4; ++j)
              L[(wm*64 + mi*16 + g*4 + j)*133 + wn*32 + ni*16 + lr] = a[j];
          }
        __syncthreads();
        int rowg0 = m0 + qm*128;          // quadrant s base (never straddles batch)
        int bb = rowg0 >> 11;
        int s0q = rowg0 & (S - 1);
        int dg0 = n0 + qn*128;            // quadrant d base
        #pragma unroll
        for (int cl = 0; cl < 16; ++cl) {
          int col = w*16 + cl;
          size_t vbase = ((size_t)bb * HID + dg0 + col) * S + s0q;
          vtg[vbase + lane]      = f2b(L[lane*133 + col]);
          vtg[vbase + 64 + lane] = f2b(L[(64 + lane)*133 + col]);
        }
        __syncthreads();
      }
    }
  }
}

// ---- duo: conv2-pieceA (shifted o1 @ W2_0) + conv2-pieceB (o1 @ W2_1), uniform K=1024 ----
__launch_bounds__(512, 1)
__global__ void gemm256_duo(const unsigned short* __restrict__ o1,
                            const unsigned short* __restrict__ w2t0,
                            const unsigned short* __restrict__ w2t1,
                            unsigned short* __restrict__ pA,
                            unsigned short* __restrict__ pB,
                            const unsigned short* __restrict__ zpg) {
  __shared__ __align__(16) unsigned short lds[65536];   // 128 KiB
  int tid = threadIdx.x;
  int lane = tid & 63, w = tid >> 6;
  int wm = w >> 2, wn = w & 3;
  int lr = lane & 15, g = lane >> 4;
  int col0 = g * 16;
  int axor = (lr & 7) << 4;
  int lin = blockIdx.x;
  int swz = (lin & 7) * 32 + (lin >> 3);
  int job = swz >> 7;                 // 0: shifted @ W2_0 ; 1: direct @ W2_1
  int s = swz & 127;
  int m0 = (s & 15) * 256;            // 16 M-tiles
  int n0 = (s >> 4) * 256;            // 8 N-tiles
  f32x4 acc[2][2][4][2] = {};

  HPtr hA0, hA1, hB0, hB1;
  if (job == 0) { hinit_sh(hA0, o1, m0, 1024, zpg, tid); hinit_sh(hA1, o1, m0 + 128, 1024, zpg, tid); }
  else          { hinit(hA0, o1, m0, 1024, tid);         hinit(hA1, o1, m0 + 128, 1024, tid); }
  const unsigned short* B = (job == 0) ? w2t0 : w2t1;
  hinit(hB0, B, n0,       1024, tid);
  hinit(hB1, B, n0 + 128, 1024, tid);
  gemm256_loop<16>(lds, hA0, hA1, hB0, hB1, acc, wm, wn, lr, col0, axor, tid);

  unsigned short* C = (job == 0) ? pA : pB;       // bf16 [4096][2048] partial
  #pragma unroll
  for (int qm = 0; qm < 2; ++qm)
    #pragma unroll
    for (int mi = 0; mi < 4; ++mi) {
      int row0 = m0 + qm*128 + wm*64 + mi*16 + g*4;
      #pragma unroll
      for (int qn = 0; qn < 2; ++qn)
        #pragma unroll
        for (int ni = 0; ni < 2; ++ni) {
          int col = n0 + qn*128 + wn*32 + ni*16 + lr;
          f32x4 a = acc[qm][qn][mi][ni];
          #pragma unroll
          for (int j = 0; j < 4; ++j)
            C[(size_t)(row0 + j) * HID + col] = f2b(a[j]);
        }
    }
}

// ---- o1 = o1a + o1b + bias (bf16, 4096x1024) ----
__global__ void add_bias(const unsigned short* __restrict__ a,
                         const unsigned short* __restrict__ b,
                         const unsigned short* __restrict__ bias,
                         unsigned short* __restrict__ o) {
  long i8 = ((long)blockIdx.x * 256 + threadIdx.x) * 8;   // over 4096*1024
  short8 va = *(const short8*)(a + i8);
  short8 vb = *(const short8*)(b + i8);
  short8 wb = *(const short8*)(bias + (i8 & 1023));
  short8 vo;
  #pragma unroll
  for (int e = 0; e < 8; ++e)
    vo[e] = (short)f2b(b2f((unsigned short)va[e]) + b2f((unsigned short)vb[e])
                       + b2f((unsigned short)wb[e]));
  *(short8*)(o + i8) = vo;
}

// ---- fused: hg = rmsnorm(pA + pB + bias + resid) * w ----
__global__ void rms_fuse(const unsigned short* __restrict__ pA,
                         const unsigned short* __restrict__ pB,
                         const unsigned short* __restrict__ bias,
                         const unsigned short* __restrict__ resid,
                         const unsigned short* __restrict__ w,
                         unsigned short* __restrict__ out) {
  int r = blockIdx.x;
  int c8 = threadIdx.x * 8;               // 256 threads x 8 = 2048
  size_t base = (size_t)r * HID + c8;
  short8 va = *(const short8*)(pA + base);
  short8 vb = *(const short8*)(pB + base);
  short8 vx = *(const short8*)(resid + base);
  short8 vbi = *(const short8*)(bias + c8);
  float f[8];
  float ss = 0.f;
  #pragma unroll
  for (int e = 0; e < 8; ++e) {
    f[e] = b2f((unsigned short)va[e]) + b2f((unsigned short)vb[e])
         + b2f((unsigned short)vbi[e]) + b2f((unsigned short)vx[e]);
    ss += f[e]*f[e];
  }
  #pragma unroll
  for (int o = 32; o; o >>= 1) ss += __shfl_xor(ss, o);
  __shared__ float red[4];
  if ((threadIdx.x & 63) == 0) red[threadIdx.x >> 6] = ss;
  __syncthreads();
  float tot = red[0] + red[1] + red[2] + red[3];
  float scale = rsqrtf(tot / (float)HID + 1e-6f);
  short8 wv = *(const short8*)(w + c8);
  short8 o8;
  #pragma unroll
  for (int e = 0; e < 8; ++e) o8[e] = (short)f2b(f[e] * scale * b2f((unsigned short)wv[e]));
  *(short8*)(out + base) = o8;
}

// ---------------- MFMA causal flash attention (16x16, DMA-staged, balanced pairs) ----------------
#define KT 64

static __device__ __forceinline__ void attn_pass(
    int qt, int b, int h, unsigned short* lds,
    const unsigned short* __restrict__ Qr, const unsigned short* __restrict__ Kr,
    const unsigned short* __restrict__ Vt, unsigned short* __restrict__ Out) {
  int tid = threadIdx.x, lane = tid & 63, w = tid >> 6;
  int q0 = qt * 64;
  size_t bS = (size_t)b * S;
  size_t ho = (size_t)h * HD;
  int lr = lane & 15, g = lane >> 4;
  int rsw = (lane & 7) << 3;                       // read-side swizzle (ushort units)
  // all waves past previous pass's LDS reads before re-staging the shared buffers
  __syncthreads();
  bf16x8 bq[4];
  {
    int qrow = q0 + w*16 + lr;
    const unsigned short* qp = Qr + (bS + qrow)*HID + ho + g*8;
    #pragma unroll
    for (int kk = 0; kk < 4; ++kk) bq[kk] = *(const bf16x8*)(qp + kk*32);
  }
  // staging pointers (pre-swizzled source cols; advance per tile)
  const unsigned short* kp[4];
  const unsigned short* vp[4];
  #pragma unroll
  for (int j = 0; j < 4; ++j) {
    int c = w*4 + j;                       // chunk 0..15 (1KB each)
    int rk = c*4 + (lane >> 4);            // K row 0..63
    int sck = ((lane & 15) * 8) ^ ((rk & 7) << 3);
    kp[j] = Kr + (bS + rk)*HID + ho + sck;
    int rv = c*8 + (lane >> 3);            // V row (d) 0..127
    int scv = ((lane & 7) * 8) ^ ((rv & 7) << 3);
    vp[j] = Vt + ((size_t)b*HID + ho + rv)*S + scv;
  }
  int cdst = (w*4) * 512;                  // this wave's chunk-group dest (ushorts)
  unsigned short* curK = lds;
  unsigned short* curV = lds + 8192;
  unsigned short* nxtK = lds + 16384;
  unsigned short* nxtV = lds + 24576;
  #pragma unroll
  for (int j = 0; j < 4; ++j) {            // prologue: tile 0 -> cur
    gload_lds16(kp[j], curK + cdst + j*512);
    gload_lds16(vp[j], curV + cdst + j*512);
    kp[j] += (size_t)KT * HID;
    vp[j] += KT;
  }
  f32x4 o[8] = {};                 // O: col(d)=lr+16*ni, row(q_local)=4g+reg
  float m = -1e30f, l = 0.f;
  unsigned short* PlW = lds + 32768 + w*1024;
  int ntiles = qt + 1;
  for (int kt = 0; kt < ntiles; ++kt) {
    // ---- single sync point: own DMA landed, then block-wide barrier ----
    asm volatile("s_waitcnt vmcnt(0)" ::: "memory");
    __builtin_amdgcn_s_barrier();
    asm volatile("" ::: "memory");
    if (kt + 1 < ntiles) {                 // issue next-tile DMA into the other buffer
      #pragma unroll
      for (int j = 0; j < 4; ++j) {
        gload_lds16(kp[j], nxtK + cdst + j*512);
        gload_lds16(vp[j], nxtV + cdst + j*512);
        kp[j] += (size_t)KT * HID;
        vp[j] += KT;
      }
    }
    f32x4 st[4] = {};
    __builtin_amdgcn_s_setprio(1);
    #pragma unroll
    for (int kk = 0; kk < 4; ++kk) {
      #pragma unroll
      for (int mi = 0; mi < 4; ++mi) {
        bf16x8 a = *(const bf16x8*)(&curK[(mi*16 + lr)*128 + ((kk*32 + g*8) ^ rsw)]);
        st[mi] = __builtin_amdgcn_mfma_f32_16x16x32_bf16(a, bq[kk], st[mi], 0, 0, 0);
      }
    }
    __builtin_amdgcn_s_setprio(0);
    bool lastt = (kt == ntiles - 1);
    float tm = -1e30f;
    #pragma unroll
    for (int mi = 0; mi < 4; ++mi)
      #pragma unroll
      for (int r = 0; r < 4; ++r) {
        float v = st[mi][r];
        if (lastt && (mi*16 + 4*g + r) > (w*16 + lr)) v = -1e30f;
        st[mi][r] = v;
        tm = fmaxf(tm, v);
      }
    tm = fmaxf(tm, __shfl_xor(tm, 16));
    tm = fmaxf(tm, __shfl_xor(tm, 32));
    if (!__all(tm - m <= 11.5f)) {
      float mn = fmaxf(m, tm);
      float sc = exp2f(m - mn);
      float s0 = __shfl(sc, 4*g+0), s1 = __shfl(sc, 4*g+1);
      float s2 = __shfl(sc, 4*g+2), s3 = __shfl(sc, 4*g+3);
      #pragma unroll
      for (int ni = 0; ni < 8; ++ni) {
        o[ni][0] *= s0; o[ni][1] *= s1; o[ni][2] *= s2; o[ni][3] *= s3;
      }
      l *= sc;
      m = mn;
    }
    float ts = 0.f;
    __bf16 pbf[4][4];
    #pragma unroll
    for (int mi = 0; mi < 4; ++mi)
      #pragma unroll
      for (int r = 0; r < 4; ++r) {
        float p = exp2f(st[mi][r] - m);
        ts += p;
        pbf[mi][r] = (__bf16)p;
      }
    ts += __shfl_xor(ts, 16);
    ts += __shfl_xor(ts, 32);
    l += ts;
    #pragma unroll
    for (int mi = 0; mi < 4; ++mi) {
      bf16x4 pk = { pbf[mi][0], pbf[mi][1], pbf[mi][2], pbf[mi][3] };
      *(bf16x4*)(&PlW[lr*64 + ((mi*16 + 4*g) ^ rsw)]) = pk;
    }
    asm volatile("" ::: "memory");   // compile-time fence: P stores before P reads
    __builtin_amdgcn_s_setprio(1);
    #pragma unroll
    for (int kk = 0; kk < 2; ++kk) {
      int pc = (kk*32 + g*8) ^ rsw;
      bf16x8 a = *(const bf16x8*)(&PlW[lr*64 + pc]);
      #pragma unroll
      for (int ni = 0; ni < 8; ++ni) {
        bf16x8 bv = *(const bf16x8*)(&curV[(ni*16 + lr)*64 + pc]);
        o[ni] = __builtin_amdgcn_mfma_f32_16x16x32_bf16(a, bv, o[ni], 0, 0, 0);
      }
    }
    __builtin_amdgcn_s_setprio(0);
    unsigned short* t0 = curK; curK = nxtK; nxtK = t0;
    unsigned short* t1 = curV; curV = nxtV; nxtV = t1;
  }
  float l0 = __shfl(l, 4*g+0), l1 = __shfl(l, 4*g+1);
  float l2 = __shfl(l, 4*g+2), l3 = __shfl(l, 4*g+3);
  float i0 = 1.f/l0, i1 = 1.f/l1, i2 = 1.f/l2, i3 = 1.f/l3;
  int rbase = q0 + w*16 + 4*g;
  #pragma unroll
  for (int ni = 0; ni < 8; ++ni) {
    size_t cbase = ho + ni*16 + lr;
    Out[(bS + rbase + 0)*HID + cbase] = f2b(o[ni][0]*i0);
    Out[(bS + rbase + 1)*HID + cbase] = f2b(o[ni][1]*i1);
    Out[(bS + rbase + 2)*HID + cbase] = f2b(o[ni][2]*i2);
    Out[(bS + rbase + 3)*HID + cbase] = f2b(o[ni][3]*i3);
  }
}

__launch_bounds__(256, 2)
__global__ void attn_mfma(const unsigned short* __restrict__ Qr,
                          const unsigned short* __restrict__ Kr,
                          const unsigned short* __restrict__ Vt,
                          unsigned short* __restrict__ Out) {
  // [0,8192) K0 | [8192,16384) V0 | [16384,24576) K1 | [24576,32768) V1 | [32768,36864) P
  __shared__ __align__(16) unsigned short lds[36864];
  int bh = blockIdx.x;
  int b = bh >> 4, h = bh & 15;
  int by = blockIdx.y;                       // 0..15
  attn_pass(31 - by, b, h, lds, Qr, Kr, Vt, Out);   // heavy tile
  attn_pass(by,      b, h, lds, Qr, Kr, Vt, Out);   // light tile; total = 33 KV-tiles/block
}

extern "C" void kernel_launch(void* const* d_in, const int* in_sizes, int n_in,
                              void* d_out, int out_size, void* d_ws, size_t ws_size,
                              hipStream_t stream) {
  const float* x_raw   = (const float*)d_in[0];
  const int* positions = (const int*)d_in[1];
  const float* wq_raw  = (const float*)d_in[2];
  const float* wk_raw  = (const float*)d_in[3];
  const float* wv_raw  = (const float*)d_in[4];
  const float* wo_raw  = (const float*)d_in[5];
  const float* c1w_raw = (const float*)d_in[6];
  const float* c1b_raw = (const float*)d_in[7];
  const float* c2w_raw = (const float*)d_in[8];
  const float* c2b_raw = (const float*)d_in[9];
  const float* rms_raw = (const float*)d_in[10];

  const size_t WS_NEEDED = 140000000;
  if (ws_size < WS_NEEDED) {
    long n = (long)out_size;
    fill_debug<<<dim3((unsigned)((n + 255) / 256)), dim3(256), 0, stream>>>((unsigned short*)d_out, n);
    return;
  }

  char* ws = (char*)d_ws;
  size_t off = 0;
  auto alloc = [&](size_t bytes) { char* p = ws + off; off += (bytes + 255) & ~(size_t)255; return p; };
  float* ctab          = (float*)alloc((size_t)S*64*4);
  float* stab          = (float*)alloc((size_t)S*64*4);
  unsigned short* wqkt = (unsigned short*)alloc((size_t)2*HID*HID*2);  // [wq^T ; wk^T], rope-permuted
  unsigned short* wvt  = (unsigned short*)alloc((size_t)HID*HID*2);
  unsigned short* wot  = (unsigned short*)alloc((size_t)HID*HID*2);
  unsigned short* w1t0 = (unsigned short*)alloc((size_t)1024*HID*2);
  unsigned short* w1t1 = (unsigned short*)alloc((size_t)1024*HID*2);
  unsigned short* w2t0 = (unsigned short*)alloc((size_t)HID*1024*2);
  unsigned short* w2t1 = (unsigned short*)alloc((size_t)HID*1024*2);
  unsigned short* xb   = (unsigned short*)alloc((size_t)ROWS*HID*2);   // resid for rms_fuse; reused as kr
  unsigned short* qrb  = (unsigned short*)alloc((size_t)ROWS*HID*2);   // q rotated
  unsigned short* o1   = (unsigned short*)alloc((size_t)ROWS*1024*2);
  unsigned short* yb   = (unsigned short*)alloc((size_t)ROWS*HID*2);   // attn out buffer
  unsigned short* hg   = (unsigned short*)alloc((size_t)ROWS*HID*2);
  unsigned short* qkf  = (unsigned short*)alloc((size_t)ROWS*2*HID*2); // partial scratch (trio/duo)
  unsigned short* vtg  = (unsigned short*)alloc((size_t)BATCH*HID*S*2);
  unsigned short* c1bb = (unsigned short*)alloc(1024*2);
  unsigned short* c2bb = (unsigned short*)alloc(2048*2);
  unsigned short* rmswb= (unsigned short*)alloc(2048*2);
  unsigned short* zpg  = (unsigned short*)alloc(8192*2);               // zero page (kk-advancing)
  unsigned short* krr  = xb;     // xb dead after rms_fuse (resid read)
  unsigned short* attn = yb;
  unsigned short* o1a  = qkf;                              // conv1 partials in qkf scratch
  unsigned short* o1b  = qkf + (size_t)ROWS*1024;
  unsigned short* cpA  = qkf;                              // conv2 partials (after add_bias)
  unsigned short* cpB  = qkf + (size_t)ROWS*HID;

  dim3 b256(256);
  dim3 b512(512);
  // merged prep: converts + rope tables + all 4 weight transposes in ONE dispatch
  prep_combined<<<dim3(4096, 5), b256, 0, stream>>>(
      c1w_raw, c2w_raw, x_raw, positions, c1b_raw, c2b_raw, rms_raw,
      wq_raw, wk_raw, wv_raw, wo_raw,
      w1t0, w1t1, w2t0, w2t1, xb, ctab, stab, c1bb, c2bb, rmswb, zpg,
      wqkt, wvt, wot);
  // trio (256^2 4-phase, 256 uniform K=2048 blocks): conv1-pieceA/B partials + V-proj
  gemm256_trio<<<dim3(256), b512, 0, stream>>>(xb, w1t0, w1t1, wvt, o1a, o1b, vtg, zpg);
  // o1 = o1a + o1b + bias
  add_bias<<<dim3(ROWS*1024/8/256), b256, 0, stream>>>(o1a, o1b, c1bb, o1);
  // duo (256^2 4-phase, 256 uniform K=1024 blocks): conv2 partials
  gemm256_duo<<<dim3(256), b512, 0, stream>>>(o1, w2t0, w2t1, cpA, cpB, zpg);
  // fused: hg = rmsnorm(pA + pB + b2 + xb) * rmsw
  rms_fuse<<<dim3(ROWS), b256, 0, stream>>>(cpA, cpB, c2bb, xb, rmswb, hg);
  // fused q|k projection + RoPE (256x256 4-phase + XCD swizzle): qrb/krr directly
  gemm256_qk_rope<<<dim3(ROWS/256, (2*HID)/256), b512, 0, stream>>>(hg, wqkt, ctab, stab, qrb, krr);
  attn_mfma<<<dim3(BATCH*HEADS, 16), b256, 0, stream>>>(qrb, krr, vtg, attn);
  // output projection: d_out = attn @ wo^T   [4096 x 2048], f32 out
  gemm8_bt<0><<<dim3(ROWS/128, HID/256), b512, 0, stream>>>(attn, attn, wot, wot, HID, 0, nullptr, nullptr, d_out, 1, HID, nullptr);
}